// Round 12
// baseline (1761.595 us; speedup 1.0000x reference)
//
#include <hip/hip_runtime.h>

#define N_NODES 100000
#define N_EDGES 320000
#define HID 256
#define NGAUSS 50
#define NLAYERS 6
#define SCAN_NB 98   // ceil(N_NODES/1024)
#define NT_PTS 4097  // filter table points over [0,8]
#define TB_BLOCKS 65 // ceil(4097/64)
#define H_STEP 0.001953125f
#define INV_H 512.0f

typedef unsigned short ushortT;
typedef unsigned int uintT;
typedef __attribute__((ext_vector_type(8))) short bf16x8;  // 8 bf16 = 4 VGPR
typedef __attribute__((ext_vector_type(4))) float f32x4;
typedef __attribute__((ext_vector_type(2))) __bf16 bf16v2;

// ---------------------------------------------------------------------------
// ShiftedSoftplus via native exp2/log2:
//   softplus(x) - ln2 = max(x,0) + ln2*log2(1 + exp2(-|x|*log2e)) - ln2
__device__ __forceinline__ float sspf(float x) {
  float e = exp2f(-fabsf(x) * 1.44269504088896340736f);
  float l = __log2f(1.0f + e);
  return fmaf(0.69314718055994530942f, l,
              fmaxf(x, 0.0f) - 0.69314718055994530942f);
}

__device__ __forceinline__ float bf2f(ushortT u) {
  union { uintT i; float f; } c;
  c.i = ((uintT)u) << 16;
  return c.f;
}

// unpack low/high bf16 of a packed dword (1 VALU op each; reinterpret is free)
__device__ __forceinline__ float bflo(uintT u) {
  union { uintT i; float f; } c;
  c.i = u << 16;
  return c.f;
}
__device__ __forceinline__ float bfhi(uintT u) {
  union { uintT i; float f; } c;
  c.i = u & 0xFFFF0000u;
  return c.f;
}

// native bf16 converts (RNE) -> v_cvt_pk_bf16_f32 on gfx950
__device__ __forceinline__ ushortT f2bf(float f) {
  union { __bf16 b; ushortT u; } c;
  c.b = (__bf16)f;
  return c.u;
}
__device__ __forceinline__ uintT f2bf2(float lo, float hi) {
  union { bf16v2 v; uintT u; } c;
  c.v = (bf16v2){(__bf16)lo, (__bf16)hi};
  return c.u;
}

// ---------------------------------------------------------------------------
// MFMA K-loops over K=256. A in LDS bf16 (row stride 264), Bt row-major [N,K].
//   A-frag: lane(16q+m) holds A[m][8q..8q+8); C/D: lane(16q+c) reg r -> row 4q+r, col c
__device__ __forceinline__ void mfma_kloop(const ushortT* As, const ushortT* Bt,
                                           f32x4 (&acc)[4][4], int lm, int q) {
#pragma unroll
  for (int k = 0; k < 256; k += 32) {
    bf16x8 a[4], b[4];
#pragma unroll
    for (int rt = 0; rt < 4; ++rt)
      a[rt] = *(const bf16x8*)&As[(rt * 16 + lm) * 264 + k + 8 * q];
#pragma unroll
    for (int ct = 0; ct < 4; ++ct)
      b[ct] = *(const bf16x8*)(Bt + (size_t)(ct * 16 + lm) * HID + k + 8 * q);
#pragma unroll
    for (int rt = 0; rt < 4; ++rt)
#pragma unroll
      for (int ct = 0; ct < 4; ++ct)
        acc[rt][ct] = __builtin_amdgcn_mfma_f32_16x16x32_bf16(a[rt], b[ct], acc[rt][ct], 0, 0, 0);
  }
}

// 8-wave variant, 32-col stripe per wave, acc[4][2].
// ALL 16 B-fragments preloaded into registers (64 VGPR) before the MFMA chain;
// sched_barrier(0) PINS the loads above the chain (R10/R11: without it the
// scheduler sank them back into the loop, VGPR=48, experiment never ran).
// One L2 latency exposure per kloop instead of one per k-step.
__device__ __forceinline__ void mfma_kloop32(const ushortT* As, const ushortT* Bt,
                                             f32x4 (&acc)[4][2], int c0, int lm, int q) {
  bf16x8 b[8][2];
#pragma unroll
  for (int ks = 0; ks < 8; ++ks)
#pragma unroll
    for (int ct = 0; ct < 2; ++ct)
      b[ks][ct] = *(const bf16x8*)(Bt + (size_t)(c0 + ct * 16 + lm) * HID + ks * 32 + 8 * q);
  __builtin_amdgcn_sched_barrier(0);  // loads may not sink past this point
#pragma unroll
  for (int ks = 0; ks < 8; ++ks) {
#pragma unroll
    for (int rt = 0; rt < 4; ++rt) {
      bf16x8 a = *(const bf16x8*)&As[(rt * 16 + lm) * 264 + ks * 32 + 8 * q];
#pragma unroll
      for (int ct = 0; ct < 2; ++ct)
        acc[rt][ct] = __builtin_amdgcn_mfma_f32_16x16x32_bf16(a, b[ks][ct], acc[rt][ct], 0, 0, 0);
    }
  }
}

__device__ __forceinline__ void stage_tile(const ushortT* __restrict__ A,
                                           ushortT* As, int m0, int M, int tid) {
#pragma unroll
  for (int i = 0; i < 8; ++i) {
    int idx = i * 256 + tid;
    int r = idx >> 5, ch = idx & 31;
    int m = m0 + r;
    uint4 u = make_uint4(0, 0, 0, 0);
    if (m < M) u = *(const uint4*)(A + (size_t)m * HID + ch * 8);
    *(uint4*)&As[r * 264 + ch * 8] = u;
  }
}

// acc tile -> LDS (bf16, A layout), 4-wave version
__device__ __forceinline__ void acc_to_lds(ushortT* As, const f32x4 (&acc)[4][4],
                                           int c0, int lm, int q) {
#pragma unroll
  for (int ct = 0; ct < 4; ++ct) {
    const int col = c0 + ct * 16 + lm;
#pragma unroll
    for (int rt = 0; rt < 4; ++rt) {
      const int row = rt * 16 + q * 4;
      uintT u01 = f2bf2(acc[rt][ct][0], acc[rt][ct][1]);
      uintT u23 = f2bf2(acc[rt][ct][2], acc[rt][ct][3]);
      As[(row + 0) * 264 + col] = (ushortT)u01;
      As[(row + 1) * 264 + col] = (ushortT)(u01 >> 16);
      As[(row + 2) * 264 + col] = (ushortT)u23;
      As[(row + 3) * 264 + col] = (ushortT)(u23 >> 16);
    }
  }
}

// coalesced LDS tile -> global (row-contiguous uint4), 256-thread version
__device__ __forceinline__ void store_tile64(const ushortT* As,
                                             ushortT* __restrict__ dst,
                                             int m0, int M, int tid) {
#pragma unroll
  for (int i = 0; i < 8; ++i) {
    int idx = i * 256 + tid;
    int r = idx >> 5, ch = idx & 31;
    int m = m0 + r;
    if (m < M)
      *(uint4*)(dst + (size_t)m * HID + ch * 8) = *(const uint4*)&As[r * 264 + ch * 8];
  }
}

// ---------------------------------------------------------------------------
// MFMA node GEMM (used once for x1_0): C[M,256] = A[M,256] @ W[256,256], bf16 out
__global__ __launch_bounds__(256) void mgemm(const ushortT* __restrict__ A,
                                             const ushortT* __restrict__ Bt,
                                             ushortT* __restrict__ Cbf, int M) {
  __shared__ ushortT As[64 * 264];
  const int tid = threadIdx.x;
  const int m0 = blockIdx.x * 64;
  stage_tile(A, As, m0, M, tid);
  __syncthreads();

  const int lane = tid & 63;
  const int lm = lane & 15, q = lane >> 4;
  const int c0 = (tid >> 6) * 64;

  f32x4 acc[4][4];
#pragma unroll
  for (int rt = 0; rt < 4; ++rt)
#pragma unroll
    for (int ct = 0; ct < 4; ++ct) acc[rt][ct] = (f32x4){0.f, 0.f, 0.f, 0.f};

  mfma_kloop(As, Bt + (size_t)c0 * HID, acc, lm, q);
  __syncthreads();  // all waves done reading As
  acc_to_lds(As, acc, c0, lm, q);
  __syncthreads();
  store_tile64(As, Cbf, m0, M, tid);
}

// ---------------------------------------------------------------------------
// Fused interaction tail + next-layer head (3 chained K=256 GEMMs, LDS-resident).
// 512 threads / 8 waves; 64-row tile; each wave owns a 32-col stripe, acc[4][2];
// B register-preloaded per kloop, pinned via sched_barrier(0).
//   x2 = ssp(agg @ B1t + b1)
//   hn = h + x2 @ B2t + b2            (write h)
//   LAST=0: x1out = hn @ B3t (bf16)   LAST=1: pout = hn @ B3t + b3 (fp32)
template <int LAST>
__global__ __launch_bounds__(512, 2) void mgemm3(const ushortT* __restrict__ A,
                                                 const ushortT* __restrict__ B1t,
                                                 const float* __restrict__ b1v,
                                                 const ushortT* __restrict__ B2t,
                                                 const float* __restrict__ b2v,
                                                 ushortT* __restrict__ h,
                                                 const ushortT* __restrict__ B3t,
                                                 const float* __restrict__ b3v,
                                                 ushortT* __restrict__ x1out,
                                                 float* __restrict__ pout, int M) {
  __shared__ ushortT As[64 * 264];  // 33792 B
  const int tid = threadIdx.x;
  const int m0 = blockIdx.x * 64;

  // stage 64x256 tile: 2048 uint4 over 512 threads
#pragma unroll
  for (int i = 0; i < 4; ++i) {
    int idx = i * 512 + tid;
    int r = idx >> 5, ch = idx & 31;
    int m = m0 + r;
    uint4 u = make_uint4(0, 0, 0, 0);
    if (m < M) u = *(const uint4*)(A + (size_t)m * HID + ch * 8);
    *(uint4*)&As[r * 264 + ch * 8] = u;
  }
  __syncthreads();

  const int lane = tid & 63;
  const int lm = lane & 15, q = lane >> 4;
  const int c0 = (tid >> 6) * 32;  // wave's 32-col stripe

  f32x4 acc[4][2];
#pragma unroll
  for (int rt = 0; rt < 4; ++rt)
#pragma unroll
    for (int ct = 0; ct < 2; ++ct) acc[rt][ct] = (f32x4){0.f, 0.f, 0.f, 0.f};
  mfma_kloop32(As, B1t, acc, c0, lm, q);
  __syncthreads();  // all waves done reading As

  // epi1: x2 = ssp(acc + b1) -> As
#pragma unroll
  for (int ct = 0; ct < 2; ++ct) {
    const int col = c0 + ct * 16 + lm;
    const float bv = b1v[col];
#pragma unroll
    for (int rt = 0; rt < 4; ++rt) {
      const int row = rt * 16 + q * 4;
      float v0 = sspf(acc[rt][ct][0] + bv);
      float v1 = sspf(acc[rt][ct][1] + bv);
      float v2 = sspf(acc[rt][ct][2] + bv);
      float v3 = sspf(acc[rt][ct][3] + bv);
      uintT u01 = f2bf2(v0, v1), u23 = f2bf2(v2, v3);
      As[(row + 0) * 264 + col] = (ushortT)u01;
      As[(row + 1) * 264 + col] = (ushortT)(u01 >> 16);
      As[(row + 2) * 264 + col] = (ushortT)u23;
      As[(row + 3) * 264 + col] = (ushortT)(u23 >> 16);
    }
  }
  __syncthreads();

#pragma unroll
  for (int rt = 0; rt < 4; ++rt)
#pragma unroll
    for (int ct = 0; ct < 2; ++ct) acc[rt][ct] = (f32x4){0.f, 0.f, 0.f, 0.f};
  mfma_kloop32(As, B2t, acc, c0, lm, q);
  __syncthreads();  // all waves done reading As

  // epi2: hn = acc + b2 + h_old -> h (scattered) and As
#pragma unroll
  for (int ct = 0; ct < 2; ++ct) {
    const int col = c0 + ct * 16 + lm;
    const float bv = b2v[col];
#pragma unroll
    for (int rt = 0; rt < 4; ++rt) {
      const int mb = m0 + rt * 16 + q * 4;
      const int row = rt * 16 + q * 4;
      float v[4];
#pragma unroll
      for (int r = 0; r < 4; ++r) {
        float res = (mb + r < M) ? bf2f(h[(size_t)(mb + r) * HID + col]) : 0.0f;
        v[r] = acc[rt][ct][r] + bv + res;
      }
      uintT u01 = f2bf2(v[0], v[1]), u23 = f2bf2(v[2], v[3]);
      As[(row + 0) * 264 + col] = (ushortT)u01;
      As[(row + 1) * 264 + col] = (ushortT)(u01 >> 16);
      As[(row + 2) * 264 + col] = (ushortT)u23;
      As[(row + 3) * 264 + col] = (ushortT)(u23 >> 16);
      if (mb + 0 < M) h[(size_t)(mb + 0) * HID + col] = (ushortT)u01;
      if (mb + 1 < M) h[(size_t)(mb + 1) * HID + col] = (ushortT)(u01 >> 16);
      if (mb + 2 < M) h[(size_t)(mb + 2) * HID + col] = (ushortT)u23;
      if (mb + 3 < M) h[(size_t)(mb + 3) * HID + col] = (ushortT)(u23 >> 16);
    }
  }
  __syncthreads();

#pragma unroll
  for (int rt = 0; rt < 4; ++rt)
#pragma unroll
    for (int ct = 0; ct < 2; ++ct) acc[rt][ct] = (f32x4){0.f, 0.f, 0.f, 0.f};
  mfma_kloop32(As, B3t, acc, c0, lm, q);

#pragma unroll
  for (int ct = 0; ct < 2; ++ct) {
    const int col = c0 + ct * 16 + lm;
    float bv = 0.0f;
    if constexpr (LAST) bv = b3v[col];
#pragma unroll
    for (int rt = 0; rt < 4; ++rt) {
      const int mb = m0 + rt * 16 + q * 4;
      if constexpr (LAST) {
#pragma unroll
        for (int r = 0; r < 4; ++r)
          if (mb + r < M) pout[(size_t)(mb + r) * HID + col] = acc[rt][ct][r] + bv;
      } else {
        uintT u01 = f2bf2(acc[rt][ct][0], acc[rt][ct][1]);
        uintT u23 = f2bf2(acc[rt][ct][2], acc[rt][ct][3]);
        if (mb + 0 < M) x1out[(size_t)(mb + 0) * HID + col] = (ushortT)u01;
        if (mb + 1 < M) x1out[(size_t)(mb + 1) * HID + col] = (ushortT)(u01 >> 16);
        if (mb + 2 < M) x1out[(size_t)(mb + 2) * HID + col] = (ushortT)u23;
        if (mb + 3 < M) x1out[(size_t)(mb + 3) * HID + col] = (ushortT)(u23 >> 16);
      }
    }
  }
}

// ---------------------------------------------------------------------------
// Filter table build: table[l][g][:] = ssp(rbf(g*H_STEP) @ w1t[l] + b1[l]) @ w2t[l] + b2[l]
__global__ __launch_bounds__(256) void table_k(
    const ushortT* __restrict__ w1t_all, const float* __restrict__ b1_all,
    const ushortT* __restrict__ w2t_all, const float* __restrict__ b2_all,
    ushortT* __restrict__ table_all) {
  __shared__ ushortT T[64 * 264];
  ushortT* R = T;  // rbf tile aliases T head; barrier before T write

  const int blk = blockIdx.x;
  const int l = blk / TB_BLOCKS, tb = blk % TB_BLOCKS;
  const ushortT* w1t = w1t_all + (size_t)l * HID * 64;
  const float* b1 = b1_all + (size_t)l * HID;
  const ushortT* w2t = w2t_all + (size_t)l * HID * HID;
  const float* b2 = b2_all + (size_t)l * HID;
  ushortT* table = table_all + (size_t)l * NT_PTS * HID;

  const int tid = threadIdx.x;
  const float delta = 5.0f / 49.0f;
  const float coeff2 = (-0.5f / (delta * delta)) * 1.44269504088896340736f;
#pragma unroll
  for (int i = 0; i < 16; ++i) {
    int idx = i * 256 + tid;
    int e = idx >> 6, k = idx & 63;
    float v = 0.0f;
    if (k < NGAUSS) {
      float dist = (float)(tb * 64 + e) * H_STEP;
      float dd = dist - (float)k * delta;
      v = exp2f(coeff2 * dd * dd);
    }
    R[e * 72 + k] = f2bf(v);
  }
  __syncthreads();

  const int lane = tid & 63;
  const int lm = lane & 15, q = lane >> 4;
  const int c0 = (tid >> 6) * 64;

  // phase 1: t = ssp(R @ w1t + b1), K=64
  {
    f32x4 acc1[4][4];
#pragma unroll
    for (int rt = 0; rt < 4; ++rt)
#pragma unroll
      for (int ct = 0; ct < 4; ++ct) acc1[rt][ct] = (f32x4){0.f, 0.f, 0.f, 0.f};
#pragma unroll
    for (int k = 0; k < 64; k += 32) {
      bf16x8 a[4], b[4];
#pragma unroll
      for (int rt = 0; rt < 4; ++rt)
        a[rt] = *(const bf16x8*)&R[(rt * 16 + lm) * 72 + k + 8 * q];
#pragma unroll
      for (int ct = 0; ct < 4; ++ct)
        b[ct] = *(const bf16x8*)(w1t + (size_t)(c0 + ct * 16 + lm) * 64 + k + 8 * q);
#pragma unroll
      for (int rt = 0; rt < 4; ++rt)
#pragma unroll
        for (int ct = 0; ct < 4; ++ct)
          acc1[rt][ct] = __builtin_amdgcn_mfma_f32_16x16x32_bf16(a[rt], b[ct], acc1[rt][ct], 0, 0, 0);
    }
    __syncthreads();  // done reading R before T (aliased) is written
#pragma unroll
    for (int ct = 0; ct < 4; ++ct) {
      const int col = c0 + ct * 16 + lm;
      const float bv = b1[col];
#pragma unroll
      for (int rt = 0; rt < 4; ++rt) {
        const int row = rt * 16 + q * 4;
        float v0 = sspf(acc1[rt][ct][0] + bv);
        float v1 = sspf(acc1[rt][ct][1] + bv);
        float v2 = sspf(acc1[rt][ct][2] + bv);
        float v3 = sspf(acc1[rt][ct][3] + bv);
        uintT u01 = f2bf2(v0, v1), u23 = f2bf2(v2, v3);
        T[(row + 0) * 264 + col] = (ushortT)u01;
        T[(row + 1) * 264 + col] = (ushortT)(u01 >> 16);
        T[(row + 2) * 264 + col] = (ushortT)u23;
        T[(row + 3) * 264 + col] = (ushortT)(u23 >> 16);
      }
    }
  }
  __syncthreads();

  // phase 2: Wf = t @ w2t + b2, write table rows directly
  f32x4 acc[4][4];
#pragma unroll
  for (int rt = 0; rt < 4; ++rt)
#pragma unroll
    for (int ct = 0; ct < 4; ++ct) acc[rt][ct] = (f32x4){0.f, 0.f, 0.f, 0.f};
  mfma_kloop(T, w2t + (size_t)c0 * HID, acc, lm, q);

#pragma unroll
  for (int ct = 0; ct < 4; ++ct) {
    const int col = c0 + ct * 16 + lm;
    const float bv = b2[col];
#pragma unroll
    for (int rt = 0; rt < 4; ++rt) {
      const int row = rt * 16 + q * 4;
#pragma unroll
      for (int r = 0; r < 4; ++r) {
        int g = tb * 64 + row + r;
        if (g < NT_PTS) table[(size_t)g * HID + col] = f2bf(acc[rt][ct][r] + bv);
      }
    }
  }
}

// ---------------------------------------------------------------------------
// CSR build: histogram -> hierarchical scan -> perm (edge -> CSR slot)
__global__ __launch_bounds__(256) void hist_k(const int* __restrict__ ei,
                                              int* __restrict__ counts) {
  int e = blockIdx.x * 256 + threadIdx.x;
  if (e < N_EDGES) atomicAdd(&counts[ei[N_EDGES + e]], 1);
}

__global__ __launch_bounds__(256) void scanA_k(const int* __restrict__ counts,
                                               int* __restrict__ bsum) {
  const int b = blockIdx.x, tid = threadIdx.x;
  const int base = b * 1024 + tid * 4;
  int s = 0;
  if (base + 3 < N_NODES) {
    int4 v = *(const int4*)(counts + base);
    s = v.x + v.y + v.z + v.w;
  } else {
#pragma unroll
    for (int i = 0; i < 4; ++i) {
      int n = base + i;
      if (n < N_NODES) s += counts[n];
    }
  }
#pragma unroll
  for (int m = 32; m; m >>= 1) s += __shfl_xor(s, m, 64);
  __shared__ int ws[4];
  if ((tid & 63) == 0) ws[tid >> 6] = s;
  __syncthreads();
  if (tid == 0) bsum[b] = ws[0] + ws[1] + ws[2] + ws[3];
}

__global__ __launch_bounds__(128) void scanB_k(int* __restrict__ bsum,
                                               int* __restrict__ row_start) {
  __shared__ int sh[SCAN_NB];
  const int tid = threadIdx.x;
  if (tid < SCAN_NB) sh[tid] = bsum[tid];
  __syncthreads();
  if (tid == 0) {
    int acc = 0;
    for (int i = 0; i < SCAN_NB; ++i) { int t = sh[i]; sh[i] = acc; acc += t; }
    row_start[N_NODES] = acc;
  }
  __syncthreads();
  if (tid < SCAN_NB) bsum[tid] = sh[tid];
}

__global__ __launch_bounds__(256) void scanC_k(const int* __restrict__ counts,
                                               const int* __restrict__ bsum,
                                               int* __restrict__ row_start,
                                               int* __restrict__ cursor) {
  const int b = blockIdx.x, tid = threadIdx.x;
  const int base = b * 1024 + tid * 4;
  int c[4];
  int s = 0;
#pragma unroll
  for (int i = 0; i < 4; ++i) {
    int n = base + i;
    c[i] = (n < N_NODES) ? counts[n] : 0;
    s += c[i];
  }
  __shared__ int sc[256];
  sc[tid] = s;
  __syncthreads();
  int acc = s;
  for (int off = 1; off < 256; off <<= 1) {
    int v = (tid >= off) ? sc[tid - off] : 0;
    __syncthreads();
    acc += v;
    sc[tid] = acc;
    __syncthreads();
  }
  int off0 = acc - s + bsum[b];
#pragma unroll
  for (int i = 0; i < 4; ++i) {
    int n = base + i;
    if (n < N_NODES) {
      row_start[n] = off0;
      cursor[n] = off0;
      off0 += c[i];
    }
  }
}

__global__ __launch_bounds__(256) void perm_k(const int* __restrict__ ei,
                                              int* __restrict__ cursor,
                                              int* __restrict__ perm) {
  int e = blockIdx.x * 256 + threadIdx.x;
  if (e < N_EDGES) perm[e] = atomicAdd(&cursor[ei[N_EDGES + e]], 1);
}

// edge_prep: per edge compute (src, table coord, cutoff), stored in CSR slot order
__global__ __launch_bounds__(256) void edge_prep_k(const int* __restrict__ ei,
                                                   const float* __restrict__ pos,
                                                   const int* __restrict__ perm,
                                                   int* __restrict__ csr_src,
                                                   float* __restrict__ csr_fi,
                                                   float* __restrict__ csr_cs) {
  int e = blockIdx.x * 256 + threadIdx.x;
  if (e >= N_EDGES) return;
  int s = ei[e], d = ei[N_EDGES + e];
  float dx = pos[s * 3 + 0] - pos[d * 3 + 0];
  float dy = pos[s * 3 + 1] - pos[d * 3 + 1];
  float dz = pos[s * 3 + 2] - pos[d * 3 + 2];
  float dist = sqrtf(fmaf(dx, dx, fmaf(dy, dy, dz * dz)) + 1e-12f);
  int slot = perm[e];
  csr_src[slot] = s;
  csr_fi[slot] = fminf(dist * INV_H, 4095.999f);
  csr_cs[slot] = 0.5f * (cosf(dist * (3.14159265358979323846f / 5.0f)) + 1.0f);
}

// fused gather: agg[n] = sum over CSR edges of x1[src] * lerp(table, dist) * C
__global__ __launch_bounds__(256) void gather2_k(const int* __restrict__ row_start,
                                                 const int* __restrict__ csr_src,
                                                 const float* __restrict__ csr_fi,
                                                 const float* __restrict__ csr_cs,
                                                 const ushortT* __restrict__ x1,
                                                 const ushortT* __restrict__ table,
                                                 ushortT* __restrict__ agg) {
  int node = blockIdx.x * 4 + (threadIdx.x >> 6);
  int lane = threadIdx.x & 63;
  if (node >= N_NODES) return;
  int a = row_start[node], b = row_start[node + 1];
  const int co = lane * 4;
  float s0 = 0.f, s1 = 0.f, s2 = 0.f, s3 = 0.f;
  for (int j = a; j < b; ++j) {
    int src = csr_src[j];
    float fi = csr_fi[j];
    float cs = csr_cs[j];
    int i = (int)fi;
    float t = fi - (float)i;
    const ushortT* trow = table + (size_t)i * HID + co;
    uint2 ta = *(const uint2*)trow;
    uint2 tb = *(const uint2*)(trow + HID);
    uint2 xv = *(const uint2*)(x1 + (size_t)src * HID + co);
    float a0 = bflo(ta.x), a1 = bfhi(ta.x), a2 = bflo(ta.y), a3 = bfhi(ta.y);
    float b0 = bflo(tb.x), b1 = bfhi(tb.x), b2 = bflo(tb.y), b3 = bfhi(tb.y);
    float w0 = fmaf(t, b0 - a0, a0);
    float w1 = fmaf(t, b1 - a1, a1);
    float w2 = fmaf(t, b2 - a2, a2);
    float w3 = fmaf(t, b3 - a3, a3);
    s0 = fmaf(bflo(xv.x) * w0, cs, s0);
    s1 = fmaf(bfhi(xv.x) * w1, cs, s1);
    s2 = fmaf(bflo(xv.y) * w2, cs, s2);
    s3 = fmaf(bfhi(xv.y) * w3, cs, s3);
  }
  uint2 o;
  o.x = f2bf2(s0, s1);
  o.y = f2bf2(s2, s3);
  *(uint2*)(agg + (size_t)node * HID + co) = o;
}

// ---------------------------------------------------------------------------
// Weight prep: fp32 W[K,256] -> bf16 Wt[256,K], square 256x256 matrices
__global__ __launch_bounds__(256) void wconv_k(const float* __restrict__ src,
                                               ushortT* __restrict__ dst) {
  __shared__ float tile[64][65];
  const int b = blockIdx.x;
  const int mat = b >> 4, t = b & 15;
  const int tr = (t >> 2) * 64, tc = (t & 3) * 64;
  const float* S = src + (size_t)mat * HID * HID;
  ushortT* D = dst + (size_t)mat * HID * HID;
  const int tid = threadIdx.x;
#pragma unroll
  for (int i = 0; i < 16; ++i) {
    int idx = i * 256 + tid;
    int r = idx >> 6, c = idx & 63;
    tile[r][c] = S[(size_t)(tr + r) * HID + tc + c];
  }
  __syncthreads();
#pragma unroll
  for (int i = 0; i < 16; ++i) {
    int idx = i * 256 + tid;
    int n = idx >> 6, k = idx & 63;
    D[(size_t)(tc + n) * HID + tr + k] = f2bf(tile[k][n]);
  }
}

// mlp_w1 [L][50][256] fp32 -> w1t [L][256][64] bf16 (k padded with zeros)
__global__ __launch_bounds__(256) void w1conv_k(const float* __restrict__ src,
                                                ushortT* __restrict__ dst) {
  const int l = blockIdx.x;
  const int n = threadIdx.x;
  const float* S = src + (size_t)l * NGAUSS * HID;
  ushortT* D = dst + (size_t)l * HID * 64;
  for (int k = 0; k < 64; ++k) {
    float v = (k < NGAUSS) ? S[(size_t)k * HID + n] : 0.0f;
    D[(size_t)n * 64 + k] = f2bf(v);
  }
}

// ---------------------------------------------------------------------------
__global__ __launch_bounds__(256) void embed_k(const int* __restrict__ z,
                                               const float* __restrict__ emb,
                                               ushortT* __restrict__ h) {
  int idx = blockIdx.x * 256 + threadIdx.x;
  if (idx >= N_NODES * HID) return;
  int n = idx >> 8;
  int c = idx & 255;
  h[idx] = f2bf(emb[z[n] * HID + c]);
}

// LayerNorm + SiLU on p (fp32), write final fp32 output
__global__ __launch_bounds__(256) void ln_k(const float* __restrict__ p,
                                            const float* __restrict__ g,
                                            const float* __restrict__ b,
                                            float* __restrict__ out) {
  const int row = blockIdx.x;
  const int tid = threadIdx.x;
  const int wave = tid >> 6, lane = tid & 63;
  __shared__ float red[4], red2[4];

  float v = p[(size_t)row * HID + tid];
  float s = v;
#pragma unroll
  for (int m = 32; m; m >>= 1) s += __shfl_xor(s, m, 64);
  if (lane == 0) red[wave] = s;
  __syncthreads();
  float mu = (red[0] + red[1] + red[2] + red[3]) * (1.0f / 256.0f);
  float diff = v - mu;
  float qv = diff * diff;
#pragma unroll
  for (int m = 32; m; m >>= 1) qv += __shfl_xor(qv, m, 64);
  if (lane == 0) red2[wave] = qv;
  __syncthreads();
  float var = (red2[0] + red2[1] + red2[2] + red2[3]) * (1.0f / 256.0f);
  float y = diff * rsqrtf(var + 1e-5f) * g[tid] + b[tid];
  out[(size_t)row * HID + tid] = y * (1.0f / (1.0f + exp2f(-y * 1.44269504088896340736f)));
}

__global__ __launch_bounds__(256) void tail_k(const int* __restrict__ batch,
                                              float* __restrict__ out) {
  int i = blockIdx.x * 256 + threadIdx.x;
  if (i < N_NODES) out[i] = (float)batch[i];
}

// ---------------------------------------------------------------------------
extern "C" void kernel_launch(void* const* d_in, const int* in_sizes, int n_in,
                              void* d_out, int out_size, void* d_ws, size_t ws_size,
                              hipStream_t stream) {
  const int* z = (const int*)d_in[0];
  const float* pos = (const float*)d_in[1];
  const int* batch = (const int*)d_in[2];
  const int* ei = (const int*)d_in[3];
  const float* emb = (const float*)d_in[4];
  const float* mlp_w1 = (const float*)d_in[5];
  const float* mlp_b1 = (const float*)d_in[6];
  const float* mlp_w2 = (const float*)d_in[7];
  const float* mlp_b2 = (const float*)d_in[8];
  const float* lin1_w = (const float*)d_in[9];
  const float* lin2_w = (const float*)d_in[10];
  const float* lin2_b = (const float*)d_in[11];
  const float* lin_w = (const float*)d_in[12];
  const float* lin_b = (const float*)d_in[13];
  const float* proj_w = (const float*)d_in[14];
  const float* proj_b = (const float*)d_in[15];
  const float* ln_g = (const float*)d_in[16];
  const float* ln_b = (const float*)d_in[17];
  float* out = (float*)d_out;  // fp32: p [N*256] then batch [N]

  const size_t NH = (size_t)N_NODES * HID;
  const size_t WSZ = (size_t)HID * HID;

  // ---- workspace layout (~280 MB) ----
  char* w = (char*)d_ws;
  ushortT* h = (ushortT*)w;      w += NH * 2;
  ushortT* x1 = (ushortT*)w;     w += NH * 2;
  ushortT* agg = (ushortT*)w;    w += NH * 2;
  float* p = (float*)w;          w += NH * 4;
  ushortT* lin1t = (ushortT*)w;  w += 6 * WSZ * 2;
  ushortT* lin2t = (ushortT*)w;  w += 6 * WSZ * 2;
  ushortT* lint = (ushortT*)w;   w += 6 * WSZ * 2;
  ushortT* w2t = (ushortT*)w;    w += 6 * WSZ * 2;
  ushortT* projt = (ushortT*)w;  w += WSZ * 2;
  ushortT* w1t = (ushortT*)w;    w += 6 * (size_t)HID * 64 * 2;
  ushortT* tables = (ushortT*)w; w += 6 * (size_t)NT_PTS * HID * 2;
  int* counts = (int*)w;         w += (size_t)N_NODES * 4;
  int* cursor = (int*)w;         w += (size_t)N_NODES * 4;
  int* row_start = (int*)w;      w += (size_t)(N_NODES + 64) * 4;
  int* perm = (int*)w;           w += (size_t)N_EDGES * 4;
  int* csr_src = (int*)w;        w += (size_t)N_EDGES * 4;
  float* csr_fi = (float*)w;     w += (size_t)N_EDGES * 4;
  float* csr_cs = (float*)w;     w += (size_t)N_EDGES * 4;
  int* bsum = (int*)w;           w += (size_t)128 * 4;

  // ---- CSR build ----
  hipMemsetAsync(counts, 0, (size_t)N_NODES * 4, stream);
  hist_k<<<(N_EDGES + 255) / 256, 256, 0, stream>>>(ei, counts);
  scanA_k<<<SCAN_NB, 256, 0, stream>>>(counts, bsum);
  scanB_k<<<1, 128, 0, stream>>>(bsum, row_start);
  scanC_k<<<SCAN_NB, 256, 0, stream>>>(counts, bsum, row_start, cursor);
  perm_k<<<(N_EDGES + 255) / 256, 256, 0, stream>>>(ei, cursor, perm);
  edge_prep_k<<<(N_EDGES + 255) / 256, 256, 0, stream>>>(ei, pos, perm, csr_src, csr_fi, csr_cs);

  // ---- weight prep ----
  wconv_k<<<6 * 16, 256, 0, stream>>>(lin1_w, lin1t);
  wconv_k<<<6 * 16, 256, 0, stream>>>(lin2_w, lin2t);
  wconv_k<<<6 * 16, 256, 0, stream>>>(lin_w, lint);
  wconv_k<<<6 * 16, 256, 0, stream>>>(mlp_w2, w2t);
  wconv_k<<<16, 256, 0, stream>>>(proj_w, projt);
  w1conv_k<<<6, 256, 0, stream>>>(mlp_w1, w1t);

  // ---- filter tables (all 6 layers, one dispatch) ----
  table_k<<<6 * TB_BLOCKS, 256, 0, stream>>>(w1t, mlp_b1, w2t, mlp_b2, tables);

  embed_k<<<(N_NODES * HID + 255) / 256, 256, 0, stream>>>(z, emb, h);

  const int MB64 = (N_NODES + 63) / 64;
  mgemm<<<MB64, 256, 0, stream>>>(h, lin1t, x1, N_NODES);  // x1_0
  for (int l = 0; l < NLAYERS; ++l) {
    const size_t oW = (size_t)l * WSZ;
    const size_t o1 = (size_t)l * HID;
    gather2_k<<<(N_NODES + 3) / 4, 256, 0, stream>>>(
        row_start, csr_src, csr_fi, csr_cs, x1,
        tables + (size_t)l * NT_PTS * HID, agg);
    if (l < NLAYERS - 1) {
      mgemm3<0><<<MB64, 512, 0, stream>>>(agg, lin2t + oW, lin2_b + o1,
                                          lint + oW, lin_b + o1, h,
                                          lin1t + (size_t)(l + 1) * WSZ, nullptr,
                                          x1, nullptr, N_NODES);
    } else {
      mgemm3<1><<<MB64, 512, 0, stream>>>(agg, lin2t + oW, lin2_b + o1,
                                          lint + oW, lin_b + o1, h,
                                          projt, proj_b, nullptr, p, N_NODES);
    }
  }
  ln_k<<<N_NODES, 256, 0, stream>>>(p, ln_g, ln_b, out);
  tail_k<<<(N_NODES + 255) / 256, 256, 0, stream>>>(batch, out + NH);
}

// Round 13
// 1511.302 us; speedup vs baseline: 1.1656x; 1.1656x over previous
//
#include <hip/hip_runtime.h>

#define N_NODES 100000
#define N_EDGES 320000
#define HID 256
#define NGAUSS 50
#define NLAYERS 6
#define SCAN_NB 98   // ceil(N_NODES/1024)
#define NT_PTS 4097  // filter table points over [0,8]
#define TB_BLOCKS 65 // ceil(4097/64)
#define H_STEP 0.001953125f
#define INV_H 512.0f

typedef unsigned short ushortT;
typedef unsigned int uintT;
typedef __attribute__((ext_vector_type(8))) short bf16x8;  // 8 bf16 = 4 VGPR
typedef __attribute__((ext_vector_type(4))) float f32x4;
typedef __attribute__((ext_vector_type(2))) __bf16 bf16v2;

// ---------------------------------------------------------------------------
// ShiftedSoftplus via native exp2/log2:
//   softplus(x) - ln2 = max(x,0) + ln2*log2(1 + exp2(-|x|*log2e)) - ln2
__device__ __forceinline__ float sspf(float x) {
  float e = exp2f(-fabsf(x) * 1.44269504088896340736f);
  float l = __log2f(1.0f + e);
  return fmaf(0.69314718055994530942f, l,
              fmaxf(x, 0.0f) - 0.69314718055994530942f);
}

__device__ __forceinline__ float bf2f(ushortT u) {
  union { uintT i; float f; } c;
  c.i = ((uintT)u) << 16;
  return c.f;
}

// unpack low/high bf16 of a packed dword (1 VALU op each; reinterpret is free)
__device__ __forceinline__ float bflo(uintT u) {
  union { uintT i; float f; } c;
  c.i = u << 16;
  return c.f;
}
__device__ __forceinline__ float bfhi(uintT u) {
  union { uintT i; float f; } c;
  c.i = u & 0xFFFF0000u;
  return c.f;
}

// native bf16 converts (RNE) -> v_cvt_pk_bf16_f32 on gfx950
__device__ __forceinline__ ushortT f2bf(float f) {
  union { __bf16 b; ushortT u; } c;
  c.b = (__bf16)f;
  return c.u;
}
__device__ __forceinline__ uintT f2bf2(float lo, float hi) {
  union { bf16v2 v; uintT u; } c;
  c.v = (bf16v2){(__bf16)lo, (__bf16)hi};
  return c.u;
}

// ---------------------------------------------------------------------------
// MFMA K-loops over K=256. A in LDS bf16 (row stride 264), Bt row-major [N,K].
//   A-frag: lane(16q+m) holds A[m][8q..8q+8); C/D: lane(16q+c) reg r -> row 4q+r, col c
__device__ __forceinline__ void mfma_kloop(const ushortT* As, const ushortT* Bt,
                                           f32x4 (&acc)[4][4], int lm, int q) {
#pragma unroll
  for (int k = 0; k < 256; k += 32) {
    bf16x8 a[4], b[4];
#pragma unroll
    for (int rt = 0; rt < 4; ++rt)
      a[rt] = *(const bf16x8*)&As[(rt * 16 + lm) * 264 + k + 8 * q];
#pragma unroll
    for (int ct = 0; ct < 4; ++ct)
      b[ct] = *(const bf16x8*)(Bt + (size_t)(ct * 16 + lm) * HID + k + 8 * q);
#pragma unroll
    for (int rt = 0; rt < 4; ++rt)
#pragma unroll
      for (int ct = 0; ct < 4; ++ct)
        acc[rt][ct] = __builtin_amdgcn_mfma_f32_16x16x32_bf16(a[rt], b[ct], acc[rt][ct], 0, 0, 0);
  }
}

// 8-wave variant, 32-col stripe per wave, acc[4][2] (measured-best plain form:
// per-k-step loads; the compiler's sunk-load schedule beat forced preloads).
__device__ __forceinline__ void mfma_kloop32(const ushortT* As, const ushortT* Bt,
                                             f32x4 (&acc)[4][2], int c0, int lm, int q) {
#pragma unroll
  for (int k = 0; k < 256; k += 32) {
    bf16x8 b[2];
#pragma unroll
    for (int ct = 0; ct < 2; ++ct)
      b[ct] = *(const bf16x8*)(Bt + (size_t)(c0 + ct * 16 + lm) * HID + k + 8 * q);
#pragma unroll
    for (int rt = 0; rt < 4; ++rt) {
      bf16x8 a = *(const bf16x8*)&As[(rt * 16 + lm) * 264 + k + 8 * q];
#pragma unroll
      for (int ct = 0; ct < 2; ++ct)
        acc[rt][ct] = __builtin_amdgcn_mfma_f32_16x16x32_bf16(a, b[ct], acc[rt][ct], 0, 0, 0);
    }
  }
}

__device__ __forceinline__ void stage_tile(const ushortT* __restrict__ A,
                                           ushortT* As, int m0, int M, int tid) {
#pragma unroll
  for (int i = 0; i < 8; ++i) {
    int idx = i * 256 + tid;
    int r = idx >> 5, ch = idx & 31;
    int m = m0 + r;
    uint4 u = make_uint4(0, 0, 0, 0);
    if (m < M) u = *(const uint4*)(A + (size_t)m * HID + ch * 8);
    *(uint4*)&As[r * 264 + ch * 8] = u;
  }
}

// acc tile -> LDS (bf16, A layout), 4-wave version
__device__ __forceinline__ void acc_to_lds(ushortT* As, const f32x4 (&acc)[4][4],
                                           int c0, int lm, int q) {
#pragma unroll
  for (int ct = 0; ct < 4; ++ct) {
    const int col = c0 + ct * 16 + lm;
#pragma unroll
    for (int rt = 0; rt < 4; ++rt) {
      const int row = rt * 16 + q * 4;
      uintT u01 = f2bf2(acc[rt][ct][0], acc[rt][ct][1]);
      uintT u23 = f2bf2(acc[rt][ct][2], acc[rt][ct][3]);
      As[(row + 0) * 264 + col] = (ushortT)u01;
      As[(row + 1) * 264 + col] = (ushortT)(u01 >> 16);
      As[(row + 2) * 264 + col] = (ushortT)u23;
      As[(row + 3) * 264 + col] = (ushortT)(u23 >> 16);
    }
  }
}

// coalesced LDS tile -> global (row-contiguous uint4), 256-thread version
__device__ __forceinline__ void store_tile64(const ushortT* As,
                                             ushortT* __restrict__ dst,
                                             int m0, int M, int tid) {
#pragma unroll
  for (int i = 0; i < 8; ++i) {
    int idx = i * 256 + tid;
    int r = idx >> 5, ch = idx & 31;
    int m = m0 + r;
    if (m < M)
      *(uint4*)(dst + (size_t)m * HID + ch * 8) = *(const uint4*)&As[r * 264 + ch * 8];
  }
}

// ---------------------------------------------------------------------------
// MFMA node GEMM (used once for x1_0): C[M,256] = A[M,256] @ W[256,256], bf16 out
__global__ __launch_bounds__(256) void mgemm(const ushortT* __restrict__ A,
                                             const ushortT* __restrict__ Bt,
                                             ushortT* __restrict__ Cbf, int M) {
  __shared__ ushortT As[64 * 264];
  const int tid = threadIdx.x;
  const int m0 = blockIdx.x * 64;
  stage_tile(A, As, m0, M, tid);
  __syncthreads();

  const int lane = tid & 63;
  const int lm = lane & 15, q = lane >> 4;
  const int c0 = (tid >> 6) * 64;

  f32x4 acc[4][4];
#pragma unroll
  for (int rt = 0; rt < 4; ++rt)
#pragma unroll
    for (int ct = 0; ct < 4; ++ct) acc[rt][ct] = (f32x4){0.f, 0.f, 0.f, 0.f};

  mfma_kloop(As, Bt + (size_t)c0 * HID, acc, lm, q);
  __syncthreads();  // all waves done reading As
  acc_to_lds(As, acc, c0, lm, q);
  __syncthreads();
  store_tile64(As, Cbf, m0, M, tid);
}

// ---------------------------------------------------------------------------
// Fused interaction tail + next-layer head (3 chained K=256 GEMMs, LDS-resident).
// 512 threads / 8 waves; 64-row tile; each wave owns a 32-col stripe, acc[4][2].
//   x2 = ssp(agg @ B1t + b1)
//   hn = h + x2 @ B2t + b2            (write h)
//   LAST=0: x1out = hn @ B3t (bf16)   LAST=1: pout = hn @ B3t + b3 (fp32)
template <int LAST>
__global__ __launch_bounds__(512, 2) void mgemm3(const ushortT* __restrict__ A,
                                                 const ushortT* __restrict__ B1t,
                                                 const float* __restrict__ b1v,
                                                 const ushortT* __restrict__ B2t,
                                                 const float* __restrict__ b2v,
                                                 ushortT* __restrict__ h,
                                                 const ushortT* __restrict__ B3t,
                                                 const float* __restrict__ b3v,
                                                 ushortT* __restrict__ x1out,
                                                 float* __restrict__ pout, int M) {
  __shared__ ushortT As[64 * 264];  // 33792 B
  const int tid = threadIdx.x;
  const int m0 = blockIdx.x * 64;

  // stage 64x256 tile: 2048 uint4 over 512 threads
#pragma unroll
  for (int i = 0; i < 4; ++i) {
    int idx = i * 512 + tid;
    int r = idx >> 5, ch = idx & 31;
    int m = m0 + r;
    uint4 u = make_uint4(0, 0, 0, 0);
    if (m < M) u = *(const uint4*)(A + (size_t)m * HID + ch * 8);
    *(uint4*)&As[r * 264 + ch * 8] = u;
  }
  __syncthreads();

  const int lane = tid & 63;
  const int lm = lane & 15, q = lane >> 4;
  const int c0 = (tid >> 6) * 32;  // wave's 32-col stripe

  f32x4 acc[4][2];
#pragma unroll
  for (int rt = 0; rt < 4; ++rt)
#pragma unroll
    for (int ct = 0; ct < 2; ++ct) acc[rt][ct] = (f32x4){0.f, 0.f, 0.f, 0.f};
  mfma_kloop32(As, B1t, acc, c0, lm, q);
  __syncthreads();  // all waves done reading As

  // epi1: x2 = ssp(acc + b1) -> As
#pragma unroll
  for (int ct = 0; ct < 2; ++ct) {
    const int col = c0 + ct * 16 + lm;
    const float bv = b1v[col];
#pragma unroll
    for (int rt = 0; rt < 4; ++rt) {
      const int row = rt * 16 + q * 4;
      float v0 = sspf(acc[rt][ct][0] + bv);
      float v1 = sspf(acc[rt][ct][1] + bv);
      float v2 = sspf(acc[rt][ct][2] + bv);
      float v3 = sspf(acc[rt][ct][3] + bv);
      uintT u01 = f2bf2(v0, v1), u23 = f2bf2(v2, v3);
      As[(row + 0) * 264 + col] = (ushortT)u01;
      As[(row + 1) * 264 + col] = (ushortT)(u01 >> 16);
      As[(row + 2) * 264 + col] = (ushortT)u23;
      As[(row + 3) * 264 + col] = (ushortT)(u23 >> 16);
    }
  }
  __syncthreads();

#pragma unroll
  for (int rt = 0; rt < 4; ++rt)
#pragma unroll
    for (int ct = 0; ct < 2; ++ct) acc[rt][ct] = (f32x4){0.f, 0.f, 0.f, 0.f};
  mfma_kloop32(As, B2t, acc, c0, lm, q);
  __syncthreads();  // all waves done reading As

  // epi2: hn = acc + b2 + h_old -> h (scattered) and As
#pragma unroll
  for (int ct = 0; ct < 2; ++ct) {
    const int col = c0 + ct * 16 + lm;
    const float bv = b2v[col];
#pragma unroll
    for (int rt = 0; rt < 4; ++rt) {
      const int mb = m0 + rt * 16 + q * 4;
      const int row = rt * 16 + q * 4;
      float v[4];
#pragma unroll
      for (int r = 0; r < 4; ++r) {
        float res = (mb + r < M) ? bf2f(h[(size_t)(mb + r) * HID + col]) : 0.0f;
        v[r] = acc[rt][ct][r] + bv + res;
      }
      uintT u01 = f2bf2(v[0], v[1]), u23 = f2bf2(v[2], v[3]);
      As[(row + 0) * 264 + col] = (ushortT)u01;
      As[(row + 1) * 264 + col] = (ushortT)(u01 >> 16);
      As[(row + 2) * 264 + col] = (ushortT)u23;
      As[(row + 3) * 264 + col] = (ushortT)(u23 >> 16);
      if (mb + 0 < M) h[(size_t)(mb + 0) * HID + col] = (ushortT)u01;
      if (mb + 1 < M) h[(size_t)(mb + 1) * HID + col] = (ushortT)(u01 >> 16);
      if (mb + 2 < M) h[(size_t)(mb + 2) * HID + col] = (ushortT)u23;
      if (mb + 3 < M) h[(size_t)(mb + 3) * HID + col] = (ushortT)(u23 >> 16);
    }
  }
  __syncthreads();

#pragma unroll
  for (int rt = 0; rt < 4; ++rt)
#pragma unroll
    for (int ct = 0; ct < 2; ++ct) acc[rt][ct] = (f32x4){0.f, 0.f, 0.f, 0.f};
  mfma_kloop32(As, B3t, acc, c0, lm, q);

#pragma unroll
  for (int ct = 0; ct < 2; ++ct) {
    const int col = c0 + ct * 16 + lm;
    float bv = 0.0f;
    if constexpr (LAST) bv = b3v[col];
#pragma unroll
    for (int rt = 0; rt < 4; ++rt) {
      const int mb = m0 + rt * 16 + q * 4;
      if constexpr (LAST) {
#pragma unroll
        for (int r = 0; r < 4; ++r)
          if (mb + r < M) pout[(size_t)(mb + r) * HID + col] = acc[rt][ct][r] + bv;
      } else {
        uintT u01 = f2bf2(acc[rt][ct][0], acc[rt][ct][1]);
        uintT u23 = f2bf2(acc[rt][ct][2], acc[rt][ct][3]);
        if (mb + 0 < M) x1out[(size_t)(mb + 0) * HID + col] = (ushortT)u01;
        if (mb + 1 < M) x1out[(size_t)(mb + 1) * HID + col] = (ushortT)(u01 >> 16);
        if (mb + 2 < M) x1out[(size_t)(mb + 2) * HID + col] = (ushortT)u23;
        if (mb + 3 < M) x1out[(size_t)(mb + 3) * HID + col] = (ushortT)(u23 >> 16);
      }
    }
  }
}

// ---------------------------------------------------------------------------
// Filter table build: table[l][g][:] = ssp(rbf(g*H_STEP) @ w1t[l] + b1[l]) @ w2t[l] + b2[l]
__global__ __launch_bounds__(256) void table_k(
    const ushortT* __restrict__ w1t_all, const float* __restrict__ b1_all,
    const ushortT* __restrict__ w2t_all, const float* __restrict__ b2_all,
    ushortT* __restrict__ table_all) {
  __shared__ ushortT T[64 * 264];
  ushortT* R = T;  // rbf tile aliases T head; barrier before T write

  const int blk = blockIdx.x;
  const int l = blk / TB_BLOCKS, tb = blk % TB_BLOCKS;
  const ushortT* w1t = w1t_all + (size_t)l * HID * 64;
  const float* b1 = b1_all + (size_t)l * HID;
  const ushortT* w2t = w2t_all + (size_t)l * HID * HID;
  const float* b2 = b2_all + (size_t)l * HID;
  ushortT* table = table_all + (size_t)l * NT_PTS * HID;

  const int tid = threadIdx.x;
  const float delta = 5.0f / 49.0f;
  const float coeff2 = (-0.5f / (delta * delta)) * 1.44269504088896340736f;
#pragma unroll
  for (int i = 0; i < 16; ++i) {
    int idx = i * 256 + tid;
    int e = idx >> 6, k = idx & 63;
    float v = 0.0f;
    if (k < NGAUSS) {
      float dist = (float)(tb * 64 + e) * H_STEP;
      float dd = dist - (float)k * delta;
      v = exp2f(coeff2 * dd * dd);
    }
    R[e * 72 + k] = f2bf(v);
  }
  __syncthreads();

  const int lane = tid & 63;
  const int lm = lane & 15, q = lane >> 4;
  const int c0 = (tid >> 6) * 64;

  // phase 1: t = ssp(R @ w1t + b1), K=64
  {
    f32x4 acc1[4][4];
#pragma unroll
    for (int rt = 0; rt < 4; ++rt)
#pragma unroll
      for (int ct = 0; ct < 4; ++ct) acc1[rt][ct] = (f32x4){0.f, 0.f, 0.f, 0.f};
#pragma unroll
    for (int k = 0; k < 64; k += 32) {
      bf16x8 a[4], b[4];
#pragma unroll
      for (int rt = 0; rt < 4; ++rt)
        a[rt] = *(const bf16x8*)&R[(rt * 16 + lm) * 72 + k + 8 * q];
#pragma unroll
      for (int ct = 0; ct < 4; ++ct)
        b[ct] = *(const bf16x8*)(w1t + (size_t)(c0 + ct * 16 + lm) * 64 + k + 8 * q);
#pragma unroll
      for (int rt = 0; rt < 4; ++rt)
#pragma unroll
        for (int ct = 0; ct < 4; ++ct)
          acc1[rt][ct] = __builtin_amdgcn_mfma_f32_16x16x32_bf16(a[rt], b[ct], acc1[rt][ct], 0, 0, 0);
    }
    __syncthreads();  // done reading R before T (aliased) is written
#pragma unroll
    for (int ct = 0; ct < 4; ++ct) {
      const int col = c0 + ct * 16 + lm;
      const float bv = b1[col];
#pragma unroll
      for (int rt = 0; rt < 4; ++rt) {
        const int row = rt * 16 + q * 4;
        float v0 = sspf(acc1[rt][ct][0] + bv);
        float v1 = sspf(acc1[rt][ct][1] + bv);
        float v2 = sspf(acc1[rt][ct][2] + bv);
        float v3 = sspf(acc1[rt][ct][3] + bv);
        uintT u01 = f2bf2(v0, v1), u23 = f2bf2(v2, v3);
        T[(row + 0) * 264 + col] = (ushortT)u01;
        T[(row + 1) * 264 + col] = (ushortT)(u01 >> 16);
        T[(row + 2) * 264 + col] = (ushortT)u23;
        T[(row + 3) * 264 + col] = (ushortT)(u23 >> 16);
      }
    }
  }
  __syncthreads();

  // phase 2: Wf = t @ w2t + b2, write table rows directly
  f32x4 acc[4][4];
#pragma unroll
  for (int rt = 0; rt < 4; ++rt)
#pragma unroll
    for (int ct = 0; ct < 4; ++ct) acc[rt][ct] = (f32x4){0.f, 0.f, 0.f, 0.f};
  mfma_kloop(T, w2t + (size_t)c0 * HID, acc, lm, q);

#pragma unroll
  for (int ct = 0; ct < 4; ++ct) {
    const int col = c0 + ct * 16 + lm;
    const float bv = b2[col];
#pragma unroll
    for (int rt = 0; rt < 4; ++rt) {
      const int row = rt * 16 + q * 4;
#pragma unroll
      for (int r = 0; r < 4; ++r) {
        int g = tb * 64 + row + r;
        if (g < NT_PTS) table[(size_t)g * HID + col] = f2bf(acc[rt][ct][r] + bv);
      }
    }
  }
}

// ---------------------------------------------------------------------------
// CSR build: histogram -> hierarchical scan -> perm (edge -> CSR slot)
__global__ __launch_bounds__(256) void hist_k(const int* __restrict__ ei,
                                              int* __restrict__ counts) {
  int e = blockIdx.x * 256 + threadIdx.x;
  if (e < N_EDGES) atomicAdd(&counts[ei[N_EDGES + e]], 1);
}

__global__ __launch_bounds__(256) void scanA_k(const int* __restrict__ counts,
                                               int* __restrict__ bsum) {
  const int b = blockIdx.x, tid = threadIdx.x;
  const int base = b * 1024 + tid * 4;
  int s = 0;
  if (base + 3 < N_NODES) {
    int4 v = *(const int4*)(counts + base);
    s = v.x + v.y + v.z + v.w;
  } else {
#pragma unroll
    for (int i = 0; i < 4; ++i) {
      int n = base + i;
      if (n < N_NODES) s += counts[n];
    }
  }
#pragma unroll
  for (int m = 32; m; m >>= 1) s += __shfl_xor(s, m, 64);
  __shared__ int ws[4];
  if ((tid & 63) == 0) ws[tid >> 6] = s;
  __syncthreads();
  if (tid == 0) bsum[b] = ws[0] + ws[1] + ws[2] + ws[3];
}

__global__ __launch_bounds__(128) void scanB_k(int* __restrict__ bsum,
                                               int* __restrict__ row_start) {
  __shared__ int sh[SCAN_NB];
  const int tid = threadIdx.x;
  if (tid < SCAN_NB) sh[tid] = bsum[tid];
  __syncthreads();
  if (tid == 0) {
    int acc = 0;
    for (int i = 0; i < SCAN_NB; ++i) { int t = sh[i]; sh[i] = acc; acc += t; }
    row_start[N_NODES] = acc;
  }
  __syncthreads();
  if (tid < SCAN_NB) bsum[tid] = sh[tid];
}

__global__ __launch_bounds__(256) void scanC_k(const int* __restrict__ counts,
                                               const int* __restrict__ bsum,
                                               int* __restrict__ row_start,
                                               int* __restrict__ cursor) {
  const int b = blockIdx.x, tid = threadIdx.x;
  const int base = b * 1024 + tid * 4;
  int c[4];
  int s = 0;
#pragma unroll
  for (int i = 0; i < 4; ++i) {
    int n = base + i;
    c[i] = (n < N_NODES) ? counts[n] : 0;
    s += c[i];
  }
  __shared__ int sc[256];
  sc[tid] = s;
  __syncthreads();
  int acc = s;
  for (int off = 1; off < 256; off <<= 1) {
    int v = (tid >= off) ? sc[tid - off] : 0;
    __syncthreads();
    acc += v;
    sc[tid] = acc;
    __syncthreads();
  }
  int off0 = acc - s + bsum[b];
#pragma unroll
  for (int i = 0; i < 4; ++i) {
    int n = base + i;
    if (n < N_NODES) {
      row_start[n] = off0;
      cursor[n] = off0;
      off0 += c[i];
    }
  }
}

__global__ __launch_bounds__(256) void perm_k(const int* __restrict__ ei,
                                              int* __restrict__ cursor,
                                              int* __restrict__ perm) {
  int e = blockIdx.x * 256 + threadIdx.x;
  if (e < N_EDGES) perm[e] = atomicAdd(&cursor[ei[N_EDGES + e]], 1);
}

// edge_prep: per edge compute packed meta {src_bits, fi, cs, 0} in CSR slot order
__global__ __launch_bounds__(256) void edge_prep_k(const int* __restrict__ ei,
                                                   const float* __restrict__ pos,
                                                   const int* __restrict__ perm,
                                                   float4* __restrict__ csr_meta) {
  int e = blockIdx.x * 256 + threadIdx.x;
  if (e >= N_EDGES) return;
  int s = ei[e], d = ei[N_EDGES + e];
  float dx = pos[s * 3 + 0] - pos[d * 3 + 0];
  float dy = pos[s * 3 + 1] - pos[d * 3 + 1];
  float dz = pos[s * 3 + 2] - pos[d * 3 + 2];
  float dist = sqrtf(fmaf(dx, dx, fmaf(dy, dy, dz * dz)) + 1e-12f);
  union { int i; float f; } sb;
  sb.i = s;
  float4 m;
  m.x = sb.f;
  m.y = fminf(dist * INV_H, 4095.999f);
  m.z = 0.5f * (cosf(dist * (3.14159265358979323846f / 5.0f)) + 1.0f);
  m.w = 0.0f;
  csr_meta[perm[e]] = m;
}

// fused gather: agg[n] = sum over CSR edges of x1[src] * lerp(table, dist) * C
// (per-edge meta = ONE 16B load instead of 3 scalar loads)
__global__ __launch_bounds__(256) void gather2_k(const int* __restrict__ row_start,
                                                 const float4* __restrict__ csr_meta,
                                                 const ushortT* __restrict__ x1,
                                                 const ushortT* __restrict__ table,
                                                 ushortT* __restrict__ agg) {
  int node = blockIdx.x * 4 + (threadIdx.x >> 6);
  int lane = threadIdx.x & 63;
  if (node >= N_NODES) return;
  int a = row_start[node], b = row_start[node + 1];
  const int co = lane * 4;
  float s0 = 0.f, s1 = 0.f, s2 = 0.f, s3 = 0.f;
  for (int j = a; j < b; ++j) {
    float4 mt = csr_meta[j];
    union { float f; int i; } sb;
    sb.f = mt.x;
    int src = sb.i;
    float fi = mt.y;
    float cs = mt.z;
    int i = (int)fi;
    float t = fi - (float)i;
    const ushortT* trow = table + (size_t)i * HID + co;
    uint2 ta = *(const uint2*)trow;
    uint2 tb = *(const uint2*)(trow + HID);
    uint2 xv = *(const uint2*)(x1 + (size_t)src * HID + co);
    float a0 = bflo(ta.x), a1 = bfhi(ta.x), a2 = bflo(ta.y), a3 = bfhi(ta.y);
    float b0 = bflo(tb.x), b1 = bfhi(tb.x), b2 = bflo(tb.y), b3 = bfhi(tb.y);
    float w0 = fmaf(t, b0 - a0, a0);
    float w1 = fmaf(t, b1 - a1, a1);
    float w2 = fmaf(t, b2 - a2, a2);
    float w3 = fmaf(t, b3 - a3, a3);
    s0 = fmaf(bflo(xv.x) * w0, cs, s0);
    s1 = fmaf(bfhi(xv.x) * w1, cs, s1);
    s2 = fmaf(bflo(xv.y) * w2, cs, s2);
    s3 = fmaf(bfhi(xv.y) * w3, cs, s3);
  }
  uint2 o;
  o.x = f2bf2(s0, s1);
  o.y = f2bf2(s2, s3);
  *(uint2*)(agg + (size_t)node * HID + co) = o;
}

// ---------------------------------------------------------------------------
// Weight prep: fp32 W[K,256] -> bf16 Wt[256,K], square 256x256 matrices
__global__ __launch_bounds__(256) void wconv_k(const float* __restrict__ src,
                                               ushortT* __restrict__ dst) {
  __shared__ float tile[64][65];
  const int b = blockIdx.x;
  const int mat = b >> 4, t = b & 15;
  const int tr = (t >> 2) * 64, tc = (t & 3) * 64;
  const float* S = src + (size_t)mat * HID * HID;
  ushortT* D = dst + (size_t)mat * HID * HID;
  const int tid = threadIdx.x;
#pragma unroll
  for (int i = 0; i < 16; ++i) {
    int idx = i * 256 + tid;
    int r = idx >> 6, c = idx & 63;
    tile[r][c] = S[(size_t)(tr + r) * HID + tc + c];
  }
  __syncthreads();
#pragma unroll
  for (int i = 0; i < 16; ++i) {
    int idx = i * 256 + tid;
    int n = idx >> 6, k = idx & 63;
    D[(size_t)(tc + n) * HID + tr + k] = f2bf(tile[k][n]);
  }
}

// mlp_w1 [L][50][256] fp32 -> w1t [L][256][64] bf16 (k padded with zeros)
__global__ __launch_bounds__(256) void w1conv_k(const float* __restrict__ src,
                                                ushortT* __restrict__ dst) {
  const int l = blockIdx.x;
  const int n = threadIdx.x;
  const float* S = src + (size_t)l * NGAUSS * HID;
  ushortT* D = dst + (size_t)l * HID * 64;
  for (int k = 0; k < 64; ++k) {
    float v = (k < NGAUSS) ? S[(size_t)k * HID + n] : 0.0f;
    D[(size_t)n * 64 + k] = f2bf(v);
  }
}

// ---------------------------------------------------------------------------
__global__ __launch_bounds__(256) void embed_k(const int* __restrict__ z,
                                               const float* __restrict__ emb,
                                               ushortT* __restrict__ h) {
  int idx = blockIdx.x * 256 + threadIdx.x;
  if (idx >= N_NODES * HID) return;
  int n = idx >> 8;
  int c = idx & 255;
  h[idx] = f2bf(emb[z[n] * HID + c]);
}

// LayerNorm + SiLU on p (fp32), write final fp32 output
__global__ __launch_bounds__(256) void ln_k(const float* __restrict__ p,
                                            const float* __restrict__ g,
                                            const float* __restrict__ b,
                                            float* __restrict__ out) {
  const int row = blockIdx.x;
  const int tid = threadIdx.x;
  const int wave = tid >> 6, lane = tid & 63;
  __shared__ float red[4], red2[4];

  float v = p[(size_t)row * HID + tid];
  float s = v;
#pragma unroll
  for (int m = 32; m; m >>= 1) s += __shfl_xor(s, m, 64);
  if (lane == 0) red[wave] = s;
  __syncthreads();
  float mu = (red[0] + red[1] + red[2] + red[3]) * (1.0f / 256.0f);
  float diff = v - mu;
  float qv = diff * diff;
#pragma unroll
  for (int m = 32; m; m >>= 1) qv += __shfl_xor(qv, m, 64);
  if (lane == 0) red2[wave] = qv;
  __syncthreads();
  float var = (red2[0] + red2[1] + red2[2] + red2[3]) * (1.0f / 256.0f);
  float y = diff * rsqrtf(var + 1e-5f) * g[tid] + b[tid];
  out[(size_t)row * HID + tid] = y * (1.0f / (1.0f + exp2f(-y * 1.44269504088896340736f)));
}

__global__ __launch_bounds__(256) void tail_k(const int* __restrict__ batch,
                                              float* __restrict__ out) {
  int i = blockIdx.x * 256 + threadIdx.x;
  if (i < N_NODES) out[i] = (float)batch[i];
}

// ---------------------------------------------------------------------------
extern "C" void kernel_launch(void* const* d_in, const int* in_sizes, int n_in,
                              void* d_out, int out_size, void* d_ws, size_t ws_size,
                              hipStream_t stream) {
  const int* z = (const int*)d_in[0];
  const float* pos = (const float*)d_in[1];
  const int* batch = (const int*)d_in[2];
  const int* ei = (const int*)d_in[3];
  const float* emb = (const float*)d_in[4];
  const float* mlp_w1 = (const float*)d_in[5];
  const float* mlp_b1 = (const float*)d_in[6];
  const float* mlp_w2 = (const float*)d_in[7];
  const float* mlp_b2 = (const float*)d_in[8];
  const float* lin1_w = (const float*)d_in[9];
  const float* lin2_w = (const float*)d_in[10];
  const float* lin2_b = (const float*)d_in[11];
  const float* lin_w = (const float*)d_in[12];
  const float* lin_b = (const float*)d_in[13];
  const float* proj_w = (const float*)d_in[14];
  const float* proj_b = (const float*)d_in[15];
  const float* ln_g = (const float*)d_in[16];
  const float* ln_b = (const float*)d_in[17];
  float* out = (float*)d_out;  // fp32: p [N*256] then batch [N]

  const size_t NH = (size_t)N_NODES * HID;
  const size_t WSZ = (size_t)HID * HID;

  // ---- workspace layout (~280 MB) ----
  char* w = (char*)d_ws;
  ushortT* h = (ushortT*)w;      w += NH * 2;
  ushortT* x1 = (ushortT*)w;     w += NH * 2;
  ushortT* agg = (ushortT*)w;    w += NH * 2;
  float* p = (float*)w;          w += NH * 4;
  ushortT* lin1t = (ushortT*)w;  w += 6 * WSZ * 2;
  ushortT* lin2t = (ushortT*)w;  w += 6 * WSZ * 2;
  ushortT* lint = (ushortT*)w;   w += 6 * WSZ * 2;
  ushortT* w2t = (ushortT*)w;    w += 6 * WSZ * 2;
  ushortT* projt = (ushortT*)w;  w += WSZ * 2;
  ushortT* w1t = (ushortT*)w;    w += 6 * (size_t)HID * 64 * 2;
  ushortT* tables = (ushortT*)w; w += 6 * (size_t)NT_PTS * HID * 2;
  int* counts = (int*)w;         w += (size_t)N_NODES * 4;
  int* cursor = (int*)w;         w += (size_t)N_NODES * 4;
  int* row_start = (int*)w;      w += (size_t)(N_NODES + 64) * 4;
  int* perm = (int*)w;           w += (size_t)N_EDGES * 4;
  float4* csr_meta = (float4*)w; w += (size_t)N_EDGES * 16;
  int* bsum = (int*)w;           w += (size_t)128 * 4;

  // ---- CSR build ----
  hipMemsetAsync(counts, 0, (size_t)N_NODES * 4, stream);
  hist_k<<<(N_EDGES + 255) / 256, 256, 0, stream>>>(ei, counts);
  scanA_k<<<SCAN_NB, 256, 0, stream>>>(counts, bsum);
  scanB_k<<<1, 128, 0, stream>>>(bsum, row_start);
  scanC_k<<<SCAN_NB, 256, 0, stream>>>(counts, bsum, row_start, cursor);
  perm_k<<<(N_EDGES + 255) / 256, 256, 0, stream>>>(ei, cursor, perm);
  edge_prep_k<<<(N_EDGES + 255) / 256, 256, 0, stream>>>(ei, pos, perm, csr_meta);

  // ---- weight prep ----
  wconv_k<<<6 * 16, 256, 0, stream>>>(lin1_w, lin1t);
  wconv_k<<<6 * 16, 256, 0, stream>>>(lin2_w, lin2t);
  wconv_k<<<6 * 16, 256, 0, stream>>>(lin_w, lint);
  wconv_k<<<6 * 16, 256, 0, stream>>>(mlp_w2, w2t);
  wconv_k<<<16, 256, 0, stream>>>(proj_w, projt);
  w1conv_k<<<6, 256, 0, stream>>>(mlp_w1, w1t);

  // ---- filter tables (all 6 layers, one dispatch) ----
  table_k<<<6 * TB_BLOCKS, 256, 0, stream>>>(w1t, mlp_b1, w2t, mlp_b2, tables);

  embed_k<<<(N_NODES * HID + 255) / 256, 256, 0, stream>>>(z, emb, h);

  const int MB64 = (N_NODES + 63) / 64;
  mgemm<<<MB64, 256, 0, stream>>>(h, lin1t, x1, N_NODES);  // x1_0
  for (int l = 0; l < NLAYERS; ++l) {
    const size_t oW = (size_t)l * WSZ;
    const size_t o1 = (size_t)l * HID;
    gather2_k<<<(N_NODES + 3) / 4, 256, 0, stream>>>(
        row_start, csr_meta, x1,
        tables + (size_t)l * NT_PTS * HID, agg);
    if (l < NLAYERS - 1) {
      mgemm3<0><<<MB64, 512, 0, stream>>>(agg, lin2t + oW, lin2_b + o1,
                                          lint + oW, lin_b + o1, h,
                                          lin1t + (size_t)(l + 1) * WSZ, nullptr,
                                          x1, nullptr, N_NODES);
    } else {
      mgemm3<1><<<MB64, 512, 0, stream>>>(agg, lin2t + oW, lin2_b + o1,
                                          lint + oW, lin_b + o1, h,
                                          projt, proj_b, nullptr, p, N_NODES);
    }
  }
  ln_k<<<N_NODES, 256, 0, stream>>>(p, ln_g, ln_b, out);
  tail_k<<<(N_NODES + 255) / 256, 256, 0, stream>>>(batch, out + NH);
}

// Round 14
// 1465.804 us; speedup vs baseline: 1.2018x; 1.0310x over previous
//
#include <hip/hip_runtime.h>

#define N_NODES 100000
#define N_EDGES 320000
#define HID 256
#define NGAUSS 50
#define NLAYERS 6
#define SCAN_NB 98   // ceil(N_NODES/1024)
#define NT_PTS 4097  // filter table points over [0,8]
#define TB_BLOCKS 65 // ceil(4097/64)
#define H_STEP 0.001953125f
#define INV_H 512.0f

typedef unsigned short ushortT;
typedef unsigned int uintT;
typedef __attribute__((ext_vector_type(8))) short bf16x8;  // 8 bf16 = 4 VGPR
typedef __attribute__((ext_vector_type(4))) float f32x4;
typedef __attribute__((ext_vector_type(2))) __bf16 bf16v2;

// ---------------------------------------------------------------------------
// ShiftedSoftplus via native exp2/log2:
//   softplus(x) - ln2 = max(x,0) + ln2*log2(1 + exp2(-|x|*log2e)) - ln2
__device__ __forceinline__ float sspf(float x) {
  float e = exp2f(-fabsf(x) * 1.44269504088896340736f);
  float l = __log2f(1.0f + e);
  return fmaf(0.69314718055994530942f, l,
              fmaxf(x, 0.0f) - 0.69314718055994530942f);
}

__device__ __forceinline__ float bf2f(ushortT u) {
  union { uintT i; float f; } c;
  c.i = ((uintT)u) << 16;
  return c.f;
}

// unpack low/high bf16 of a packed dword (1 VALU op each; reinterpret is free)
__device__ __forceinline__ float bflo(uintT u) {
  union { uintT i; float f; } c;
  c.i = u << 16;
  return c.f;
}
__device__ __forceinline__ float bfhi(uintT u) {
  union { uintT i; float f; } c;
  c.i = u & 0xFFFF0000u;
  return c.f;
}

// native bf16 converts (RNE) -> v_cvt_pk_bf16_f32 on gfx950
__device__ __forceinline__ ushortT f2bf(float f) {
  union { __bf16 b; ushortT u; } c;
  c.b = (__bf16)f;
  return c.u;
}
__device__ __forceinline__ uintT f2bf2(float lo, float hi) {
  union { bf16v2 v; uintT u; } c;
  c.v = (bf16v2){(__bf16)lo, (__bf16)hi};
  return c.u;
}

// ---------------------------------------------------------------------------
// MFMA K-loops over K=256. A in LDS bf16 (row stride 264), Bt row-major [N,K].
//   A-frag: lane(16q+m) holds A[m][8q..8q+8); C/D: lane(16q+c) reg r -> row 4q+r, col c
__device__ __forceinline__ void mfma_kloop(const ushortT* As, const ushortT* Bt,
                                           f32x4 (&acc)[4][4], int lm, int q) {
#pragma unroll
  for (int k = 0; k < 256; k += 32) {
    bf16x8 a[4], b[4];
#pragma unroll
    for (int rt = 0; rt < 4; ++rt)
      a[rt] = *(const bf16x8*)&As[(rt * 16 + lm) * 264 + k + 8 * q];
#pragma unroll
    for (int ct = 0; ct < 4; ++ct)
      b[ct] = *(const bf16x8*)(Bt + (size_t)(ct * 16 + lm) * HID + k + 8 * q);
#pragma unroll
    for (int rt = 0; rt < 4; ++rt)
#pragma unroll
      for (int ct = 0; ct < 4; ++ct)
        acc[rt][ct] = __builtin_amdgcn_mfma_f32_16x16x32_bf16(a[rt], b[ct], acc[rt][ct], 0, 0, 0);
  }
}

// 8-wave variant, 32-col stripe per wave, acc[4][2] (measured-best plain form:
// per-k-step loads; the compiler's sunk-load schedule beat forced preloads).
__device__ __forceinline__ void mfma_kloop32(const ushortT* As, const ushortT* Bt,
                                             f32x4 (&acc)[4][2], int c0, int lm, int q) {
#pragma unroll
  for (int k = 0; k < 256; k += 32) {
    bf16x8 b[2];
#pragma unroll
    for (int ct = 0; ct < 2; ++ct)
      b[ct] = *(const bf16x8*)(Bt + (size_t)(c0 + ct * 16 + lm) * HID + k + 8 * q);
#pragma unroll
    for (int rt = 0; rt < 4; ++rt) {
      bf16x8 a = *(const bf16x8*)&As[(rt * 16 + lm) * 264 + k + 8 * q];
#pragma unroll
      for (int ct = 0; ct < 2; ++ct)
        acc[rt][ct] = __builtin_amdgcn_mfma_f32_16x16x32_bf16(a, b[ct], acc[rt][ct], 0, 0, 0);
    }
  }
}

__device__ __forceinline__ void stage_tile(const ushortT* __restrict__ A,
                                           ushortT* As, int m0, int M, int tid) {
#pragma unroll
  for (int i = 0; i < 8; ++i) {
    int idx = i * 256 + tid;
    int r = idx >> 5, ch = idx & 31;
    int m = m0 + r;
    uint4 u = make_uint4(0, 0, 0, 0);
    if (m < M) u = *(const uint4*)(A + (size_t)m * HID + ch * 8);
    *(uint4*)&As[r * 264 + ch * 8] = u;
  }
}

// acc tile -> LDS (bf16, A layout), 4-wave version
__device__ __forceinline__ void acc_to_lds(ushortT* As, const f32x4 (&acc)[4][4],
                                           int c0, int lm, int q) {
#pragma unroll
  for (int ct = 0; ct < 4; ++ct) {
    const int col = c0 + ct * 16 + lm;
#pragma unroll
    for (int rt = 0; rt < 4; ++rt) {
      const int row = rt * 16 + q * 4;
      uintT u01 = f2bf2(acc[rt][ct][0], acc[rt][ct][1]);
      uintT u23 = f2bf2(acc[rt][ct][2], acc[rt][ct][3]);
      As[(row + 0) * 264 + col] = (ushortT)u01;
      As[(row + 1) * 264 + col] = (ushortT)(u01 >> 16);
      As[(row + 2) * 264 + col] = (ushortT)u23;
      As[(row + 3) * 264 + col] = (ushortT)(u23 >> 16);
    }
  }
}

// coalesced LDS tile -> global (row-contiguous uint4), 256-thread version
__device__ __forceinline__ void store_tile64(const ushortT* As,
                                             ushortT* __restrict__ dst,
                                             int m0, int M, int tid) {
#pragma unroll
  for (int i = 0; i < 8; ++i) {
    int idx = i * 256 + tid;
    int r = idx >> 5, ch = idx & 31;
    int m = m0 + r;
    if (m < M)
      *(uint4*)(dst + (size_t)m * HID + ch * 8) = *(const uint4*)&As[r * 264 + ch * 8];
  }
}

// ---------------------------------------------------------------------------
// MFMA node GEMM (used once for x1_0): C[M,256] = A[M,256] @ W[256,256], bf16 out
__global__ __launch_bounds__(256) void mgemm(const ushortT* __restrict__ A,
                                             const ushortT* __restrict__ Bt,
                                             ushortT* __restrict__ Cbf, int M) {
  __shared__ ushortT As[64 * 264];
  const int tid = threadIdx.x;
  const int m0 = blockIdx.x * 64;
  stage_tile(A, As, m0, M, tid);
  __syncthreads();

  const int lane = tid & 63;
  const int lm = lane & 15, q = lane >> 4;
  const int c0 = (tid >> 6) * 64;

  f32x4 acc[4][4];
#pragma unroll
  for (int rt = 0; rt < 4; ++rt)
#pragma unroll
    for (int ct = 0; ct < 4; ++ct) acc[rt][ct] = (f32x4){0.f, 0.f, 0.f, 0.f};

  mfma_kloop(As, Bt + (size_t)c0 * HID, acc, lm, q);
  __syncthreads();  // all waves done reading As
  acc_to_lds(As, acc, c0, lm, q);
  __syncthreads();
  store_tile64(As, Cbf, m0, M, tid);
}

// ---------------------------------------------------------------------------
// Fused interaction tail + next-layer head (3 chained K=256 GEMMs, LDS-resident).
// 512 threads / 8 waves; 64-row tile; each wave owns a 32-col stripe, acc[4][2].
//   x2 = ssp(agg @ B1t + b1)
//   hn = h + x2 @ B2t + b2            (write h)
//   LAST=0: x1out = hn @ B3t (bf16)   LAST=1: pout = hn @ B3t + b3 (fp32)
template <int LAST>
__global__ __launch_bounds__(512, 2) void mgemm3(const ushortT* __restrict__ A,
                                                 const ushortT* __restrict__ B1t,
                                                 const float* __restrict__ b1v,
                                                 const ushortT* __restrict__ B2t,
                                                 const float* __restrict__ b2v,
                                                 ushortT* __restrict__ h,
                                                 const ushortT* __restrict__ B3t,
                                                 const float* __restrict__ b3v,
                                                 ushortT* __restrict__ x1out,
                                                 float* __restrict__ pout, int M) {
  __shared__ ushortT As[64 * 264];  // 33792 B
  const int tid = threadIdx.x;
  const int m0 = blockIdx.x * 64;

  // stage 64x256 tile: 2048 uint4 over 512 threads
#pragma unroll
  for (int i = 0; i < 4; ++i) {
    int idx = i * 512 + tid;
    int r = idx >> 5, ch = idx & 31;
    int m = m0 + r;
    uint4 u = make_uint4(0, 0, 0, 0);
    if (m < M) u = *(const uint4*)(A + (size_t)m * HID + ch * 8);
    *(uint4*)&As[r * 264 + ch * 8] = u;
  }
  __syncthreads();

  const int lane = tid & 63;
  const int lm = lane & 15, q = lane >> 4;
  const int c0 = (tid >> 6) * 32;  // wave's 32-col stripe

  f32x4 acc[4][2];
#pragma unroll
  for (int rt = 0; rt < 4; ++rt)
#pragma unroll
    for (int ct = 0; ct < 2; ++ct) acc[rt][ct] = (f32x4){0.f, 0.f, 0.f, 0.f};
  mfma_kloop32(As, B1t, acc, c0, lm, q);
  __syncthreads();  // all waves done reading As

  // epi1: x2 = ssp(acc + b1) -> As
#pragma unroll
  for (int ct = 0; ct < 2; ++ct) {
    const int col = c0 + ct * 16 + lm;
    const float bv = b1v[col];
#pragma unroll
    for (int rt = 0; rt < 4; ++rt) {
      const int row = rt * 16 + q * 4;
      float v0 = sspf(acc[rt][ct][0] + bv);
      float v1 = sspf(acc[rt][ct][1] + bv);
      float v2 = sspf(acc[rt][ct][2] + bv);
      float v3 = sspf(acc[rt][ct][3] + bv);
      uintT u01 = f2bf2(v0, v1), u23 = f2bf2(v2, v3);
      As[(row + 0) * 264 + col] = (ushortT)u01;
      As[(row + 1) * 264 + col] = (ushortT)(u01 >> 16);
      As[(row + 2) * 264 + col] = (ushortT)u23;
      As[(row + 3) * 264 + col] = (ushortT)(u23 >> 16);
    }
  }
  __syncthreads();

#pragma unroll
  for (int rt = 0; rt < 4; ++rt)
#pragma unroll
    for (int ct = 0; ct < 2; ++ct) acc[rt][ct] = (f32x4){0.f, 0.f, 0.f, 0.f};
  mfma_kloop32(As, B2t, acc, c0, lm, q);
  __syncthreads();  // all waves done reading As

  // epi2: hn = acc + b2 + h_old -> h (scattered) and As
#pragma unroll
  for (int ct = 0; ct < 2; ++ct) {
    const int col = c0 + ct * 16 + lm;
    const float bv = b2v[col];
#pragma unroll
    for (int rt = 0; rt < 4; ++rt) {
      const int mb = m0 + rt * 16 + q * 4;
      const int row = rt * 16 + q * 4;
      float v[4];
#pragma unroll
      for (int r = 0; r < 4; ++r) {
        float res = (mb + r < M) ? bf2f(h[(size_t)(mb + r) * HID + col]) : 0.0f;
        v[r] = acc[rt][ct][r] + bv + res;
      }
      uintT u01 = f2bf2(v[0], v[1]), u23 = f2bf2(v[2], v[3]);
      As[(row + 0) * 264 + col] = (ushortT)u01;
      As[(row + 1) * 264 + col] = (ushortT)(u01 >> 16);
      As[(row + 2) * 264 + col] = (ushortT)u23;
      As[(row + 3) * 264 + col] = (ushortT)(u23 >> 16);
      if (mb + 0 < M) h[(size_t)(mb + 0) * HID + col] = (ushortT)u01;
      if (mb + 1 < M) h[(size_t)(mb + 1) * HID + col] = (ushortT)(u01 >> 16);
      if (mb + 2 < M) h[(size_t)(mb + 2) * HID + col] = (ushortT)u23;
      if (mb + 3 < M) h[(size_t)(mb + 3) * HID + col] = (ushortT)(u23 >> 16);
    }
  }
  __syncthreads();

#pragma unroll
  for (int rt = 0; rt < 4; ++rt)
#pragma unroll
    for (int ct = 0; ct < 2; ++ct) acc[rt][ct] = (f32x4){0.f, 0.f, 0.f, 0.f};
  mfma_kloop32(As, B3t, acc, c0, lm, q);

#pragma unroll
  for (int ct = 0; ct < 2; ++ct) {
    const int col = c0 + ct * 16 + lm;
    float bv = 0.0f;
    if constexpr (LAST) bv = b3v[col];
#pragma unroll
    for (int rt = 0; rt < 4; ++rt) {
      const int mb = m0 + rt * 16 + q * 4;
      if constexpr (LAST) {
#pragma unroll
        for (int r = 0; r < 4; ++r)
          if (mb + r < M) pout[(size_t)(mb + r) * HID + col] = acc[rt][ct][r] + bv;
      } else {
        uintT u01 = f2bf2(acc[rt][ct][0], acc[rt][ct][1]);
        uintT u23 = f2bf2(acc[rt][ct][2], acc[rt][ct][3]);
        if (mb + 0 < M) x1out[(size_t)(mb + 0) * HID + col] = (ushortT)u01;
        if (mb + 1 < M) x1out[(size_t)(mb + 1) * HID + col] = (ushortT)(u01 >> 16);
        if (mb + 2 < M) x1out[(size_t)(mb + 2) * HID + col] = (ushortT)u23;
        if (mb + 3 < M) x1out[(size_t)(mb + 3) * HID + col] = (ushortT)(u23 >> 16);
      }
    }
  }
}

// ---------------------------------------------------------------------------
// Filter table build: table[l][g][:] = ssp(rbf(g*H_STEP) @ w1t[l] + b1[l]) @ w2t[l] + b2[l]
__global__ __launch_bounds__(256) void table_k(
    const ushortT* __restrict__ w1t_all, const float* __restrict__ b1_all,
    const ushortT* __restrict__ w2t_all, const float* __restrict__ b2_all,
    ushortT* __restrict__ table_all) {
  __shared__ ushortT T[64 * 264];
  ushortT* R = T;  // rbf tile aliases T head; barrier before T write

  const int blk = blockIdx.x;
  const int l = blk / TB_BLOCKS, tb = blk % TB_BLOCKS;
  const ushortT* w1t = w1t_all + (size_t)l * HID * 64;
  const float* b1 = b1_all + (size_t)l * HID;
  const ushortT* w2t = w2t_all + (size_t)l * HID * HID;
  const float* b2 = b2_all + (size_t)l * HID;
  ushortT* table = table_all + (size_t)l * NT_PTS * HID;

  const int tid = threadIdx.x;
  const float delta = 5.0f / 49.0f;
  const float coeff2 = (-0.5f / (delta * delta)) * 1.44269504088896340736f;
#pragma unroll
  for (int i = 0; i < 16; ++i) {
    int idx = i * 256 + tid;
    int e = idx >> 6, k = idx & 63;
    float v = 0.0f;
    if (k < NGAUSS) {
      float dist = (float)(tb * 64 + e) * H_STEP;
      float dd = dist - (float)k * delta;
      v = exp2f(coeff2 * dd * dd);
    }
    R[e * 72 + k] = f2bf(v);
  }
  __syncthreads();

  const int lane = tid & 63;
  const int lm = lane & 15, q = lane >> 4;
  const int c0 = (tid >> 6) * 64;

  // phase 1: t = ssp(R @ w1t + b1), K=64
  {
    f32x4 acc1[4][4];
#pragma unroll
    for (int rt = 0; rt < 4; ++rt)
#pragma unroll
      for (int ct = 0; ct < 4; ++ct) acc1[rt][ct] = (f32x4){0.f, 0.f, 0.f, 0.f};
#pragma unroll
    for (int k = 0; k < 64; k += 32) {
      bf16x8 a[4], b[4];
#pragma unroll
      for (int rt = 0; rt < 4; ++rt)
        a[rt] = *(const bf16x8*)&R[(rt * 16 + lm) * 72 + k + 8 * q];
#pragma unroll
      for (int ct = 0; ct < 4; ++ct)
        b[ct] = *(const bf16x8*)(w1t + (size_t)(c0 + ct * 16 + lm) * 64 + k + 8 * q);
#pragma unroll
      for (int rt = 0; rt < 4; ++rt)
#pragma unroll
        for (int ct = 0; ct < 4; ++ct)
          acc1[rt][ct] = __builtin_amdgcn_mfma_f32_16x16x32_bf16(a[rt], b[ct], acc1[rt][ct], 0, 0, 0);
    }
    __syncthreads();  // done reading R before T (aliased) is written
#pragma unroll
    for (int ct = 0; ct < 4; ++ct) {
      const int col = c0 + ct * 16 + lm;
      const float bv = b1[col];
#pragma unroll
      for (int rt = 0; rt < 4; ++rt) {
        const int row = rt * 16 + q * 4;
        float v0 = sspf(acc1[rt][ct][0] + bv);
        float v1 = sspf(acc1[rt][ct][1] + bv);
        float v2 = sspf(acc1[rt][ct][2] + bv);
        float v3 = sspf(acc1[rt][ct][3] + bv);
        uintT u01 = f2bf2(v0, v1), u23 = f2bf2(v2, v3);
        T[(row + 0) * 264 + col] = (ushortT)u01;
        T[(row + 1) * 264 + col] = (ushortT)(u01 >> 16);
        T[(row + 2) * 264 + col] = (ushortT)u23;
        T[(row + 3) * 264 + col] = (ushortT)(u23 >> 16);
      }
    }
  }
  __syncthreads();

  // phase 2: Wf = t @ w2t + b2, write table rows directly
  f32x4 acc[4][4];
#pragma unroll
  for (int rt = 0; rt < 4; ++rt)
#pragma unroll
    for (int ct = 0; ct < 4; ++ct) acc[rt][ct] = (f32x4){0.f, 0.f, 0.f, 0.f};
  mfma_kloop(T, w2t + (size_t)c0 * HID, acc, lm, q);

#pragma unroll
  for (int ct = 0; ct < 4; ++ct) {
    const int col = c0 + ct * 16 + lm;
    const float bv = b2[col];
#pragma unroll
    for (int rt = 0; rt < 4; ++rt) {
      const int row = rt * 16 + q * 4;
#pragma unroll
      for (int r = 0; r < 4; ++r) {
        int g = tb * 64 + row + r;
        if (g < NT_PTS) table[(size_t)g * HID + col] = f2bf(acc[rt][ct][r] + bv);
      }
    }
  }
}

// ---------------------------------------------------------------------------
// CSR build: histogram -> hierarchical scan -> perm (edge -> CSR slot)
__global__ __launch_bounds__(256) void hist_k(const int* __restrict__ ei,
                                              int* __restrict__ counts) {
  int e = blockIdx.x * 256 + threadIdx.x;
  if (e < N_EDGES) atomicAdd(&counts[ei[N_EDGES + e]], 1);
}

__global__ __launch_bounds__(256) void scanA_k(const int* __restrict__ counts,
                                               int* __restrict__ bsum) {
  const int b = blockIdx.x, tid = threadIdx.x;
  const int base = b * 1024 + tid * 4;
  int s = 0;
  if (base + 3 < N_NODES) {
    int4 v = *(const int4*)(counts + base);
    s = v.x + v.y + v.z + v.w;
  } else {
#pragma unroll
    for (int i = 0; i < 4; ++i) {
      int n = base + i;
      if (n < N_NODES) s += counts[n];
    }
  }
#pragma unroll
  for (int m = 32; m; m >>= 1) s += __shfl_xor(s, m, 64);
  __shared__ int ws[4];
  if ((tid & 63) == 0) ws[tid >> 6] = s;
  __syncthreads();
  if (tid == 0) bsum[b] = ws[0] + ws[1] + ws[2] + ws[3];
}

__global__ __launch_bounds__(128) void scanB_k(int* __restrict__ bsum,
                                               int* __restrict__ row_start) {
  __shared__ int sh[SCAN_NB];
  const int tid = threadIdx.x;
  if (tid < SCAN_NB) sh[tid] = bsum[tid];
  __syncthreads();
  if (tid == 0) {
    int acc = 0;
    for (int i = 0; i < SCAN_NB; ++i) { int t = sh[i]; sh[i] = acc; acc += t; }
    row_start[N_NODES] = acc;
  }
  __syncthreads();
  if (tid < SCAN_NB) bsum[tid] = sh[tid];
}

__global__ __launch_bounds__(256) void scanC_k(const int* __restrict__ counts,
                                               const int* __restrict__ bsum,
                                               int* __restrict__ row_start,
                                               int* __restrict__ cursor) {
  const int b = blockIdx.x, tid = threadIdx.x;
  const int base = b * 1024 + tid * 4;
  int c[4];
  int s = 0;
#pragma unroll
  for (int i = 0; i < 4; ++i) {
    int n = base + i;
    c[i] = (n < N_NODES) ? counts[n] : 0;
    s += c[i];
  }
  __shared__ int sc[256];
  sc[tid] = s;
  __syncthreads();
  int acc = s;
  for (int off = 1; off < 256; off <<= 1) {
    int v = (tid >= off) ? sc[tid - off] : 0;
    __syncthreads();
    acc += v;
    sc[tid] = acc;
    __syncthreads();
  }
  int off0 = acc - s + bsum[b];
#pragma unroll
  for (int i = 0; i < 4; ++i) {
    int n = base + i;
    if (n < N_NODES) {
      row_start[n] = off0;
      cursor[n] = off0;
      off0 += c[i];
    }
  }
}

__global__ __launch_bounds__(256) void perm_k(const int* __restrict__ ei,
                                              int* __restrict__ cursor,
                                              int* __restrict__ perm) {
  int e = blockIdx.x * 256 + threadIdx.x;
  if (e < N_EDGES) perm[e] = atomicAdd(&cursor[ei[N_EDGES + e]], 1);
}

// edge_prep: per edge compute packed meta {src_bits, fi, cs, 0} in CSR slot order
__global__ __launch_bounds__(256) void edge_prep_k(const int* __restrict__ ei,
                                                   const float* __restrict__ pos,
                                                   const int* __restrict__ perm,
                                                   float4* __restrict__ csr_meta) {
  int e = blockIdx.x * 256 + threadIdx.x;
  if (e >= N_EDGES) return;
  int s = ei[e], d = ei[N_EDGES + e];
  float dx = pos[s * 3 + 0] - pos[d * 3 + 0];
  float dy = pos[s * 3 + 1] - pos[d * 3 + 1];
  float dz = pos[s * 3 + 2] - pos[d * 3 + 2];
  float dist = sqrtf(fmaf(dx, dx, fmaf(dy, dy, dz * dz)) + 1e-12f);
  union { int i; float f; } sb;
  sb.i = s;
  float4 m;
  m.x = sb.f;
  m.y = fminf(dist * INV_H, 4095.999f);
  m.z = 0.5f * (cosf(dist * (3.14159265358979323846f / 5.0f)) + 1.0f);
  m.w = 0.0f;
  csr_meta[perm[e]] = m;
}

// fused gather: agg[n] = sum over CSR edges of x1[src] * lerp(table, dist) * C
// 2-way unrolled edge loop: doubles in-flight loads per wave (latency-bound,
// avg 3.2 edges/node). Accumulation order preserved (j then j+1).
__global__ __launch_bounds__(256) void gather2_k(const int* __restrict__ row_start,
                                                 const float4* __restrict__ csr_meta,
                                                 const ushortT* __restrict__ x1,
                                                 const ushortT* __restrict__ table,
                                                 ushortT* __restrict__ agg) {
  int node = blockIdx.x * 4 + (threadIdx.x >> 6);
  int lane = threadIdx.x & 63;
  if (node >= N_NODES) return;
  int a = row_start[node], b = row_start[node + 1];
  const int co = lane * 4;
  float s0 = 0.f, s1 = 0.f, s2 = 0.f, s3 = 0.f;
  int j = a;
  for (; j + 1 < b; j += 2) {
    float4 mtA = csr_meta[j];
    float4 mtB = csr_meta[j + 1];
    union { float f; int i; } sa, sb2;
    sa.f = mtA.x;
    sb2.f = mtB.x;
    int iA = (int)mtA.y, iB = (int)mtB.y;
    float tA = mtA.y - (float)iA, tB = mtB.y - (float)iB;
    const ushortT* trowA = table + (size_t)iA * HID + co;
    const ushortT* trowB = table + (size_t)iB * HID + co;
    uint2 taA = *(const uint2*)trowA;
    uint2 tbA = *(const uint2*)(trowA + HID);
    uint2 xvA = *(const uint2*)(x1 + (size_t)sa.i * HID + co);
    uint2 taB = *(const uint2*)trowB;
    uint2 tbB = *(const uint2*)(trowB + HID);
    uint2 xvB = *(const uint2*)(x1 + (size_t)sb2.i * HID + co);
    // edge j
    {
      float cs = mtA.z;
      float a0 = bflo(taA.x), a1 = bfhi(taA.x), a2 = bflo(taA.y), a3 = bfhi(taA.y);
      float b0 = bflo(tbA.x), b1 = bfhi(tbA.x), b2 = bflo(tbA.y), b3 = bfhi(tbA.y);
      float w0 = fmaf(tA, b0 - a0, a0);
      float w1 = fmaf(tA, b1 - a1, a1);
      float w2 = fmaf(tA, b2 - a2, a2);
      float w3 = fmaf(tA, b3 - a3, a3);
      s0 = fmaf(bflo(xvA.x) * w0, cs, s0);
      s1 = fmaf(bfhi(xvA.x) * w1, cs, s1);
      s2 = fmaf(bflo(xvA.y) * w2, cs, s2);
      s3 = fmaf(bfhi(xvA.y) * w3, cs, s3);
    }
    // edge j+1
    {
      float cs = mtB.z;
      float a0 = bflo(taB.x), a1 = bfhi(taB.x), a2 = bflo(taB.y), a3 = bfhi(taB.y);
      float b0 = bflo(tbB.x), b1 = bfhi(tbB.x), b2 = bflo(tbB.y), b3 = bfhi(tbB.y);
      float w0 = fmaf(tB, b0 - a0, a0);
      float w1 = fmaf(tB, b1 - a1, a1);
      float w2 = fmaf(tB, b2 - a2, a2);
      float w3 = fmaf(tB, b3 - a3, a3);
      s0 = fmaf(bflo(xvB.x) * w0, cs, s0);
      s1 = fmaf(bfhi(xvB.x) * w1, cs, s1);
      s2 = fmaf(bflo(xvB.y) * w2, cs, s2);
      s3 = fmaf(bfhi(xvB.y) * w3, cs, s3);
    }
  }
  if (j < b) {
    float4 mt = csr_meta[j];
    union { float f; int i; } sb;
    sb.f = mt.x;
    float fi = mt.y;
    float cs = mt.z;
    int i = (int)fi;
    float t = fi - (float)i;
    const ushortT* trow = table + (size_t)i * HID + co;
    uint2 ta = *(const uint2*)trow;
    uint2 tb = *(const uint2*)(trow + HID);
    uint2 xv = *(const uint2*)(x1 + (size_t)sb.i * HID + co);
    float a0 = bflo(ta.x), a1 = bfhi(ta.x), a2 = bflo(ta.y), a3 = bfhi(ta.y);
    float b0 = bflo(tb.x), b1 = bfhi(tb.x), b2 = bflo(tb.y), b3 = bfhi(tb.y);
    float w0 = fmaf(t, b0 - a0, a0);
    float w1 = fmaf(t, b1 - a1, a1);
    float w2 = fmaf(t, b2 - a2, a2);
    float w3 = fmaf(t, b3 - a3, a3);
    s0 = fmaf(bflo(xv.x) * w0, cs, s0);
    s1 = fmaf(bfhi(xv.x) * w1, cs, s1);
    s2 = fmaf(bflo(xv.y) * w2, cs, s2);
    s3 = fmaf(bfhi(xv.y) * w3, cs, s3);
  }
  uint2 o;
  o.x = f2bf2(s0, s1);
  o.y = f2bf2(s2, s3);
  *(uint2*)(agg + (size_t)node * HID + co) = o;
}

// ---------------------------------------------------------------------------
// Weight prep: fp32 W[K,256] -> bf16 Wt[256,K], square 256x256 matrices
__global__ __launch_bounds__(256) void wconv_k(const float* __restrict__ src,
                                               ushortT* __restrict__ dst) {
  __shared__ float tile[64][65];
  const int b = blockIdx.x;
  const int mat = b >> 4, t = b & 15;
  const int tr = (t >> 2) * 64, tc = (t & 3) * 64;
  const float* S = src + (size_t)mat * HID * HID;
  ushortT* D = dst + (size_t)mat * HID * HID;
  const int tid = threadIdx.x;
#pragma unroll
  for (int i = 0; i < 16; ++i) {
    int idx = i * 256 + tid;
    int r = idx >> 6, c = idx & 63;
    tile[r][c] = S[(size_t)(tr + r) * HID + tc + c];
  }
  __syncthreads();
#pragma unroll
  for (int i = 0; i < 16; ++i) {
    int idx = i * 256 + tid;
    int n = idx >> 6, k = idx & 63;
    D[(size_t)(tc + n) * HID + tr + k] = f2bf(tile[k][n]);
  }
}

// mlp_w1 [L][50][256] fp32 -> w1t [L][256][64] bf16 (k padded with zeros)
__global__ __launch_bounds__(256) void w1conv_k(const float* __restrict__ src,
                                                ushortT* __restrict__ dst) {
  const int l = blockIdx.x;
  const int n = threadIdx.x;
  const float* S = src + (size_t)l * NGAUSS * HID;
  ushortT* D = dst + (size_t)l * HID * 64;
  for (int k = 0; k < 64; ++k) {
    float v = (k < NGAUSS) ? S[(size_t)k * HID + n] : 0.0f;
    D[(size_t)n * 64 + k] = f2bf(v);
  }
}

// ---------------------------------------------------------------------------
__global__ __launch_bounds__(256) void embed_k(const int* __restrict__ z,
                                               const float* __restrict__ emb,
                                               ushortT* __restrict__ h) {
  int idx = blockIdx.x * 256 + threadIdx.x;
  if (idx >= N_NODES * HID) return;
  int n = idx >> 8;
  int c = idx & 255;
  h[idx] = f2bf(emb[z[n] * HID + c]);
}

// LayerNorm + SiLU on p (fp32), write final fp32 output
__global__ __launch_bounds__(256) void ln_k(const float* __restrict__ p,
                                            const float* __restrict__ g,
                                            const float* __restrict__ b,
                                            float* __restrict__ out) {
  const int row = blockIdx.x;
  const int tid = threadIdx.x;
  const int wave = tid >> 6, lane = tid & 63;
  __shared__ float red[4], red2[4];

  float v = p[(size_t)row * HID + tid];
  float s = v;
#pragma unroll
  for (int m = 32; m; m >>= 1) s += __shfl_xor(s, m, 64);
  if (lane == 0) red[wave] = s;
  __syncthreads();
  float mu = (red[0] + red[1] + red[2] + red[3]) * (1.0f / 256.0f);
  float diff = v - mu;
  float qv = diff * diff;
#pragma unroll
  for (int m = 32; m; m >>= 1) qv += __shfl_xor(qv, m, 64);
  if (lane == 0) red2[wave] = qv;
  __syncthreads();
  float var = (red2[0] + red2[1] + red2[2] + red2[3]) * (1.0f / 256.0f);
  float y = diff * rsqrtf(var + 1e-5f) * g[tid] + b[tid];
  out[(size_t)row * HID + tid] = y * (1.0f / (1.0f + exp2f(-y * 1.44269504088896340736f)));
}

__global__ __launch_bounds__(256) void tail_k(const int* __restrict__ batch,
                                              float* __restrict__ out) {
  int i = blockIdx.x * 256 + threadIdx.x;
  if (i < N_NODES) out[i] = (float)batch[i];
}

// ---------------------------------------------------------------------------
extern "C" void kernel_launch(void* const* d_in, const int* in_sizes, int n_in,
                              void* d_out, int out_size, void* d_ws, size_t ws_size,
                              hipStream_t stream) {
  const int* z = (const int*)d_in[0];
  const float* pos = (const float*)d_in[1];
  const int* batch = (const int*)d_in[2];
  const int* ei = (const int*)d_in[3];
  const float* emb = (const float*)d_in[4];
  const float* mlp_w1 = (const float*)d_in[5];
  const float* mlp_b1 = (const float*)d_in[6];
  const float* mlp_w2 = (const float*)d_in[7];
  const float* mlp_b2 = (const float*)d_in[8];
  const float* lin1_w = (const float*)d_in[9];
  const float* lin2_w = (const float*)d_in[10];
  const float* lin2_b = (const float*)d_in[11];
  const float* lin_w = (const float*)d_in[12];
  const float* lin_b = (const float*)d_in[13];
  const float* proj_w = (const float*)d_in[14];
  const float* proj_b = (const float*)d_in[15];
  const float* ln_g = (const float*)d_in[16];
  const float* ln_b = (const float*)d_in[17];
  float* out = (float*)d_out;  // fp32: p [N*256] then batch [N]

  const size_t NH = (size_t)N_NODES * HID;
  const size_t WSZ = (size_t)HID * HID;

  // ---- workspace layout (~280 MB) ----
  char* w = (char*)d_ws;
  ushortT* h = (ushortT*)w;      w += NH * 2;
  ushortT* x1 = (ushortT*)w;     w += NH * 2;
  ushortT* agg = (ushortT*)w;    w += NH * 2;
  float* p = (float*)w;          w += NH * 4;
  ushortT* lin1t = (ushortT*)w;  w += 6 * WSZ * 2;
  ushortT* lin2t = (ushortT*)w;  w += 6 * WSZ * 2;
  ushortT* lint = (ushortT*)w;   w += 6 * WSZ * 2;
  ushortT* w2t = (ushortT*)w;    w += 6 * WSZ * 2;
  ushortT* projt = (ushortT*)w;  w += WSZ * 2;
  ushortT* w1t = (ushortT*)w;    w += 6 * (size_t)HID * 64 * 2;
  ushortT* tables = (ushortT*)w; w += 6 * (size_t)NT_PTS * HID * 2;
  int* counts = (int*)w;         w += (size_t)N_NODES * 4;
  int* cursor = (int*)w;         w += (size_t)N_NODES * 4;
  int* row_start = (int*)w;      w += (size_t)(N_NODES + 64) * 4;
  int* perm = (int*)w;           w += (size_t)N_EDGES * 4;
  float4* csr_meta = (float4*)w; w += (size_t)N_EDGES * 16;
  int* bsum = (int*)w;           w += (size_t)128 * 4;

  // ---- CSR build ----
  hipMemsetAsync(counts, 0, (size_t)N_NODES * 4, stream);
  hist_k<<<(N_EDGES + 255) / 256, 256, 0, stream>>>(ei, counts);
  scanA_k<<<SCAN_NB, 256, 0, stream>>>(counts, bsum);
  scanB_k<<<1, 128, 0, stream>>>(bsum, row_start);
  scanC_k<<<SCAN_NB, 256, 0, stream>>>(counts, bsum, row_start, cursor);
  perm_k<<<(N_EDGES + 255) / 256, 256, 0, stream>>>(ei, cursor, perm);
  edge_prep_k<<<(N_EDGES + 255) / 256, 256, 0, stream>>>(ei, pos, perm, csr_meta);

  // ---- weight prep ----
  wconv_k<<<6 * 16, 256, 0, stream>>>(lin1_w, lin1t);
  wconv_k<<<6 * 16, 256, 0, stream>>>(lin2_w, lin2t);
  wconv_k<<<6 * 16, 256, 0, stream>>>(lin_w, lint);
  wconv_k<<<6 * 16, 256, 0, stream>>>(mlp_w2, w2t);
  wconv_k<<<16, 256, 0, stream>>>(proj_w, projt);
  w1conv_k<<<6, 256, 0, stream>>>(mlp_w1, w1t);

  // ---- filter tables (all 6 layers, one dispatch) ----
  table_k<<<6 * TB_BLOCKS, 256, 0, stream>>>(w1t, mlp_b1, w2t, mlp_b2, tables);

  embed_k<<<(N_NODES * HID + 255) / 256, 256, 0, stream>>>(z, emb, h);

  const int MB64 = (N_NODES + 63) / 64;
  mgemm<<<MB64, 256, 0, stream>>>(h, lin1t, x1, N_NODES);  // x1_0
  for (int l = 0; l < NLAYERS; ++l) {
    const size_t oW = (size_t)l * WSZ;
    const size_t o1 = (size_t)l * HID;
    gather2_k<<<(N_NODES + 3) / 4, 256, 0, stream>>>(
        row_start, csr_meta, x1,
        tables + (size_t)l * NT_PTS * HID, agg);
    if (l < NLAYERS - 1) {
      mgemm3<0><<<MB64, 512, 0, stream>>>(agg, lin2t + oW, lin2_b + o1,
                                          lint + oW, lin_b + o1, h,
                                          lin1t + (size_t)(l + 1) * WSZ, nullptr,
                                          x1, nullptr, N_NODES);
    } else {
      mgemm3<1><<<MB64, 512, 0, stream>>>(agg, lin2t + oW, lin2_b + o1,
                                          lint + oW, lin_b + o1, h,
                                          projt, proj_b, nullptr, p, N_NODES);
    }
  }
  ln_k<<<N_NODES, 256, 0, stream>>>(p, ln_g, ln_b, out);
  tail_k<<<(N_NODES + 255) / 256, 256, 0, stream>>>(batch, out + NH);
}

// Round 15
// 1457.943 us; speedup vs baseline: 1.2083x; 1.0054x over previous
//
#include <hip/hip_runtime.h>

#define N_NODES 100000
#define N_EDGES 320000
#define HID 256
#define NGAUSS 50
#define NLAYERS 6
#define SCAN_NB 98   // ceil(N_NODES/1024)
#define NT_PTS 1025  // filter table points over [0,8], h=1/128 (L2-resident: 525KB/layer)
#define TB_BLOCKS 17 // ceil(1025/64)
#define H_STEP 0.0078125f
#define INV_H 128.0f

typedef unsigned short ushortT;
typedef unsigned int uintT;
typedef __attribute__((ext_vector_type(8))) short bf16x8;  // 8 bf16 = 4 VGPR
typedef __attribute__((ext_vector_type(4))) float f32x4;
typedef __attribute__((ext_vector_type(2))) __bf16 bf16v2;

// ---------------------------------------------------------------------------
// ShiftedSoftplus via native exp2/log2:
//   softplus(x) - ln2 = max(x,0) + ln2*log2(1 + exp2(-|x|*log2e)) - ln2
__device__ __forceinline__ float sspf(float x) {
  float e = exp2f(-fabsf(x) * 1.44269504088896340736f);
  float l = __log2f(1.0f + e);
  return fmaf(0.69314718055994530942f, l,
              fmaxf(x, 0.0f) - 0.69314718055994530942f);
}

__device__ __forceinline__ float bf2f(ushortT u) {
  union { uintT i; float f; } c;
  c.i = ((uintT)u) << 16;
  return c.f;
}

// unpack low/high bf16 of a packed dword (1 VALU op each; reinterpret is free)
__device__ __forceinline__ float bflo(uintT u) {
  union { uintT i; float f; } c;
  c.i = u << 16;
  return c.f;
}
__device__ __forceinline__ float bfhi(uintT u) {
  union { uintT i; float f; } c;
  c.i = u & 0xFFFF0000u;
  return c.f;
}

// native bf16 converts (RNE) -> v_cvt_pk_bf16_f32 on gfx950
__device__ __forceinline__ ushortT f2bf(float f) {
  union { __bf16 b; ushortT u; } c;
  c.b = (__bf16)f;
  return c.u;
}
__device__ __forceinline__ uintT f2bf2(float lo, float hi) {
  union { bf16v2 v; uintT u; } c;
  c.v = (bf16v2){(__bf16)lo, (__bf16)hi};
  return c.u;
}

// ---------------------------------------------------------------------------
// MFMA K-loops over K=256. A in LDS bf16 (row stride 264), Bt row-major [N,K].
//   A-frag: lane(16q+m) holds A[m][8q..8q+8); C/D: lane(16q+c) reg r -> row 4q+r, col c
__device__ __forceinline__ void mfma_kloop(const ushortT* As, const ushortT* Bt,
                                           f32x4 (&acc)[4][4], int lm, int q) {
#pragma unroll
  for (int k = 0; k < 256; k += 32) {
    bf16x8 a[4], b[4];
#pragma unroll
    for (int rt = 0; rt < 4; ++rt)
      a[rt] = *(const bf16x8*)&As[(rt * 16 + lm) * 264 + k + 8 * q];
#pragma unroll
    for (int ct = 0; ct < 4; ++ct)
      b[ct] = *(const bf16x8*)(Bt + (size_t)(ct * 16 + lm) * HID + k + 8 * q);
#pragma unroll
    for (int rt = 0; rt < 4; ++rt)
#pragma unroll
      for (int ct = 0; ct < 4; ++ct)
        acc[rt][ct] = __builtin_amdgcn_mfma_f32_16x16x32_bf16(a[rt], b[ct], acc[rt][ct], 0, 0, 0);
  }
}

// 8-wave variant, 32-col stripe per wave, acc[4][2] (measured-best plain form:
// per-k-step loads; the compiler's sunk-load schedule beat forced preloads).
__device__ __forceinline__ void mfma_kloop32(const ushortT* As, const ushortT* Bt,
                                             f32x4 (&acc)[4][2], int c0, int lm, int q) {
#pragma unroll
  for (int k = 0; k < 256; k += 32) {
    bf16x8 b[2];
#pragma unroll
    for (int ct = 0; ct < 2; ++ct)
      b[ct] = *(const bf16x8*)(Bt + (size_t)(c0 + ct * 16 + lm) * HID + k + 8 * q);
#pragma unroll
    for (int rt = 0; rt < 4; ++rt) {
      bf16x8 a = *(const bf16x8*)&As[(rt * 16 + lm) * 264 + k + 8 * q];
#pragma unroll
      for (int ct = 0; ct < 2; ++ct)
        acc[rt][ct] = __builtin_amdgcn_mfma_f32_16x16x32_bf16(a, b[ct], acc[rt][ct], 0, 0, 0);
    }
  }
}

__device__ __forceinline__ void stage_tile(const ushortT* __restrict__ A,
                                           ushortT* As, int m0, int M, int tid) {
#pragma unroll
  for (int i = 0; i < 8; ++i) {
    int idx = i * 256 + tid;
    int r = idx >> 5, ch = idx & 31;
    int m = m0 + r;
    uint4 u = make_uint4(0, 0, 0, 0);
    if (m < M) u = *(const uint4*)(A + (size_t)m * HID + ch * 8);
    *(uint4*)&As[r * 264 + ch * 8] = u;
  }
}

// acc tile -> LDS (bf16, A layout), 4-wave version
__device__ __forceinline__ void acc_to_lds(ushortT* As, const f32x4 (&acc)[4][4],
                                           int c0, int lm, int q) {
#pragma unroll
  for (int ct = 0; ct < 4; ++ct) {
    const int col = c0 + ct * 16 + lm;
#pragma unroll
    for (int rt = 0; rt < 4; ++rt) {
      const int row = rt * 16 + q * 4;
      uintT u01 = f2bf2(acc[rt][ct][0], acc[rt][ct][1]);
      uintT u23 = f2bf2(acc[rt][ct][2], acc[rt][ct][3]);
      As[(row + 0) * 264 + col] = (ushortT)u01;
      As[(row + 1) * 264 + col] = (ushortT)(u01 >> 16);
      As[(row + 2) * 264 + col] = (ushortT)u23;
      As[(row + 3) * 264 + col] = (ushortT)(u23 >> 16);
    }
  }
}

// coalesced LDS tile -> global (row-contiguous uint4), 256-thread version
__device__ __forceinline__ void store_tile64(const ushortT* As,
                                             ushortT* __restrict__ dst,
                                             int m0, int M, int tid) {
#pragma unroll
  for (int i = 0; i < 8; ++i) {
    int idx = i * 256 + tid;
    int r = idx >> 5, ch = idx & 31;
    int m = m0 + r;
    if (m < M)
      *(uint4*)(dst + (size_t)m * HID + ch * 8) = *(const uint4*)&As[r * 264 + ch * 8];
  }
}

// ---------------------------------------------------------------------------
// MFMA node GEMM (used once for x1_0): C[M,256] = A[M,256] @ W[256,256], bf16 out
__global__ __launch_bounds__(256) void mgemm(const ushortT* __restrict__ A,
                                             const ushortT* __restrict__ Bt,
                                             ushortT* __restrict__ Cbf, int M) {
  __shared__ ushortT As[64 * 264];
  const int tid = threadIdx.x;
  const int m0 = blockIdx.x * 64;
  stage_tile(A, As, m0, M, tid);
  __syncthreads();

  const int lane = tid & 63;
  const int lm = lane & 15, q = lane >> 4;
  const int c0 = (tid >> 6) * 64;

  f32x4 acc[4][4];
#pragma unroll
  for (int rt = 0; rt < 4; ++rt)
#pragma unroll
    for (int ct = 0; ct < 4; ++ct) acc[rt][ct] = (f32x4){0.f, 0.f, 0.f, 0.f};

  mfma_kloop(As, Bt + (size_t)c0 * HID, acc, lm, q);
  __syncthreads();  // all waves done reading As
  acc_to_lds(As, acc, c0, lm, q);
  __syncthreads();
  store_tile64(As, Cbf, m0, M, tid);
}

// ---------------------------------------------------------------------------
// Fused interaction tail + next-layer head (3 chained K=256 GEMMs, LDS-resident).
// 512 threads / 8 waves; 64-row tile; each wave owns a 32-col stripe, acc[4][2].
//   x2 = ssp(agg @ B1t + b1)
//   hn = h + x2 @ B2t + b2            (write h)
//   LAST=0: x1out = hn @ B3t (bf16)   LAST=1: pout = hn @ B3t + b3 (fp32)
template <int LAST>
__global__ __launch_bounds__(512, 2) void mgemm3(const ushortT* __restrict__ A,
                                                 const ushortT* __restrict__ B1t,
                                                 const float* __restrict__ b1v,
                                                 const ushortT* __restrict__ B2t,
                                                 const float* __restrict__ b2v,
                                                 ushortT* __restrict__ h,
                                                 const ushortT* __restrict__ B3t,
                                                 const float* __restrict__ b3v,
                                                 ushortT* __restrict__ x1out,
                                                 float* __restrict__ pout, int M) {
  __shared__ ushortT As[64 * 264];  // 33792 B
  const int tid = threadIdx.x;
  const int m0 = blockIdx.x * 64;

  // stage 64x256 tile: 2048 uint4 over 512 threads
#pragma unroll
  for (int i = 0; i < 4; ++i) {
    int idx = i * 512 + tid;
    int r = idx >> 5, ch = idx & 31;
    int m = m0 + r;
    uint4 u = make_uint4(0, 0, 0, 0);
    if (m < M) u = *(const uint4*)(A + (size_t)m * HID + ch * 8);
    *(uint4*)&As[r * 264 + ch * 8] = u;
  }
  __syncthreads();

  const int lane = tid & 63;
  const int lm = lane & 15, q = lane >> 4;
  const int c0 = (tid >> 6) * 32;  // wave's 32-col stripe

  f32x4 acc[4][2];
#pragma unroll
  for (int rt = 0; rt < 4; ++rt)
#pragma unroll
    for (int ct = 0; ct < 2; ++ct) acc[rt][ct] = (f32x4){0.f, 0.f, 0.f, 0.f};
  mfma_kloop32(As, B1t, acc, c0, lm, q);
  __syncthreads();  // all waves done reading As

  // epi1: x2 = ssp(acc + b1) -> As
#pragma unroll
  for (int ct = 0; ct < 2; ++ct) {
    const int col = c0 + ct * 16 + lm;
    const float bv = b1v[col];
#pragma unroll
    for (int rt = 0; rt < 4; ++rt) {
      const int row = rt * 16 + q * 4;
      float v0 = sspf(acc[rt][ct][0] + bv);
      float v1 = sspf(acc[rt][ct][1] + bv);
      float v2 = sspf(acc[rt][ct][2] + bv);
      float v3 = sspf(acc[rt][ct][3] + bv);
      uintT u01 = f2bf2(v0, v1), u23 = f2bf2(v2, v3);
      As[(row + 0) * 264 + col] = (ushortT)u01;
      As[(row + 1) * 264 + col] = (ushortT)(u01 >> 16);
      As[(row + 2) * 264 + col] = (ushortT)u23;
      As[(row + 3) * 264 + col] = (ushortT)(u23 >> 16);
    }
  }
  __syncthreads();

#pragma unroll
  for (int rt = 0; rt < 4; ++rt)
#pragma unroll
    for (int ct = 0; ct < 2; ++ct) acc[rt][ct] = (f32x4){0.f, 0.f, 0.f, 0.f};
  mfma_kloop32(As, B2t, acc, c0, lm, q);
  __syncthreads();  // all waves done reading As

  // epi2: hn = acc + b2 + h_old -> h (scattered) and As
#pragma unroll
  for (int ct = 0; ct < 2; ++ct) {
    const int col = c0 + ct * 16 + lm;
    const float bv = b2v[col];
#pragma unroll
    for (int rt = 0; rt < 4; ++rt) {
      const int mb = m0 + rt * 16 + q * 4;
      const int row = rt * 16 + q * 4;
      float v[4];
#pragma unroll
      for (int r = 0; r < 4; ++r) {
        float res = (mb + r < M) ? bf2f(h[(size_t)(mb + r) * HID + col]) : 0.0f;
        v[r] = acc[rt][ct][r] + bv + res;
      }
      uintT u01 = f2bf2(v[0], v[1]), u23 = f2bf2(v[2], v[3]);
      As[(row + 0) * 264 + col] = (ushortT)u01;
      As[(row + 1) * 264 + col] = (ushortT)(u01 >> 16);
      As[(row + 2) * 264 + col] = (ushortT)u23;
      As[(row + 3) * 264 + col] = (ushortT)(u23 >> 16);
      if (mb + 0 < M) h[(size_t)(mb + 0) * HID + col] = (ushortT)u01;
      if (mb + 1 < M) h[(size_t)(mb + 1) * HID + col] = (ushortT)(u01 >> 16);
      if (mb + 2 < M) h[(size_t)(mb + 2) * HID + col] = (ushortT)u23;
      if (mb + 3 < M) h[(size_t)(mb + 3) * HID + col] = (ushortT)(u23 >> 16);
    }
  }
  __syncthreads();

#pragma unroll
  for (int rt = 0; rt < 4; ++rt)
#pragma unroll
    for (int ct = 0; ct < 2; ++ct) acc[rt][ct] = (f32x4){0.f, 0.f, 0.f, 0.f};
  mfma_kloop32(As, B3t, acc, c0, lm, q);

#pragma unroll
  for (int ct = 0; ct < 2; ++ct) {
    const int col = c0 + ct * 16 + lm;
    float bv = 0.0f;
    if constexpr (LAST) bv = b3v[col];
#pragma unroll
    for (int rt = 0; rt < 4; ++rt) {
      const int mb = m0 + rt * 16 + q * 4;
      if constexpr (LAST) {
#pragma unroll
        for (int r = 0; r < 4; ++r)
          if (mb + r < M) pout[(size_t)(mb + r) * HID + col] = acc[rt][ct][r] + bv;
      } else {
        uintT u01 = f2bf2(acc[rt][ct][0], acc[rt][ct][1]);
        uintT u23 = f2bf2(acc[rt][ct][2], acc[rt][ct][3]);
        if (mb + 0 < M) x1out[(size_t)(mb + 0) * HID + col] = (ushortT)u01;
        if (mb + 1 < M) x1out[(size_t)(mb + 1) * HID + col] = (ushortT)(u01 >> 16);
        if (mb + 2 < M) x1out[(size_t)(mb + 2) * HID + col] = (ushortT)u23;
        if (mb + 3 < M) x1out[(size_t)(mb + 3) * HID + col] = (ushortT)(u23 >> 16);
      }
    }
  }
}

// ---------------------------------------------------------------------------
// Filter table build: table[l][g][:] = ssp(rbf(g*H_STEP) @ w1t[l] + b1[l]) @ w2t[l] + b2[l]
__global__ __launch_bounds__(256) void table_k(
    const ushortT* __restrict__ w1t_all, const float* __restrict__ b1_all,
    const ushortT* __restrict__ w2t_all, const float* __restrict__ b2_all,
    ushortT* __restrict__ table_all) {
  __shared__ ushortT T[64 * 264];
  ushortT* R = T;  // rbf tile aliases T head; barrier before T write

  const int blk = blockIdx.x;
  const int l = blk / TB_BLOCKS, tb = blk % TB_BLOCKS;
  const ushortT* w1t = w1t_all + (size_t)l * HID * 64;
  const float* b1 = b1_all + (size_t)l * HID;
  const ushortT* w2t = w2t_all + (size_t)l * HID * HID;
  const float* b2 = b2_all + (size_t)l * HID;
  ushortT* table = table_all + (size_t)l * NT_PTS * HID;

  const int tid = threadIdx.x;
  const float delta = 5.0f / 49.0f;
  const float coeff2 = (-0.5f / (delta * delta)) * 1.44269504088896340736f;
#pragma unroll
  for (int i = 0; i < 16; ++i) {
    int idx = i * 256 + tid;
    int e = idx >> 6, k = idx & 63;
    float v = 0.0f;
    if (k < NGAUSS) {
      float dist = (float)(tb * 64 + e) * H_STEP;
      float dd = dist - (float)k * delta;
      v = exp2f(coeff2 * dd * dd);
    }
    R[e * 72 + k] = f2bf(v);
  }
  __syncthreads();

  const int lane = tid & 63;
  const int lm = lane & 15, q = lane >> 4;
  const int c0 = (tid >> 6) * 64;

  // phase 1: t = ssp(R @ w1t + b1), K=64
  {
    f32x4 acc1[4][4];
#pragma unroll
    for (int rt = 0; rt < 4; ++rt)
#pragma unroll
      for (int ct = 0; ct < 4; ++ct) acc1[rt][ct] = (f32x4){0.f, 0.f, 0.f, 0.f};
#pragma unroll
    for (int k = 0; k < 64; k += 32) {
      bf16x8 a[4], b[4];
#pragma unroll
      for (int rt = 0; rt < 4; ++rt)
        a[rt] = *(const bf16x8*)&R[(rt * 16 + lm) * 72 + k + 8 * q];
#pragma unroll
      for (int ct = 0; ct < 4; ++ct)
        b[ct] = *(const bf16x8*)(w1t + (size_t)(c0 + ct * 16 + lm) * 64 + k + 8 * q);
#pragma unroll
      for (int rt = 0; rt < 4; ++rt)
#pragma unroll
        for (int ct = 0; ct < 4; ++ct)
          acc1[rt][ct] = __builtin_amdgcn_mfma_f32_16x16x32_bf16(a[rt], b[ct], acc1[rt][ct], 0, 0, 0);
    }
    __syncthreads();  // done reading R before T (aliased) is written
#pragma unroll
    for (int ct = 0; ct < 4; ++ct) {
      const int col = c0 + ct * 16 + lm;
      const float bv = b1[col];
#pragma unroll
      for (int rt = 0; rt < 4; ++rt) {
        const int row = rt * 16 + q * 4;
        float v0 = sspf(acc1[rt][ct][0] + bv);
        float v1 = sspf(acc1[rt][ct][1] + bv);
        float v2 = sspf(acc1[rt][ct][2] + bv);
        float v3 = sspf(acc1[rt][ct][3] + bv);
        uintT u01 = f2bf2(v0, v1), u23 = f2bf2(v2, v3);
        T[(row + 0) * 264 + col] = (ushortT)u01;
        T[(row + 1) * 264 + col] = (ushortT)(u01 >> 16);
        T[(row + 2) * 264 + col] = (ushortT)u23;
        T[(row + 3) * 264 + col] = (ushortT)(u23 >> 16);
      }
    }
  }
  __syncthreads();

  // phase 2: Wf = t @ w2t + b2, write table rows directly
  f32x4 acc[4][4];
#pragma unroll
  for (int rt = 0; rt < 4; ++rt)
#pragma unroll
    for (int ct = 0; ct < 4; ++ct) acc[rt][ct] = (f32x4){0.f, 0.f, 0.f, 0.f};
  mfma_kloop(T, w2t + (size_t)c0 * HID, acc, lm, q);

#pragma unroll
  for (int ct = 0; ct < 4; ++ct) {
    const int col = c0 + ct * 16 + lm;
    const float bv = b2[col];
#pragma unroll
    for (int rt = 0; rt < 4; ++rt) {
      const int row = rt * 16 + q * 4;
#pragma unroll
      for (int r = 0; r < 4; ++r) {
        int g = tb * 64 + row + r;
        if (g < NT_PTS) table[(size_t)g * HID + col] = f2bf(acc[rt][ct][r] + bv);
      }
    }
  }
}

// ---------------------------------------------------------------------------
// CSR build: histogram -> hierarchical scan -> perm (edge -> CSR slot)
__global__ __launch_bounds__(256) void hist_k(const int* __restrict__ ei,
                                              int* __restrict__ counts) {
  int e = blockIdx.x * 256 + threadIdx.x;
  if (e < N_EDGES) atomicAdd(&counts[ei[N_EDGES + e]], 1);
}

__global__ __launch_bounds__(256) void scanA_k(const int* __restrict__ counts,
                                               int* __restrict__ bsum) {
  const int b = blockIdx.x, tid = threadIdx.x;
  const int base = b * 1024 + tid * 4;
  int s = 0;
  if (base + 3 < N_NODES) {
    int4 v = *(const int4*)(counts + base);
    s = v.x + v.y + v.z + v.w;
  } else {
#pragma unroll
    for (int i = 0; i < 4; ++i) {
      int n = base + i;
      if (n < N_NODES) s += counts[n];
    }
  }
#pragma unroll
  for (int m = 32; m; m >>= 1) s += __shfl_xor(s, m, 64);
  __shared__ int ws[4];
  if ((tid & 63) == 0) ws[tid >> 6] = s;
  __syncthreads();
  if (tid == 0) bsum[b] = ws[0] + ws[1] + ws[2] + ws[3];
}

__global__ __launch_bounds__(128) void scanB_k(int* __restrict__ bsum,
                                               int* __restrict__ row_start) {
  __shared__ int sh[SCAN_NB];
  const int tid = threadIdx.x;
  if (tid < SCAN_NB) sh[tid] = bsum[tid];
  __syncthreads();
  if (tid == 0) {
    int acc = 0;
    for (int i = 0; i < SCAN_NB; ++i) { int t = sh[i]; sh[i] = acc; acc += t; }
    row_start[N_NODES] = acc;
  }
  __syncthreads();
  if (tid < SCAN_NB) bsum[tid] = sh[tid];
}

__global__ __launch_bounds__(256) void scanC_k(const int* __restrict__ counts,
                                               const int* __restrict__ bsum,
                                               int* __restrict__ row_start,
                                               int* __restrict__ cursor) {
  const int b = blockIdx.x, tid = threadIdx.x;
  const int base = b * 1024 + tid * 4;
  int c[4];
  int s = 0;
#pragma unroll
  for (int i = 0; i < 4; ++i) {
    int n = base + i;
    c[i] = (n < N_NODES) ? counts[n] : 0;
    s += c[i];
  }
  __shared__ int sc[256];
  sc[tid] = s;
  __syncthreads();
  int acc = s;
  for (int off = 1; off < 256; off <<= 1) {
    int v = (tid >= off) ? sc[tid - off] : 0;
    __syncthreads();
    acc += v;
    sc[tid] = acc;
    __syncthreads();
  }
  int off0 = acc - s + bsum[b];
#pragma unroll
  for (int i = 0; i < 4; ++i) {
    int n = base + i;
    if (n < N_NODES) {
      row_start[n] = off0;
      cursor[n] = off0;
      off0 += c[i];
    }
  }
}

__global__ __launch_bounds__(256) void perm_k(const int* __restrict__ ei,
                                              int* __restrict__ cursor,
                                              int* __restrict__ perm) {
  int e = blockIdx.x * 256 + threadIdx.x;
  if (e < N_EDGES) perm[e] = atomicAdd(&cursor[ei[N_EDGES + e]], 1);
}

// edge_prep: per edge compute packed meta {src_bits, fi, cs, 0} in CSR slot order
__global__ __launch_bounds__(256) void edge_prep_k(const int* __restrict__ ei,
                                                   const float* __restrict__ pos,
                                                   const int* __restrict__ perm,
                                                   float4* __restrict__ csr_meta) {
  int e = blockIdx.x * 256 + threadIdx.x;
  if (e >= N_EDGES) return;
  int s = ei[e], d = ei[N_EDGES + e];
  float dx = pos[s * 3 + 0] - pos[d * 3 + 0];
  float dy = pos[s * 3 + 1] - pos[d * 3 + 1];
  float dz = pos[s * 3 + 2] - pos[d * 3 + 2];
  float dist = sqrtf(fmaf(dx, dx, fmaf(dy, dy, dz * dz)) + 1e-12f);
  union { int i; float f; } sb;
  sb.i = s;
  float4 m;
  m.x = sb.f;
  m.y = fminf(dist * INV_H, 1023.999f);
  m.z = 0.5f * (cosf(dist * (3.14159265358979323846f / 5.0f)) + 1.0f);
  m.w = 0.0f;
  csr_meta[perm[e]] = m;
}

// fused gather: agg[n] = sum over CSR edges of x1[src] * lerp(table, dist) * C
// 2-way unrolled edge loop: doubles in-flight loads per wave (latency-bound,
// avg 3.2 edges/node). Accumulation order preserved (j then j+1).
__global__ __launch_bounds__(256) void gather2_k(const int* __restrict__ row_start,
                                                 const float4* __restrict__ csr_meta,
                                                 const ushortT* __restrict__ x1,
                                                 const ushortT* __restrict__ table,
                                                 ushortT* __restrict__ agg) {
  int node = blockIdx.x * 4 + (threadIdx.x >> 6);
  int lane = threadIdx.x & 63;
  if (node >= N_NODES) return;
  int a = row_start[node], b = row_start[node + 1];
  const int co = lane * 4;
  float s0 = 0.f, s1 = 0.f, s2 = 0.f, s3 = 0.f;
  int j = a;
  for (; j + 1 < b; j += 2) {
    float4 mtA = csr_meta[j];
    float4 mtB = csr_meta[j + 1];
    union { float f; int i; } sa, sb2;
    sa.f = mtA.x;
    sb2.f = mtB.x;
    int iA = (int)mtA.y, iB = (int)mtB.y;
    float tA = mtA.y - (float)iA, tB = mtB.y - (float)iB;
    const ushortT* trowA = table + (size_t)iA * HID + co;
    const ushortT* trowB = table + (size_t)iB * HID + co;
    uint2 taA = *(const uint2*)trowA;
    uint2 tbA = *(const uint2*)(trowA + HID);
    uint2 xvA = *(const uint2*)(x1 + (size_t)sa.i * HID + co);
    uint2 taB = *(const uint2*)trowB;
    uint2 tbB = *(const uint2*)(trowB + HID);
    uint2 xvB = *(const uint2*)(x1 + (size_t)sb2.i * HID + co);
    // edge j
    {
      float cs = mtA.z;
      float a0 = bflo(taA.x), a1 = bfhi(taA.x), a2 = bflo(taA.y), a3 = bfhi(taA.y);
      float b0 = bflo(tbA.x), b1 = bfhi(tbA.x), b2 = bflo(tbA.y), b3 = bfhi(tbA.y);
      float w0 = fmaf(tA, b0 - a0, a0);
      float w1 = fmaf(tA, b1 - a1, a1);
      float w2 = fmaf(tA, b2 - a2, a2);
      float w3 = fmaf(tA, b3 - a3, a3);
      s0 = fmaf(bflo(xvA.x) * w0, cs, s0);
      s1 = fmaf(bfhi(xvA.x) * w1, cs, s1);
      s2 = fmaf(bflo(xvA.y) * w2, cs, s2);
      s3 = fmaf(bfhi(xvA.y) * w3, cs, s3);
    }
    // edge j+1
    {
      float cs = mtB.z;
      float a0 = bflo(taB.x), a1 = bfhi(taB.x), a2 = bflo(taB.y), a3 = bfhi(taB.y);
      float b0 = bflo(tbB.x), b1 = bfhi(tbB.x), b2 = bflo(tbB.y), b3 = bfhi(tbB.y);
      float w0 = fmaf(tB, b0 - a0, a0);
      float w1 = fmaf(tB, b1 - a1, a1);
      float w2 = fmaf(tB, b2 - a2, a2);
      float w3 = fmaf(tB, b3 - a3, a3);
      s0 = fmaf(bflo(xvB.x) * w0, cs, s0);
      s1 = fmaf(bfhi(xvB.x) * w1, cs, s1);
      s2 = fmaf(bflo(xvB.y) * w2, cs, s2);
      s3 = fmaf(bfhi(xvB.y) * w3, cs, s3);
    }
  }
  if (j < b) {
    float4 mt = csr_meta[j];
    union { float f; int i; } sb;
    sb.f = mt.x;
    float fi = mt.y;
    float cs = mt.z;
    int i = (int)fi;
    float t = fi - (float)i;
    const ushortT* trow = table + (size_t)i * HID + co;
    uint2 ta = *(const uint2*)trow;
    uint2 tb = *(const uint2*)(trow + HID);
    uint2 xv = *(const uint2*)(x1 + (size_t)sb.i * HID + co);
    float a0 = bflo(ta.x), a1 = bfhi(ta.x), a2 = bflo(ta.y), a3 = bfhi(ta.y);
    float b0 = bflo(tb.x), b1 = bfhi(tb.x), b2 = bflo(tb.y), b3 = bfhi(tb.y);
    float w0 = fmaf(t, b0 - a0, a0);
    float w1 = fmaf(t, b1 - a1, a1);
    float w2 = fmaf(t, b2 - a2, a2);
    float w3 = fmaf(t, b3 - a3, a3);
    s0 = fmaf(bflo(xv.x) * w0, cs, s0);
    s1 = fmaf(bfhi(xv.x) * w1, cs, s1);
    s2 = fmaf(bflo(xv.y) * w2, cs, s2);
    s3 = fmaf(bfhi(xv.y) * w3, cs, s3);
  }
  uint2 o;
  o.x = f2bf2(s0, s1);
  o.y = f2bf2(s2, s3);
  *(uint2*)(agg + (size_t)node * HID + co) = o;
}

// ---------------------------------------------------------------------------
// Weight prep: fp32 W[K,256] -> bf16 Wt[256,K], square 256x256 matrices
__global__ __launch_bounds__(256) void wconv_k(const float* __restrict__ src,
                                               ushortT* __restrict__ dst) {
  __shared__ float tile[64][65];
  const int b = blockIdx.x;
  const int mat = b >> 4, t = b & 15;
  const int tr = (t >> 2) * 64, tc = (t & 3) * 64;
  const float* S = src + (size_t)mat * HID * HID;
  ushortT* D = dst + (size_t)mat * HID * HID;
  const int tid = threadIdx.x;
#pragma unroll
  for (int i = 0; i < 16; ++i) {
    int idx = i * 256 + tid;
    int r = idx >> 6, c = idx & 63;
    tile[r][c] = S[(size_t)(tr + r) * HID + tc + c];
  }
  __syncthreads();
#pragma unroll
  for (int i = 0; i < 16; ++i) {
    int idx = i * 256 + tid;
    int n = idx >> 6, k = idx & 63;
    D[(size_t)(tc + n) * HID + tr + k] = f2bf(tile[k][n]);
  }
}

// mlp_w1 [L][50][256] fp32 -> w1t [L][256][64] bf16 (k padded with zeros)
__global__ __launch_bounds__(256) void w1conv_k(const float* __restrict__ src,
                                                ushortT* __restrict__ dst) {
  const int l = blockIdx.x;
  const int n = threadIdx.x;
  const float* S = src + (size_t)l * NGAUSS * HID;
  ushortT* D = dst + (size_t)l * HID * 64;
  for (int k = 0; k < 64; ++k) {
    float v = (k < NGAUSS) ? S[(size_t)k * HID + n] : 0.0f;
    D[(size_t)n * 64 + k] = f2bf(v);
  }
}

// ---------------------------------------------------------------------------
__global__ __launch_bounds__(256) void embed_k(const int* __restrict__ z,
                                               const float* __restrict__ emb,
                                               ushortT* __restrict__ h) {
  int idx = blockIdx.x * 256 + threadIdx.x;
  if (idx >= N_NODES * HID) return;
  int n = idx >> 8;
  int c = idx & 255;
  h[idx] = f2bf(emb[z[n] * HID + c]);
}

// LayerNorm + SiLU on p (fp32), write final fp32 output
__global__ __launch_bounds__(256) void ln_k(const float* __restrict__ p,
                                            const float* __restrict__ g,
                                            const float* __restrict__ b,
                                            float* __restrict__ out) {
  const int row = blockIdx.x;
  const int tid = threadIdx.x;
  const int wave = tid >> 6, lane = tid & 63;
  __shared__ float red[4], red2[4];

  float v = p[(size_t)row * HID + tid];
  float s = v;
#pragma unroll
  for (int m = 32; m; m >>= 1) s += __shfl_xor(s, m, 64);
  if (lane == 0) red[wave] = s;
  __syncthreads();
  float mu = (red[0] + red[1] + red[2] + red[3]) * (1.0f / 256.0f);
  float diff = v - mu;
  float qv = diff * diff;
#pragma unroll
  for (int m = 32; m; m >>= 1) qv += __shfl_xor(qv, m, 64);
  if (lane == 0) red2[wave] = qv;
  __syncthreads();
  float var = (red2[0] + red2[1] + red2[2] + red2[3]) * (1.0f / 256.0f);
  float y = diff * rsqrtf(var + 1e-5f) * g[tid] + b[tid];
  out[(size_t)row * HID + tid] = y * (1.0f / (1.0f + exp2f(-y * 1.44269504088896340736f)));
}

__global__ __launch_bounds__(256) void tail_k(const int* __restrict__ batch,
                                              float* __restrict__ out) {
  int i = blockIdx.x * 256 + threadIdx.x;
  if (i < N_NODES) out[i] = (float)batch[i];
}

// ---------------------------------------------------------------------------
extern "C" void kernel_launch(void* const* d_in, const int* in_sizes, int n_in,
                              void* d_out, int out_size, void* d_ws, size_t ws_size,
                              hipStream_t stream) {
  const int* z = (const int*)d_in[0];
  const float* pos = (const float*)d_in[1];
  const int* batch = (const int*)d_in[2];
  const int* ei = (const int*)d_in[3];
  const float* emb = (const float*)d_in[4];
  const float* mlp_w1 = (const float*)d_in[5];
  const float* mlp_b1 = (const float*)d_in[6];
  const float* mlp_w2 = (const float*)d_in[7];
  const float* mlp_b2 = (const float*)d_in[8];
  const float* lin1_w = (const float*)d_in[9];
  const float* lin2_w = (const float*)d_in[10];
  const float* lin2_b = (const float*)d_in[11];
  const float* lin_w = (const float*)d_in[12];
  const float* lin_b = (const float*)d_in[13];
  const float* proj_w = (const float*)d_in[14];
  const float* proj_b = (const float*)d_in[15];
  const float* ln_g = (const float*)d_in[16];
  const float* ln_b = (const float*)d_in[17];
  float* out = (float*)d_out;  // fp32: p [N*256] then batch [N]

  const size_t NH = (size_t)N_NODES * HID;
  const size_t WSZ = (size_t)HID * HID;

  // ---- workspace layout (~270 MB) ----
  char* w = (char*)d_ws;
  ushortT* h = (ushortT*)w;      w += NH * 2;
  ushortT* x1 = (ushortT*)w;     w += NH * 2;
  ushortT* agg = (ushortT*)w;    w += NH * 2;
  float* p = (float*)w;          w += NH * 4;
  ushortT* lin1t = (ushortT*)w;  w += 6 * WSZ * 2;
  ushortT* lin2t = (ushortT*)w;  w += 6 * WSZ * 2;
  ushortT* lint = (ushortT*)w;   w += 6 * WSZ * 2;
  ushortT* w2t = (ushortT*)w;    w += 6 * WSZ * 2;
  ushortT* projt = (ushortT*)w;  w += WSZ * 2;
  ushortT* w1t = (ushortT*)w;    w += 6 * (size_t)HID * 64 * 2;
  ushortT* tables = (ushortT*)w; w += 6 * (size_t)NT_PTS * HID * 2;
  int* counts = (int*)w;         w += (size_t)N_NODES * 4;
  int* cursor = (int*)w;         w += (size_t)N_NODES * 4;
  int* row_start = (int*)w;      w += (size_t)(N_NODES + 64) * 4;
  int* perm = (int*)w;           w += (size_t)N_EDGES * 4;
  float4* csr_meta = (float4*)w; w += (size_t)N_EDGES * 16;
  int* bsum = (int*)w;           w += (size_t)128 * 4;

  // ---- CSR build ----
  hipMemsetAsync(counts, 0, (size_t)N_NODES * 4, stream);
  hist_k<<<(N_EDGES + 255) / 256, 256, 0, stream>>>(ei, counts);
  scanA_k<<<SCAN_NB, 256, 0, stream>>>(counts, bsum);
  scanB_k<<<1, 128, 0, stream>>>(bsum, row_start);
  scanC_k<<<SCAN_NB, 256, 0, stream>>>(counts, bsum, row_start, cursor);
  perm_k<<<(N_EDGES + 255) / 256, 256, 0, stream>>>(ei, cursor, perm);
  edge_prep_k<<<(N_EDGES + 255) / 256, 256, 0, stream>>>(ei, pos, perm, csr_meta);

  // ---- weight prep ----
  wconv_k<<<6 * 16, 256, 0, stream>>>(lin1_w, lin1t);
  wconv_k<<<6 * 16, 256, 0, stream>>>(lin2_w, lin2t);
  wconv_k<<<6 * 16, 256, 0, stream>>>(lin_w, lint);
  wconv_k<<<6 * 16, 256, 0, stream>>>(mlp_w2, w2t);
  wconv_k<<<16, 256, 0, stream>>>(proj_w, projt);
  w1conv_k<<<6, 256, 0, stream>>>(mlp_w1, w1t);

  // ---- filter tables (all 6 layers, one dispatch) ----
  table_k<<<6 * TB_BLOCKS, 256, 0, stream>>>(w1t, mlp_b1, w2t, mlp_b2, tables);

  embed_k<<<(N_NODES * HID + 255) / 256, 256, 0, stream>>>(z, emb, h);

  const int MB64 = (N_NODES + 63) / 64;
  mgemm<<<MB64, 256, 0, stream>>>(h, lin1t, x1, N_NODES);  // x1_0
  for (int l = 0; l < NLAYERS; ++l) {
    const size_t oW = (size_t)l * WSZ;
    const size_t o1 = (size_t)l * HID;
    gather2_k<<<(N_NODES + 3) / 4, 256, 0, stream>>>(
        row_start, csr_meta, x1,
        tables + (size_t)l * NT_PTS * HID, agg);
    if (l < NLAYERS - 1) {
      mgemm3<0><<<MB64, 512, 0, stream>>>(agg, lin2t + oW, lin2_b + o1,
                                          lint + oW, lin_b + o1, h,
                                          lin1t + (size_t)(l + 1) * WSZ, nullptr,
                                          x1, nullptr, N_NODES);
    } else {
      mgemm3<1><<<MB64, 512, 0, stream>>>(agg, lin2t + oW, lin2_b + o1,
                                          lint + oW, lin_b + o1, h,
                                          projt, proj_b, nullptr, p, N_NODES);
    }
  }
  ln_k<<<N_NODES, 256, 0, stream>>>(p, ln_g, ln_b, out);
  tail_k<<<(N_NODES + 255) / 256, 256, 0, stream>>>(batch, out + NH);
}

// Round 16
// 1350.849 us; speedup vs baseline: 1.3041x; 1.0793x over previous
//
#include <hip/hip_runtime.h>

#define N_NODES 100000
#define N_EDGES 320000
#define HID 256
#define NGAUSS 50
#define NLAYERS 6
#define SCAN_NB 98   // ceil(N_NODES/1024)
#define NT_PTS 1025  // filter table points over [0,8], h=1/128 (L2-resident: 525KB/layer)
#define TB_BLOCKS 17 // ceil(1025/64)
#define H_STEP 0.0078125f
#define INV_H 128.0f

typedef unsigned short ushortT;
typedef unsigned int uintT;
typedef __attribute__((ext_vector_type(8))) short bf16x8;  // 8 bf16 = 4 VGPR
typedef __attribute__((ext_vector_type(4))) float f32x4;
typedef __attribute__((ext_vector_type(2))) __bf16 bf16v2;

// ---------------------------------------------------------------------------
// ShiftedSoftplus via native exp2/log2:
//   softplus(x) - ln2 = max(x,0) + ln2*log2(1 + exp2(-|x|*log2e)) - ln2
__device__ __forceinline__ float sspf(float x) {
  float e = exp2f(-fabsf(x) * 1.44269504088896340736f);
  float l = __log2f(1.0f + e);
  return fmaf(0.69314718055994530942f, l,
              fmaxf(x, 0.0f) - 0.69314718055994530942f);
}

__device__ __forceinline__ float bf2f(ushortT u) {
  union { uintT i; float f; } c;
  c.i = ((uintT)u) << 16;
  return c.f;
}

// unpack low/high bf16 of a packed dword (1 VALU op each; reinterpret is free)
__device__ __forceinline__ float bflo(uintT u) {
  union { uintT i; float f; } c;
  c.i = u << 16;
  return c.f;
}
__device__ __forceinline__ float bfhi(uintT u) {
  union { uintT i; float f; } c;
  c.i = u & 0xFFFF0000u;
  return c.f;
}

// native bf16 converts (RNE) -> v_cvt_pk_bf16_f32 on gfx950
__device__ __forceinline__ ushortT f2bf(float f) {
  union { __bf16 b; ushortT u; } c;
  c.b = (__bf16)f;
  return c.u;
}
__device__ __forceinline__ uintT f2bf2(float lo, float hi) {
  union { bf16v2 v; uintT u; } c;
  c.v = (bf16v2){(__bf16)lo, (__bf16)hi};
  return c.u;
}

// ---------------------------------------------------------------------------
// MFMA K-loops over K=256. A in LDS bf16 (row stride 264), Bt row-major [N,K].
//   A-frag: lane(16q+m) holds A[m][8q..8q+8); C/D: lane(16q+c) reg r -> row 4q+r, col c
__device__ __forceinline__ void mfma_kloop(const ushortT* As, const ushortT* Bt,
                                           f32x4 (&acc)[4][4], int lm, int q) {
#pragma unroll
  for (int k = 0; k < 256; k += 32) {
    bf16x8 a[4], b[4];
#pragma unroll
    for (int rt = 0; rt < 4; ++rt)
      a[rt] = *(const bf16x8*)&As[(rt * 16 + lm) * 264 + k + 8 * q];
#pragma unroll
    for (int ct = 0; ct < 4; ++ct)
      b[ct] = *(const bf16x8*)(Bt + (size_t)(ct * 16 + lm) * HID + k + 8 * q);
#pragma unroll
    for (int rt = 0; rt < 4; ++rt)
#pragma unroll
      for (int ct = 0; ct < 4; ++ct)
        acc[rt][ct] = __builtin_amdgcn_mfma_f32_16x16x32_bf16(a[rt], b[ct], acc[rt][ct], 0, 0, 0);
  }
}

// 8-wave variant, 32-col stripe per wave, acc[4][2] (measured-best plain form:
// per-k-step loads; the compiler's sunk-load schedule beat forced preloads).
__device__ __forceinline__ void mfma_kloop32(const ushortT* As, const ushortT* Bt,
                                             f32x4 (&acc)[4][2], int c0, int lm, int q) {
#pragma unroll
  for (int k = 0; k < 256; k += 32) {
    bf16x8 b[2];
#pragma unroll
    for (int ct = 0; ct < 2; ++ct)
      b[ct] = *(const bf16x8*)(Bt + (size_t)(c0 + ct * 16 + lm) * HID + k + 8 * q);
#pragma unroll
    for (int rt = 0; rt < 4; ++rt) {
      bf16x8 a = *(const bf16x8*)&As[(rt * 16 + lm) * 264 + k + 8 * q];
#pragma unroll
      for (int ct = 0; ct < 2; ++ct)
        acc[rt][ct] = __builtin_amdgcn_mfma_f32_16x16x32_bf16(a, b[ct], acc[rt][ct], 0, 0, 0);
    }
  }
}

__device__ __forceinline__ void stage_tile(const ushortT* __restrict__ A,
                                           ushortT* As, int m0, int M, int tid) {
#pragma unroll
  for (int i = 0; i < 8; ++i) {
    int idx = i * 256 + tid;
    int r = idx >> 5, ch = idx & 31;
    int m = m0 + r;
    uint4 u = make_uint4(0, 0, 0, 0);
    if (m < M) u = *(const uint4*)(A + (size_t)m * HID + ch * 8);
    *(uint4*)&As[r * 264 + ch * 8] = u;
  }
}

// acc tile -> LDS (bf16, A layout), 4-wave version
__device__ __forceinline__ void acc_to_lds(ushortT* As, const f32x4 (&acc)[4][4],
                                           int c0, int lm, int q) {
#pragma unroll
  for (int ct = 0; ct < 4; ++ct) {
    const int col = c0 + ct * 16 + lm;
#pragma unroll
    for (int rt = 0; rt < 4; ++rt) {
      const int row = rt * 16 + q * 4;
      uintT u01 = f2bf2(acc[rt][ct][0], acc[rt][ct][1]);
      uintT u23 = f2bf2(acc[rt][ct][2], acc[rt][ct][3]);
      As[(row + 0) * 264 + col] = (ushortT)u01;
      As[(row + 1) * 264 + col] = (ushortT)(u01 >> 16);
      As[(row + 2) * 264 + col] = (ushortT)u23;
      As[(row + 3) * 264 + col] = (ushortT)(u23 >> 16);
    }
  }
}

// coalesced LDS tile -> global (row-contiguous uint4), 256-thread version
__device__ __forceinline__ void store_tile64(const ushortT* As,
                                             ushortT* __restrict__ dst,
                                             int m0, int M, int tid) {
#pragma unroll
  for (int i = 0; i < 8; ++i) {
    int idx = i * 256 + tid;
    int r = idx >> 5, ch = idx & 31;
    int m = m0 + r;
    if (m < M)
      *(uint4*)(dst + (size_t)m * HID + ch * 8) = *(const uint4*)&As[r * 264 + ch * 8];
  }
}

// ---------------------------------------------------------------------------
// MFMA node GEMM (used once for x1_0): C[M,256] = A[M,256] @ W[256,256], bf16 out
__global__ __launch_bounds__(256) void mgemm(const ushortT* __restrict__ A,
                                             const ushortT* __restrict__ Bt,
                                             ushortT* __restrict__ Cbf, int M) {
  __shared__ ushortT As[64 * 264];
  const int tid = threadIdx.x;
  const int m0 = blockIdx.x * 64;
  stage_tile(A, As, m0, M, tid);
  __syncthreads();

  const int lane = tid & 63;
  const int lm = lane & 15, q = lane >> 4;
  const int c0 = (tid >> 6) * 64;

  f32x4 acc[4][4];
#pragma unroll
  for (int rt = 0; rt < 4; ++rt)
#pragma unroll
    for (int ct = 0; ct < 4; ++ct) acc[rt][ct] = (f32x4){0.f, 0.f, 0.f, 0.f};

  mfma_kloop(As, Bt + (size_t)c0 * HID, acc, lm, q);
  __syncthreads();  // all waves done reading As
  acc_to_lds(As, acc, c0, lm, q);
  __syncthreads();
  store_tile64(As, Cbf, m0, M, tid);
}

// ---------------------------------------------------------------------------
// Fused interaction tail + next-layer head (3 chained K=256 GEMMs, LDS-resident).
// 512 threads / 8 waves; 64-row tile; each wave owns a 32-col stripe, acc[4][2].
//   x2 = ssp(agg @ B1t + b1)
//   hn = h + x2 @ B2t + b2            (write h)
//   LAST=0: x1out = hn @ B3t (bf16)
//   LAST=1: out = SiLU(LayerNorm(hn @ B3t + b3)) fp32 -- LN fused in-block
//           (LDS reused as fp32 [32][260] tile, two halves; fp32 end-to-end)
template <int LAST>
__global__ __launch_bounds__(512, 2) void mgemm3(const ushortT* __restrict__ A,
                                                 const ushortT* __restrict__ B1t,
                                                 const float* __restrict__ b1v,
                                                 const ushortT* __restrict__ B2t,
                                                 const float* __restrict__ b2v,
                                                 ushortT* __restrict__ h,
                                                 const ushortT* __restrict__ B3t,
                                                 const float* __restrict__ b3v,
                                                 ushortT* __restrict__ x1out,
                                                 const float* __restrict__ lng,
                                                 const float* __restrict__ lnb,
                                                 float* __restrict__ outp, int M) {
  __shared__ ushortT As[64 * 264];  // 33792 B
  const int tid = threadIdx.x;
  const int m0 = blockIdx.x * 64;

  // stage 64x256 tile: 2048 uint4 over 512 threads
#pragma unroll
  for (int i = 0; i < 4; ++i) {
    int idx = i * 512 + tid;
    int r = idx >> 5, ch = idx & 31;
    int m = m0 + r;
    uint4 u = make_uint4(0, 0, 0, 0);
    if (m < M) u = *(const uint4*)(A + (size_t)m * HID + ch * 8);
    *(uint4*)&As[r * 264 + ch * 8] = u;
  }
  __syncthreads();

  const int lane = tid & 63;
  const int lm = lane & 15, q = lane >> 4;
  const int c0 = (tid >> 6) * 32;  // wave's 32-col stripe

  f32x4 acc[4][2];
#pragma unroll
  for (int rt = 0; rt < 4; ++rt)
#pragma unroll
    for (int ct = 0; ct < 2; ++ct) acc[rt][ct] = (f32x4){0.f, 0.f, 0.f, 0.f};
  mfma_kloop32(As, B1t, acc, c0, lm, q);
  __syncthreads();  // all waves done reading As

  // epi1: x2 = ssp(acc + b1) -> As
#pragma unroll
  for (int ct = 0; ct < 2; ++ct) {
    const int col = c0 + ct * 16 + lm;
    const float bv = b1v[col];
#pragma unroll
    for (int rt = 0; rt < 4; ++rt) {
      const int row = rt * 16 + q * 4;
      float v0 = sspf(acc[rt][ct][0] + bv);
      float v1 = sspf(acc[rt][ct][1] + bv);
      float v2 = sspf(acc[rt][ct][2] + bv);
      float v3 = sspf(acc[rt][ct][3] + bv);
      uintT u01 = f2bf2(v0, v1), u23 = f2bf2(v2, v3);
      As[(row + 0) * 264 + col] = (ushortT)u01;
      As[(row + 1) * 264 + col] = (ushortT)(u01 >> 16);
      As[(row + 2) * 264 + col] = (ushortT)u23;
      As[(row + 3) * 264 + col] = (ushortT)(u23 >> 16);
    }
  }
  __syncthreads();

#pragma unroll
  for (int rt = 0; rt < 4; ++rt)
#pragma unroll
    for (int ct = 0; ct < 2; ++ct) acc[rt][ct] = (f32x4){0.f, 0.f, 0.f, 0.f};
  mfma_kloop32(As, B2t, acc, c0, lm, q);
  __syncthreads();  // all waves done reading As

  // epi2: hn = acc + b2 + h_old -> h (scattered) and As
#pragma unroll
  for (int ct = 0; ct < 2; ++ct) {
    const int col = c0 + ct * 16 + lm;
    const float bv = b2v[col];
#pragma unroll
    for (int rt = 0; rt < 4; ++rt) {
      const int mb = m0 + rt * 16 + q * 4;
      const int row = rt * 16 + q * 4;
      float v[4];
#pragma unroll
      for (int r = 0; r < 4; ++r) {
        float res = (mb + r < M) ? bf2f(h[(size_t)(mb + r) * HID + col]) : 0.0f;
        v[r] = acc[rt][ct][r] + bv + res;
      }
      uintT u01 = f2bf2(v[0], v[1]), u23 = f2bf2(v[2], v[3]);
      As[(row + 0) * 264 + col] = (ushortT)u01;
      As[(row + 1) * 264 + col] = (ushortT)(u01 >> 16);
      As[(row + 2) * 264 + col] = (ushortT)u23;
      As[(row + 3) * 264 + col] = (ushortT)(u23 >> 16);
      if (mb + 0 < M) h[(size_t)(mb + 0) * HID + col] = (ushortT)u01;
      if (mb + 1 < M) h[(size_t)(mb + 1) * HID + col] = (ushortT)(u01 >> 16);
      if (mb + 2 < M) h[(size_t)(mb + 2) * HID + col] = (ushortT)u23;
      if (mb + 3 < M) h[(size_t)(mb + 3) * HID + col] = (ushortT)(u23 >> 16);
    }
  }
  __syncthreads();

#pragma unroll
  for (int rt = 0; rt < 4; ++rt)
#pragma unroll
    for (int ct = 0; ct < 2; ++ct) acc[rt][ct] = (f32x4){0.f, 0.f, 0.f, 0.f};
  mfma_kloop32(As, B3t, acc, c0, lm, q);

  if constexpr (LAST) {
    // fused LayerNorm + SiLU, fp32 end-to-end via LDS (two 32-row halves)
    __syncthreads();  // all waves done reading As (kloop3)
    float* Pf = (float*)As;
    const int PSTR = 260;  // 32*260*4 = 33280 B <= 33792 B
    const int wv = tid >> 6;
#pragma unroll
    for (int half = 0; half < 2; ++half) {
      // write this half's rows (rt = 2*half .. 2*half+1) + bias into LDS fp32
#pragma unroll
      for (int ct = 0; ct < 2; ++ct) {
        const int col = c0 + ct * 16 + lm;
        const float bv = b3v[col];
#pragma unroll
        for (int rtl = 0; rtl < 2; ++rtl) {
          const int rt = half * 2 + rtl;
          const int lrow = rtl * 16 + q * 4;
#pragma unroll
          for (int r = 0; r < 4; ++r)
            Pf[(lrow + r) * PSTR + col] = acc[rt][ct][r] + bv;
        }
      }
      __syncthreads();
      // LN+SiLU: wave wv owns rows wv*4..wv*4+3 of this half; lane holds 4 cols
#pragma unroll
      for (int rr = 0; rr < 4; ++rr) {
        const int lrow = wv * 4 + rr;
        const int grow = m0 + half * 32 + lrow;
        float4 v4 = *(float4*)&Pf[lrow * PSTR + lane * 4];
        float s = v4.x + v4.y + v4.z + v4.w;
#pragma unroll
        for (int m = 32; m; m >>= 1) s += __shfl_xor(s, m, 64);
        float mu = s * (1.0f / 256.0f);
        float d0 = v4.x - mu, d1 = v4.y - mu, d2 = v4.z - mu, d3 = v4.w - mu;
        float qv = d0 * d0 + d1 * d1 + d2 * d2 + d3 * d3;
#pragma unroll
        for (int m = 32; m; m >>= 1) qv += __shfl_xor(qv, m, 64);
        float rstd = rsqrtf(qv * (1.0f / 256.0f) + 1e-5f);
        if (grow < M) {
          float4 g4 = *(const float4*)&lng[lane * 4];
          float4 b4 = *(const float4*)&lnb[lane * 4];
          float y0 = d0 * rstd * g4.x + b4.x;
          float y1 = d1 * rstd * g4.y + b4.y;
          float y2 = d2 * rstd * g4.z + b4.z;
          float y3 = d3 * rstd * g4.w + b4.w;
          float4 o;
          o.x = y0 * (1.0f / (1.0f + exp2f(-y0 * 1.44269504088896340736f)));
          o.y = y1 * (1.0f / (1.0f + exp2f(-y1 * 1.44269504088896340736f)));
          o.z = y2 * (1.0f / (1.0f + exp2f(-y2 * 1.44269504088896340736f)));
          o.w = y3 * (1.0f / (1.0f + exp2f(-y3 * 1.44269504088896340736f)));
          *(float4*)&outp[(size_t)grow * HID + lane * 4] = o;
        }
      }
      __syncthreads();  // before next half reuses Pf
    }
  } else {
#pragma unroll
    for (int ct = 0; ct < 2; ++ct) {
      const int col = c0 + ct * 16 + lm;
#pragma unroll
      for (int rt = 0; rt < 4; ++rt) {
        const int mb = m0 + rt * 16 + q * 4;
        uintT u01 = f2bf2(acc[rt][ct][0], acc[rt][ct][1]);
        uintT u23 = f2bf2(acc[rt][ct][2], acc[rt][ct][3]);
        if (mb + 0 < M) x1out[(size_t)(mb + 0) * HID + col] = (ushortT)u01;
        if (mb + 1 < M) x1out[(size_t)(mb + 1) * HID + col] = (ushortT)(u01 >> 16);
        if (mb + 2 < M) x1out[(size_t)(mb + 2) * HID + col] = (ushortT)u23;
        if (mb + 3 < M) x1out[(size_t)(mb + 3) * HID + col] = (ushortT)(u23 >> 16);
      }
    }
  }
}

// ---------------------------------------------------------------------------
// Filter table build: table[l][g][:] = ssp(rbf(g*H_STEP) @ w1t[l] + b1[l]) @ w2t[l] + b2[l]
__global__ __launch_bounds__(256) void table_k(
    const ushortT* __restrict__ w1t_all, const float* __restrict__ b1_all,
    const ushortT* __restrict__ w2t_all, const float* __restrict__ b2_all,
    ushortT* __restrict__ table_all) {
  __shared__ ushortT T[64 * 264];
  ushortT* R = T;  // rbf tile aliases T head; barrier before T write

  const int blk = blockIdx.x;
  const int l = blk / TB_BLOCKS, tb = blk % TB_BLOCKS;
  const ushortT* w1t = w1t_all + (size_t)l * HID * 64;
  const float* b1 = b1_all + (size_t)l * HID;
  const ushortT* w2t = w2t_all + (size_t)l * HID * HID;
  const float* b2 = b2_all + (size_t)l * HID;
  ushortT* table = table_all + (size_t)l * NT_PTS * HID;

  const int tid = threadIdx.x;
  const float delta = 5.0f / 49.0f;
  const float coeff2 = (-0.5f / (delta * delta)) * 1.44269504088896340736f;
#pragma unroll
  for (int i = 0; i < 16; ++i) {
    int idx = i * 256 + tid;
    int e = idx >> 6, k = idx & 63;
    float v = 0.0f;
    if (k < NGAUSS) {
      float dist = (float)(tb * 64 + e) * H_STEP;
      float dd = dist - (float)k * delta;
      v = exp2f(coeff2 * dd * dd);
    }
    R[e * 72 + k] = f2bf(v);
  }
  __syncthreads();

  const int lane = tid & 63;
  const int lm = lane & 15, q = lane >> 4;
  const int c0 = (tid >> 6) * 64;

  // phase 1: t = ssp(R @ w1t + b1), K=64
  {
    f32x4 acc1[4][4];
#pragma unroll
    for (int rt = 0; rt < 4; ++rt)
#pragma unroll
      for (int ct = 0; ct < 4; ++ct) acc1[rt][ct] = (f32x4){0.f, 0.f, 0.f, 0.f};
#pragma unroll
    for (int k = 0; k < 64; k += 32) {
      bf16x8 a[4], b[4];
#pragma unroll
      for (int rt = 0; rt < 4; ++rt)
        a[rt] = *(const bf16x8*)&R[(rt * 16 + lm) * 72 + k + 8 * q];
#pragma unroll
      for (int ct = 0; ct < 4; ++ct)
        b[ct] = *(const bf16x8*)(w1t + (size_t)(c0 + ct * 16 + lm) * 64 + k + 8 * q);
#pragma unroll
      for (int rt = 0; rt < 4; ++rt)
#pragma unroll
        for (int ct = 0; ct < 4; ++ct)
          acc1[rt][ct] = __builtin_amdgcn_mfma_f32_16x16x32_bf16(a[rt], b[ct], acc1[rt][ct], 0, 0, 0);
    }
    __syncthreads();  // done reading R before T (aliased) is written
#pragma unroll
    for (int ct = 0; ct < 4; ++ct) {
      const int col = c0 + ct * 16 + lm;
      const float bv = b1[col];
#pragma unroll
      for (int rt = 0; rt < 4; ++rt) {
        const int row = rt * 16 + q * 4;
        float v0 = sspf(acc1[rt][ct][0] + bv);
        float v1 = sspf(acc1[rt][ct][1] + bv);
        float v2 = sspf(acc1[rt][ct][2] + bv);
        float v3 = sspf(acc1[rt][ct][3] + bv);
        uintT u01 = f2bf2(v0, v1), u23 = f2bf2(v2, v3);
        T[(row + 0) * 264 + col] = (ushortT)u01;
        T[(row + 1) * 264 + col] = (ushortT)(u01 >> 16);
        T[(row + 2) * 264 + col] = (ushortT)u23;
        T[(row + 3) * 264 + col] = (ushortT)(u23 >> 16);
      }
    }
  }
  __syncthreads();

  // phase 2: Wf = t @ w2t + b2, write table rows directly
  f32x4 acc[4][4];
#pragma unroll
  for (int rt = 0; rt < 4; ++rt)
#pragma unroll
    for (int ct = 0; ct < 4; ++ct) acc[rt][ct] = (f32x4){0.f, 0.f, 0.f, 0.f};
  mfma_kloop(T, w2t + (size_t)c0 * HID, acc, lm, q);

#pragma unroll
  for (int ct = 0; ct < 4; ++ct) {
    const int col = c0 + ct * 16 + lm;
    const float bv = b2[col];
#pragma unroll
    for (int rt = 0; rt < 4; ++rt) {
      const int row = rt * 16 + q * 4;
#pragma unroll
      for (int r = 0; r < 4; ++r) {
        int g = tb * 64 + row + r;
        if (g < NT_PTS) table[(size_t)g * HID + col] = f2bf(acc[rt][ct][r] + bv);
      }
    }
  }
}

// ---------------------------------------------------------------------------
// CSR build: histogram -> hierarchical scan -> perm (edge -> CSR slot)
__global__ __launch_bounds__(256) void hist_k(const int* __restrict__ ei,
                                              int* __restrict__ counts) {
  int e = blockIdx.x * 256 + threadIdx.x;
  if (e < N_EDGES) atomicAdd(&counts[ei[N_EDGES + e]], 1);
}

__global__ __launch_bounds__(256) void scanA_k(const int* __restrict__ counts,
                                               int* __restrict__ bsum) {
  const int b = blockIdx.x, tid = threadIdx.x;
  const int base = b * 1024 + tid * 4;
  int s = 0;
  if (base + 3 < N_NODES) {
    int4 v = *(const int4*)(counts + base);
    s = v.x + v.y + v.z + v.w;
  } else {
#pragma unroll
    for (int i = 0; i < 4; ++i) {
      int n = base + i;
      if (n < N_NODES) s += counts[n];
    }
  }
#pragma unroll
  for (int m = 32; m; m >>= 1) s += __shfl_xor(s, m, 64);
  __shared__ int ws[4];
  if ((tid & 63) == 0) ws[tid >> 6] = s;
  __syncthreads();
  if (tid == 0) bsum[b] = ws[0] + ws[1] + ws[2] + ws[3];
}

__global__ __launch_bounds__(128) void scanB_k(int* __restrict__ bsum,
                                               int* __restrict__ row_start) {
  __shared__ int sh[SCAN_NB];
  const int tid = threadIdx.x;
  if (tid < SCAN_NB) sh[tid] = bsum[tid];
  __syncthreads();
  if (tid == 0) {
    int acc = 0;
    for (int i = 0; i < SCAN_NB; ++i) { int t = sh[i]; sh[i] = acc; acc += t; }
    row_start[N_NODES] = acc;
  }
  __syncthreads();
  if (tid < SCAN_NB) bsum[tid] = sh[tid];
}

__global__ __launch_bounds__(256) void scanC_k(const int* __restrict__ counts,
                                               const int* __restrict__ bsum,
                                               int* __restrict__ row_start,
                                               int* __restrict__ cursor) {
  const int b = blockIdx.x, tid = threadIdx.x;
  const int base = b * 1024 + tid * 4;
  int c[4];
  int s = 0;
#pragma unroll
  for (int i = 0; i < 4; ++i) {
    int n = base + i;
    c[i] = (n < N_NODES) ? counts[n] : 0;
    s += c[i];
  }
  __shared__ int sc[256];
  sc[tid] = s;
  __syncthreads();
  int acc = s;
  for (int off = 1; off < 256; off <<= 1) {
    int v = (tid >= off) ? sc[tid - off] : 0;
    __syncthreads();
    acc += v;
    sc[tid] = acc;
    __syncthreads();
  }
  int off0 = acc - s + bsum[b];
#pragma unroll
  for (int i = 0; i < 4; ++i) {
    int n = base + i;
    if (n < N_NODES) {
      row_start[n] = off0;
      cursor[n] = off0;
      off0 += c[i];
    }
  }
}

__global__ __launch_bounds__(256) void perm_k(const int* __restrict__ ei,
                                              int* __restrict__ cursor,
                                              int* __restrict__ perm) {
  int e = blockIdx.x * 256 + threadIdx.x;
  if (e < N_EDGES) perm[e] = atomicAdd(&cursor[ei[N_EDGES + e]], 1);
}

// edge_prep: per edge compute packed meta {src_bits, fi, cs, 0} in CSR slot order
__global__ __launch_bounds__(256) void edge_prep_k(const int* __restrict__ ei,
                                                   const float* __restrict__ pos,
                                                   const int* __restrict__ perm,
                                                   float4* __restrict__ csr_meta) {
  int e = blockIdx.x * 256 + threadIdx.x;
  if (e >= N_EDGES) return;
  int s = ei[e], d = ei[N_EDGES + e];
  float dx = pos[s * 3 + 0] - pos[d * 3 + 0];
  float dy = pos[s * 3 + 1] - pos[d * 3 + 1];
  float dz = pos[s * 3 + 2] - pos[d * 3 + 2];
  float dist = sqrtf(fmaf(dx, dx, fmaf(dy, dy, dz * dz)) + 1e-12f);
  union { int i; float f; } sb;
  sb.i = s;
  float4 m;
  m.x = sb.f;
  m.y = fminf(dist * INV_H, 1023.999f);
  m.z = 0.5f * (cosf(dist * (3.14159265358979323846f / 5.0f)) + 1.0f);
  m.w = 0.0f;
  csr_meta[perm[e]] = m;
}

// fused gather: agg[n] = sum over CSR edges of x1[src] * lerp(table, dist) * C
// 2-way unrolled edge loop: doubles in-flight loads per wave (latency-bound,
// avg 3.2 edges/node). Accumulation order preserved (j then j+1).
__global__ __launch_bounds__(256) void gather2_k(const int* __restrict__ row_start,
                                                 const float4* __restrict__ csr_meta,
                                                 const ushortT* __restrict__ x1,
                                                 const ushortT* __restrict__ table,
                                                 ushortT* __restrict__ agg) {
  int node = blockIdx.x * 4 + (threadIdx.x >> 6);
  int lane = threadIdx.x & 63;
  if (node >= N_NODES) return;
  int a = row_start[node], b = row_start[node + 1];
  const int co = lane * 4;
  float s0 = 0.f, s1 = 0.f, s2 = 0.f, s3 = 0.f;
  int j = a;
  for (; j + 1 < b; j += 2) {
    float4 mtA = csr_meta[j];
    float4 mtB = csr_meta[j + 1];
    union { float f; int i; } sa, sb2;
    sa.f = mtA.x;
    sb2.f = mtB.x;
    int iA = (int)mtA.y, iB = (int)mtB.y;
    float tA = mtA.y - (float)iA, tB = mtB.y - (float)iB;
    const ushortT* trowA = table + (size_t)iA * HID + co;
    const ushortT* trowB = table + (size_t)iB * HID + co;
    uint2 taA = *(const uint2*)trowA;
    uint2 tbA = *(const uint2*)(trowA + HID);
    uint2 xvA = *(const uint2*)(x1 + (size_t)sa.i * HID + co);
    uint2 taB = *(const uint2*)trowB;
    uint2 tbB = *(const uint2*)(trowB + HID);
    uint2 xvB = *(const uint2*)(x1 + (size_t)sb2.i * HID + co);
    // edge j
    {
      float cs = mtA.z;
      float a0 = bflo(taA.x), a1 = bfhi(taA.x), a2 = bflo(taA.y), a3 = bfhi(taA.y);
      float b0 = bflo(tbA.x), b1 = bfhi(tbA.x), b2 = bflo(tbA.y), b3 = bfhi(tbA.y);
      float w0 = fmaf(tA, b0 - a0, a0);
      float w1 = fmaf(tA, b1 - a1, a1);
      float w2 = fmaf(tA, b2 - a2, a2);
      float w3 = fmaf(tA, b3 - a3, a3);
      s0 = fmaf(bflo(xvA.x) * w0, cs, s0);
      s1 = fmaf(bfhi(xvA.x) * w1, cs, s1);
      s2 = fmaf(bflo(xvA.y) * w2, cs, s2);
      s3 = fmaf(bfhi(xvA.y) * w3, cs, s3);
    }
    // edge j+1
    {
      float cs = mtB.z;
      float a0 = bflo(taB.x), a1 = bfhi(taB.x), a2 = bflo(taB.y), a3 = bfhi(taB.y);
      float b0 = bflo(tbB.x), b1 = bfhi(tbB.x), b2 = bflo(tbB.y), b3 = bfhi(tbB.y);
      float w0 = fmaf(tB, b0 - a0, a0);
      float w1 = fmaf(tB, b1 - a1, a1);
      float w2 = fmaf(tB, b2 - a2, a2);
      float w3 = fmaf(tB, b3 - a3, a3);
      s0 = fmaf(bflo(xvB.x) * w0, cs, s0);
      s1 = fmaf(bfhi(xvB.x) * w1, cs, s1);
      s2 = fmaf(bflo(xvB.y) * w2, cs, s2);
      s3 = fmaf(bfhi(xvB.y) * w3, cs, s3);
    }
  }
  if (j < b) {
    float4 mt = csr_meta[j];
    union { float f; int i; } sb;
    sb.f = mt.x;
    float fi = mt.y;
    float cs = mt.z;
    int i = (int)fi;
    float t = fi - (float)i;
    const ushortT* trow = table + (size_t)i * HID + co;
    uint2 ta = *(const uint2*)trow;
    uint2 tb = *(const uint2*)(trow + HID);
    uint2 xv = *(const uint2*)(x1 + (size_t)sb.i * HID + co);
    float a0 = bflo(ta.x), a1 = bfhi(ta.x), a2 = bflo(ta.y), a3 = bfhi(ta.y);
    float b0 = bflo(tb.x), b1 = bfhi(tb.x), b2 = bflo(tb.y), b3 = bfhi(tb.y);
    float w0 = fmaf(t, b0 - a0, a0);
    float w1 = fmaf(t, b1 - a1, a1);
    float w2 = fmaf(t, b2 - a2, a2);
    float w3 = fmaf(t, b3 - a3, a3);
    s0 = fmaf(bflo(xv.x) * w0, cs, s0);
    s1 = fmaf(bfhi(xv.x) * w1, cs, s1);
    s2 = fmaf(bflo(xv.y) * w2, cs, s2);
    s3 = fmaf(bfhi(xv.y) * w3, cs, s3);
  }
  uint2 o;
  o.x = f2bf2(s0, s1);
  o.y = f2bf2(s2, s3);
  *(uint2*)(agg + (size_t)node * HID + co) = o;
}

// ---------------------------------------------------------------------------
// Weight prep: fp32 W[K,256] -> bf16 Wt[256,K], square 256x256 matrices
__global__ __launch_bounds__(256) void wconv_k(const float* __restrict__ src,
                                               ushortT* __restrict__ dst) {
  __shared__ float tile[64][65];
  const int b = blockIdx.x;
  const int mat = b >> 4, t = b & 15;
  const int tr = (t >> 2) * 64, tc = (t & 3) * 64;
  const float* S = src + (size_t)mat * HID * HID;
  ushortT* D = dst + (size_t)mat * HID * HID;
  const int tid = threadIdx.x;
#pragma unroll
  for (int i = 0; i < 16; ++i) {
    int idx = i * 256 + tid;
    int r = idx >> 6, c = idx & 63;
    tile[r][c] = S[(size_t)(tr + r) * HID + tc + c];
  }
  __syncthreads();
#pragma unroll
  for (int i = 0; i < 16; ++i) {
    int idx = i * 256 + tid;
    int n = idx >> 6, k = idx & 63;
    D[(size_t)(tc + n) * HID + tr + k] = f2bf(tile[k][n]);
  }
}

// mlp_w1 [L][50][256] fp32 -> w1t [L][256][64] bf16 (k padded with zeros)
__global__ __launch_bounds__(256) void w1conv_k(const float* __restrict__ src,
                                                ushortT* __restrict__ dst) {
  const int l = blockIdx.x;
  const int n = threadIdx.x;
  const float* S = src + (size_t)l * NGAUSS * HID;
  ushortT* D = dst + (size_t)l * HID * 64;
  for (int k = 0; k < 64; ++k) {
    float v = (k < NGAUSS) ? S[(size_t)k * HID + n] : 0.0f;
    D[(size_t)n * 64 + k] = f2bf(v);
  }
}

// ---------------------------------------------------------------------------
__global__ __launch_bounds__(256) void embed_k(const int* __restrict__ z,
                                               const float* __restrict__ emb,
                                               ushortT* __restrict__ h) {
  int idx = blockIdx.x * 256 + threadIdx.x;
  if (idx >= N_NODES * HID) return;
  int n = idx >> 8;
  int c = idx & 255;
  h[idx] = f2bf(emb[z[n] * HID + c]);
}

__global__ __launch_bounds__(256) void tail_k(const int* __restrict__ batch,
                                              float* __restrict__ out) {
  int i = blockIdx.x * 256 + threadIdx.x;
  if (i < N_NODES) out[i] = (float)batch[i];
}

// ---------------------------------------------------------------------------
extern "C" void kernel_launch(void* const* d_in, const int* in_sizes, int n_in,
                              void* d_out, int out_size, void* d_ws, size_t ws_size,
                              hipStream_t stream) {
  const int* z = (const int*)d_in[0];
  const float* pos = (const float*)d_in[1];
  const int* batch = (const int*)d_in[2];
  const int* ei = (const int*)d_in[3];
  const float* emb = (const float*)d_in[4];
  const float* mlp_w1 = (const float*)d_in[5];
  const float* mlp_b1 = (const float*)d_in[6];
  const float* mlp_w2 = (const float*)d_in[7];
  const float* mlp_b2 = (const float*)d_in[8];
  const float* lin1_w = (const float*)d_in[9];
  const float* lin2_w = (const float*)d_in[10];
  const float* lin2_b = (const float*)d_in[11];
  const float* lin_w = (const float*)d_in[12];
  const float* lin_b = (const float*)d_in[13];
  const float* proj_w = (const float*)d_in[14];
  const float* proj_b = (const float*)d_in[15];
  const float* ln_g = (const float*)d_in[16];
  const float* ln_b = (const float*)d_in[17];
  float* out = (float*)d_out;  // fp32: p [N*256] then batch [N]

  const size_t NH = (size_t)N_NODES * HID;
  const size_t WSZ = (size_t)HID * HID;

  // ---- workspace layout (~270 MB) ----
  char* w = (char*)d_ws;
  ushortT* h = (ushortT*)w;      w += NH * 2;
  ushortT* x1 = (ushortT*)w;     w += NH * 2;
  ushortT* agg = (ushortT*)w;    w += NH * 2;
  ushortT* lin1t = (ushortT*)w;  w += 6 * WSZ * 2;
  ushortT* lin2t = (ushortT*)w;  w += 6 * WSZ * 2;
  ushortT* lint = (ushortT*)w;   w += 6 * WSZ * 2;
  ushortT* w2t = (ushortT*)w;    w += 6 * WSZ * 2;
  ushortT* projt = (ushortT*)w;  w += WSZ * 2;
  ushortT* w1t = (ushortT*)w;    w += 6 * (size_t)HID * 64 * 2;
  ushortT* tables = (ushortT*)w; w += 6 * (size_t)NT_PTS * HID * 2;
  int* counts = (int*)w;         w += (size_t)N_NODES * 4;
  int* cursor = (int*)w;         w += (size_t)N_NODES * 4;
  int* row_start = (int*)w;      w += (size_t)(N_NODES + 64) * 4;
  int* perm = (int*)w;           w += (size_t)N_EDGES * 4;
  float4* csr_meta = (float4*)w; w += (size_t)N_EDGES * 16;
  int* bsum = (int*)w;           w += (size_t)128 * 4;

  // ---- CSR build ----
  hipMemsetAsync(counts, 0, (size_t)N_NODES * 4, stream);
  hist_k<<<(N_EDGES + 255) / 256, 256, 0, stream>>>(ei, counts);
  scanA_k<<<SCAN_NB, 256, 0, stream>>>(counts, bsum);
  scanB_k<<<1, 128, 0, stream>>>(bsum, row_start);
  scanC_k<<<SCAN_NB, 256, 0, stream>>>(counts, bsum, row_start, cursor);
  perm_k<<<(N_EDGES + 255) / 256, 256, 0, stream>>>(ei, cursor, perm);
  edge_prep_k<<<(N_EDGES + 255) / 256, 256, 0, stream>>>(ei, pos, perm, csr_meta);

  // ---- weight prep ----
  wconv_k<<<6 * 16, 256, 0, stream>>>(lin1_w, lin1t);
  wconv_k<<<6 * 16, 256, 0, stream>>>(lin2_w, lin2t);
  wconv_k<<<6 * 16, 256, 0, stream>>>(lin_w, lint);
  wconv_k<<<6 * 16, 256, 0, stream>>>(mlp_w2, w2t);
  wconv_k<<<16, 256, 0, stream>>>(proj_w, projt);
  w1conv_k<<<6, 256, 0, stream>>>(mlp_w1, w1t);

  // ---- filter tables (all 6 layers, one dispatch) ----
  table_k<<<6 * TB_BLOCKS, 256, 0, stream>>>(w1t, mlp_b1, w2t, mlp_b2, tables);

  embed_k<<<(N_NODES * HID + 255) / 256, 256, 0, stream>>>(z, emb, h);

  const int MB64 = (N_NODES + 63) / 64;
  mgemm<<<MB64, 256, 0, stream>>>(h, lin1t, x1, N_NODES);  // x1_0
  for (int l = 0; l < NLAYERS; ++l) {
    const size_t oW = (size_t)l * WSZ;
    const size_t o1 = (size_t)l * HID;
    gather2_k<<<(N_NODES + 3) / 4, 256, 0, stream>>>(
        row_start, csr_meta, x1,
        tables + (size_t)l * NT_PTS * HID, agg);
    if (l < NLAYERS - 1) {
      mgemm3<0><<<MB64, 512, 0, stream>>>(agg, lin2t + oW, lin2_b + o1,
                                          lint + oW, lin_b + o1, h,
                                          lin1t + (size_t)(l + 1) * WSZ, nullptr,
                                          x1, nullptr, nullptr, nullptr, N_NODES);
    } else {
      mgemm3<1><<<MB64, 512, 0, stream>>>(agg, lin2t + oW, lin2_b + o1,
                                          lint + oW, lin_b + o1, h,
                                          projt, proj_b,
                                          nullptr, ln_g, ln_b, out, N_NODES);
    }
  }
  tail_k<<<(N_NODES + 255) / 256, 256, 0, stream>>>(batch, out + NH);
}

// Round 17
// 1331.706 us; speedup vs baseline: 1.3228x; 1.0144x over previous
//
#include <hip/hip_runtime.h>

#define N_NODES 100000
#define N_EDGES 320000
#define HID 256
#define NGAUSS 50
#define NLAYERS 6
#define SCAN_NB 98   // ceil(N_NODES/1024)
#define NT_PTS 2049  // filter table points over [0,8], h=1/256, nearest-neighbor
#define TB_BLOCKS 33 // ceil(2049/64)
#define H_STEP 0.00390625f
#define INV_H 256.0f

typedef unsigned short ushortT;
typedef unsigned int uintT;
typedef __attribute__((ext_vector_type(8))) short bf16x8;  // 8 bf16 = 4 VGPR
typedef __attribute__((ext_vector_type(4))) float f32x4;
typedef __attribute__((ext_vector_type(2))) __bf16 bf16v2;

// ---------------------------------------------------------------------------
// ShiftedSoftplus via native exp2/log2:
//   softplus(x) - ln2 = max(x,0) + ln2*log2(1 + exp2(-|x|*log2e)) - ln2
__device__ __forceinline__ float sspf(float x) {
  float e = exp2f(-fabsf(x) * 1.44269504088896340736f);
  float l = __log2f(1.0f + e);
  return fmaf(0.69314718055994530942f, l,
              fmaxf(x, 0.0f) - 0.69314718055994530942f);
}

__device__ __forceinline__ float bf2f(ushortT u) {
  union { uintT i; float f; } c;
  c.i = ((uintT)u) << 16;
  return c.f;
}

// unpack low/high bf16 of a packed dword (1 VALU op each; reinterpret is free)
__device__ __forceinline__ float bflo(uintT u) {
  union { uintT i; float f; } c;
  c.i = u << 16;
  return c.f;
}
__device__ __forceinline__ float bfhi(uintT u) {
  union { uintT i; float f; } c;
  c.i = u & 0xFFFF0000u;
  return c.f;
}

// native bf16 converts (RNE) -> v_cvt_pk_bf16_f32 on gfx950
__device__ __forceinline__ ushortT f2bf(float f) {
  union { __bf16 b; ushortT u; } c;
  c.b = (__bf16)f;
  return c.u;
}
__device__ __forceinline__ uintT f2bf2(float lo, float hi) {
  union { bf16v2 v; uintT u; } c;
  c.v = (bf16v2){(__bf16)lo, (__bf16)hi};
  return c.u;
}

// ---------------------------------------------------------------------------
// MFMA K-loops over K=256. A in LDS bf16 (row stride 264), Bt row-major [N,K].
//   A-frag: lane(16q+m) holds A[m][8q..8q+8); C/D: lane(16q+c) reg r -> row 4q+r, col c
__device__ __forceinline__ void mfma_kloop(const ushortT* As, const ushortT* Bt,
                                           f32x4 (&acc)[4][4], int lm, int q) {
#pragma unroll
  for (int k = 0; k < 256; k += 32) {
    bf16x8 a[4], b[4];
#pragma unroll
    for (int rt = 0; rt < 4; ++rt)
      a[rt] = *(const bf16x8*)&As[(rt * 16 + lm) * 264 + k + 8 * q];
#pragma unroll
    for (int ct = 0; ct < 4; ++ct)
      b[ct] = *(const bf16x8*)(Bt + (size_t)(ct * 16 + lm) * HID + k + 8 * q);
#pragma unroll
    for (int rt = 0; rt < 4; ++rt)
#pragma unroll
      for (int ct = 0; ct < 4; ++ct)
        acc[rt][ct] = __builtin_amdgcn_mfma_f32_16x16x32_bf16(a[rt], b[ct], acc[rt][ct], 0, 0, 0);
  }
}

// 8-wave variant, 32-col stripe per wave, acc[4][2] (measured-best plain form:
// per-k-step loads; the compiler's sunk-load schedule beat forced preloads).
__device__ __forceinline__ void mfma_kloop32(const ushortT* As, const ushortT* Bt,
                                             f32x4 (&acc)[4][2], int c0, int lm, int q) {
#pragma unroll
  for (int k = 0; k < 256; k += 32) {
    bf16x8 b[2];
#pragma unroll
    for (int ct = 0; ct < 2; ++ct)
      b[ct] = *(const bf16x8*)(Bt + (size_t)(c0 + ct * 16 + lm) * HID + k + 8 * q);
#pragma unroll
    for (int rt = 0; rt < 4; ++rt) {
      bf16x8 a = *(const bf16x8*)&As[(rt * 16 + lm) * 264 + k + 8 * q];
#pragma unroll
      for (int ct = 0; ct < 2; ++ct)
        acc[rt][ct] = __builtin_amdgcn_mfma_f32_16x16x32_bf16(a, b[ct], acc[rt][ct], 0, 0, 0);
    }
  }
}

__device__ __forceinline__ void stage_tile(const ushortT* __restrict__ A,
                                           ushortT* As, int m0, int M, int tid) {
#pragma unroll
  for (int i = 0; i < 8; ++i) {
    int idx = i * 256 + tid;
    int r = idx >> 5, ch = idx & 31;
    int m = m0 + r;
    uint4 u = make_uint4(0, 0, 0, 0);
    if (m < M) u = *(const uint4*)(A + (size_t)m * HID + ch * 8);
    *(uint4*)&As[r * 264 + ch * 8] = u;
  }
}

// acc tile -> LDS (bf16, A layout), 4-wave version
__device__ __forceinline__ void acc_to_lds(ushortT* As, const f32x4 (&acc)[4][4],
                                           int c0, int lm, int q) {
#pragma unroll
  for (int ct = 0; ct < 4; ++ct) {
    const int col = c0 + ct * 16 + lm;
#pragma unroll
    for (int rt = 0; rt < 4; ++rt) {
      const int row = rt * 16 + q * 4;
      uintT u01 = f2bf2(acc[rt][ct][0], acc[rt][ct][1]);
      uintT u23 = f2bf2(acc[rt][ct][2], acc[rt][ct][3]);
      As[(row + 0) * 264 + col] = (ushortT)u01;
      As[(row + 1) * 264 + col] = (ushortT)(u01 >> 16);
      As[(row + 2) * 264 + col] = (ushortT)u23;
      As[(row + 3) * 264 + col] = (ushortT)(u23 >> 16);
    }
  }
}

// coalesced LDS tile -> global (row-contiguous uint4), 256-thread version
__device__ __forceinline__ void store_tile64(const ushortT* As,
                                             ushortT* __restrict__ dst,
                                             int m0, int M, int tid) {
#pragma unroll
  for (int i = 0; i < 8; ++i) {
    int idx = i * 256 + tid;
    int r = idx >> 5, ch = idx & 31;
    int m = m0 + r;
    if (m < M)
      *(uint4*)(dst + (size_t)m * HID + ch * 8) = *(const uint4*)&As[r * 264 + ch * 8];
  }
}

// ---------------------------------------------------------------------------
// MFMA node GEMM (used once for x1_0): C[M,256] = A[M,256] @ W[256,256], bf16 out
__global__ __launch_bounds__(256) void mgemm(const ushortT* __restrict__ A,
                                             const ushortT* __restrict__ Bt,
                                             ushortT* __restrict__ Cbf, int M) {
  __shared__ ushortT As[64 * 264];
  const int tid = threadIdx.x;
  const int m0 = blockIdx.x * 64;
  stage_tile(A, As, m0, M, tid);
  __syncthreads();

  const int lane = tid & 63;
  const int lm = lane & 15, q = lane >> 4;
  const int c0 = (tid >> 6) * 64;

  f32x4 acc[4][4];
#pragma unroll
  for (int rt = 0; rt < 4; ++rt)
#pragma unroll
    for (int ct = 0; ct < 4; ++ct) acc[rt][ct] = (f32x4){0.f, 0.f, 0.f, 0.f};

  mfma_kloop(As, Bt + (size_t)c0 * HID, acc, lm, q);
  __syncthreads();  // all waves done reading As
  acc_to_lds(As, acc, c0, lm, q);
  __syncthreads();
  store_tile64(As, Cbf, m0, M, tid);
}

// ---------------------------------------------------------------------------
// Fused interaction tail + next-layer head (3 chained K=256 GEMMs, LDS-resident).
// 512 threads / 8 waves; 64-row tile; each wave owns a 32-col stripe, acc[4][2].
//   x2 = ssp(agg @ B1t + b1)
//   hn = h + x2 @ B2t + b2            (write h)
//   LAST=0: x1out = hn @ B3t (bf16)
//   LAST=1: out = SiLU(LayerNorm(hn @ B3t + b3)) fp32 -- LN fused in-block
//           (LDS reused as fp32 [32][260] tile, two halves; fp32 end-to-end)
template <int LAST>
__global__ __launch_bounds__(512, 2) void mgemm3(const ushortT* __restrict__ A,
                                                 const ushortT* __restrict__ B1t,
                                                 const float* __restrict__ b1v,
                                                 const ushortT* __restrict__ B2t,
                                                 const float* __restrict__ b2v,
                                                 ushortT* __restrict__ h,
                                                 const ushortT* __restrict__ B3t,
                                                 const float* __restrict__ b3v,
                                                 ushortT* __restrict__ x1out,
                                                 const float* __restrict__ lng,
                                                 const float* __restrict__ lnb,
                                                 float* __restrict__ outp, int M) {
  __shared__ ushortT As[64 * 264];  // 33792 B
  const int tid = threadIdx.x;
  const int m0 = blockIdx.x * 64;

  // stage 64x256 tile: 2048 uint4 over 512 threads
#pragma unroll
  for (int i = 0; i < 4; ++i) {
    int idx = i * 512 + tid;
    int r = idx >> 5, ch = idx & 31;
    int m = m0 + r;
    uint4 u = make_uint4(0, 0, 0, 0);
    if (m < M) u = *(const uint4*)(A + (size_t)m * HID + ch * 8);
    *(uint4*)&As[r * 264 + ch * 8] = u;
  }
  __syncthreads();

  const int lane = tid & 63;
  const int lm = lane & 15, q = lane >> 4;
  const int c0 = (tid >> 6) * 32;  // wave's 32-col stripe

  f32x4 acc[4][2];
#pragma unroll
  for (int rt = 0; rt < 4; ++rt)
#pragma unroll
    for (int ct = 0; ct < 2; ++ct) acc[rt][ct] = (f32x4){0.f, 0.f, 0.f, 0.f};
  mfma_kloop32(As, B1t, acc, c0, lm, q);
  __syncthreads();  // all waves done reading As

  // epi1: x2 = ssp(acc + b1) -> As
#pragma unroll
  for (int ct = 0; ct < 2; ++ct) {
    const int col = c0 + ct * 16 + lm;
    const float bv = b1v[col];
#pragma unroll
    for (int rt = 0; rt < 4; ++rt) {
      const int row = rt * 16 + q * 4;
      float v0 = sspf(acc[rt][ct][0] + bv);
      float v1 = sspf(acc[rt][ct][1] + bv);
      float v2 = sspf(acc[rt][ct][2] + bv);
      float v3 = sspf(acc[rt][ct][3] + bv);
      uintT u01 = f2bf2(v0, v1), u23 = f2bf2(v2, v3);
      As[(row + 0) * 264 + col] = (ushortT)u01;
      As[(row + 1) * 264 + col] = (ushortT)(u01 >> 16);
      As[(row + 2) * 264 + col] = (ushortT)u23;
      As[(row + 3) * 264 + col] = (ushortT)(u23 >> 16);
    }
  }
  __syncthreads();

#pragma unroll
  for (int rt = 0; rt < 4; ++rt)
#pragma unroll
    for (int ct = 0; ct < 2; ++ct) acc[rt][ct] = (f32x4){0.f, 0.f, 0.f, 0.f};
  mfma_kloop32(As, B2t, acc, c0, lm, q);
  __syncthreads();  // all waves done reading As

  // epi2: hn = acc + b2 + h_old -> h (scattered) and As
#pragma unroll
  for (int ct = 0; ct < 2; ++ct) {
    const int col = c0 + ct * 16 + lm;
    const float bv = b2v[col];
#pragma unroll
    for (int rt = 0; rt < 4; ++rt) {
      const int mb = m0 + rt * 16 + q * 4;
      const int row = rt * 16 + q * 4;
      float v[4];
#pragma unroll
      for (int r = 0; r < 4; ++r) {
        float res = (mb + r < M) ? bf2f(h[(size_t)(mb + r) * HID + col]) : 0.0f;
        v[r] = acc[rt][ct][r] + bv + res;
      }
      uintT u01 = f2bf2(v[0], v[1]), u23 = f2bf2(v[2], v[3]);
      As[(row + 0) * 264 + col] = (ushortT)u01;
      As[(row + 1) * 264 + col] = (ushortT)(u01 >> 16);
      As[(row + 2) * 264 + col] = (ushortT)u23;
      As[(row + 3) * 264 + col] = (ushortT)(u23 >> 16);
      if (mb + 0 < M) h[(size_t)(mb + 0) * HID + col] = (ushortT)u01;
      if (mb + 1 < M) h[(size_t)(mb + 1) * HID + col] = (ushortT)(u01 >> 16);
      if (mb + 2 < M) h[(size_t)(mb + 2) * HID + col] = (ushortT)u23;
      if (mb + 3 < M) h[(size_t)(mb + 3) * HID + col] = (ushortT)(u23 >> 16);
    }
  }
  __syncthreads();

#pragma unroll
  for (int rt = 0; rt < 4; ++rt)
#pragma unroll
    for (int ct = 0; ct < 2; ++ct) acc[rt][ct] = (f32x4){0.f, 0.f, 0.f, 0.f};
  mfma_kloop32(As, B3t, acc, c0, lm, q);

  if constexpr (LAST) {
    // fused LayerNorm + SiLU, fp32 end-to-end via LDS (two 32-row halves)
    __syncthreads();  // all waves done reading As (kloop3)
    float* Pf = (float*)As;
    const int PSTR = 260;  // 32*260*4 = 33280 B <= 33792 B
    const int wv = tid >> 6;
#pragma unroll
    for (int half = 0; half < 2; ++half) {
      // write this half's rows (rt = 2*half .. 2*half+1) + bias into LDS fp32
#pragma unroll
      for (int ct = 0; ct < 2; ++ct) {
        const int col = c0 + ct * 16 + lm;
        const float bv = b3v[col];
#pragma unroll
        for (int rtl = 0; rtl < 2; ++rtl) {
          const int rt = half * 2 + rtl;
          const int lrow = rtl * 16 + q * 4;
#pragma unroll
          for (int r = 0; r < 4; ++r)
            Pf[(lrow + r) * PSTR + col] = acc[rt][ct][r] + bv;
        }
      }
      __syncthreads();
      // LN+SiLU: wave wv owns rows wv*4..wv*4+3 of this half; lane holds 4 cols
#pragma unroll
      for (int rr = 0; rr < 4; ++rr) {
        const int lrow = wv * 4 + rr;
        const int grow = m0 + half * 32 + lrow;
        float4 v4 = *(float4*)&Pf[lrow * PSTR + lane * 4];
        float s = v4.x + v4.y + v4.z + v4.w;
#pragma unroll
        for (int m = 32; m; m >>= 1) s += __shfl_xor(s, m, 64);
        float mu = s * (1.0f / 256.0f);
        float d0 = v4.x - mu, d1 = v4.y - mu, d2 = v4.z - mu, d3 = v4.w - mu;
        float qv = d0 * d0 + d1 * d1 + d2 * d2 + d3 * d3;
#pragma unroll
        for (int m = 32; m; m >>= 1) qv += __shfl_xor(qv, m, 64);
        float rstd = rsqrtf(qv * (1.0f / 256.0f) + 1e-5f);
        if (grow < M) {
          float4 g4 = *(const float4*)&lng[lane * 4];
          float4 b4 = *(const float4*)&lnb[lane * 4];
          float y0 = d0 * rstd * g4.x + b4.x;
          float y1 = d1 * rstd * g4.y + b4.y;
          float y2 = d2 * rstd * g4.z + b4.z;
          float y3 = d3 * rstd * g4.w + b4.w;
          float4 o;
          o.x = y0 * (1.0f / (1.0f + exp2f(-y0 * 1.44269504088896340736f)));
          o.y = y1 * (1.0f / (1.0f + exp2f(-y1 * 1.44269504088896340736f)));
          o.z = y2 * (1.0f / (1.0f + exp2f(-y2 * 1.44269504088896340736f)));
          o.w = y3 * (1.0f / (1.0f + exp2f(-y3 * 1.44269504088896340736f)));
          *(float4*)&outp[(size_t)grow * HID + lane * 4] = o;
        }
      }
      __syncthreads();  // before next half reuses Pf
    }
  } else {
#pragma unroll
    for (int ct = 0; ct < 2; ++ct) {
      const int col = c0 + ct * 16 + lm;
#pragma unroll
      for (int rt = 0; rt < 4; ++rt) {
        const int mb = m0 + rt * 16 + q * 4;
        uintT u01 = f2bf2(acc[rt][ct][0], acc[rt][ct][1]);
        uintT u23 = f2bf2(acc[rt][ct][2], acc[rt][ct][3]);
        if (mb + 0 < M) x1out[(size_t)(mb + 0) * HID + col] = (ushortT)u01;
        if (mb + 1 < M) x1out[(size_t)(mb + 1) * HID + col] = (ushortT)(u01 >> 16);
        if (mb + 2 < M) x1out[(size_t)(mb + 2) * HID + col] = (ushortT)u23;
        if (mb + 3 < M) x1out[(size_t)(mb + 3) * HID + col] = (ushortT)(u23 >> 16);
      }
    }
  }
}

// ---------------------------------------------------------------------------
// Filter table build: table[l][g][:] = ssp(rbf(g*H_STEP) @ w1t[l] + b1[l]) @ w2t[l] + b2[l]
__global__ __launch_bounds__(256) void table_k(
    const ushortT* __restrict__ w1t_all, const float* __restrict__ b1_all,
    const ushortT* __restrict__ w2t_all, const float* __restrict__ b2_all,
    ushortT* __restrict__ table_all) {
  __shared__ ushortT T[64 * 264];
  ushortT* R = T;  // rbf tile aliases T head; barrier before T write

  const int blk = blockIdx.x;
  const int l = blk / TB_BLOCKS, tb = blk % TB_BLOCKS;
  const ushortT* w1t = w1t_all + (size_t)l * HID * 64;
  const float* b1 = b1_all + (size_t)l * HID;
  const ushortT* w2t = w2t_all + (size_t)l * HID * HID;
  const float* b2 = b2_all + (size_t)l * HID;
  ushortT* table = table_all + (size_t)l * NT_PTS * HID;

  const int tid = threadIdx.x;
  const float delta = 5.0f / 49.0f;
  const float coeff2 = (-0.5f / (delta * delta)) * 1.44269504088896340736f;
#pragma unroll
  for (int i = 0; i < 16; ++i) {
    int idx = i * 256 + tid;
    int e = idx >> 6, k = idx & 63;
    float v = 0.0f;
    if (k < NGAUSS) {
      float dist = (float)(tb * 64 + e) * H_STEP;
      float dd = dist - (float)k * delta;
      v = exp2f(coeff2 * dd * dd);
    }
    R[e * 72 + k] = f2bf(v);
  }
  __syncthreads();

  const int lane = tid & 63;
  const int lm = lane & 15, q = lane >> 4;
  const int c0 = (tid >> 6) * 64;

  // phase 1: t = ssp(R @ w1t + b1), K=64
  {
    f32x4 acc1[4][4];
#pragma unroll
    for (int rt = 0; rt < 4; ++rt)
#pragma unroll
      for (int ct = 0; ct < 4; ++ct) acc1[rt][ct] = (f32x4){0.f, 0.f, 0.f, 0.f};
#pragma unroll
    for (int k = 0; k < 64; k += 32) {
      bf16x8 a[4], b[4];
#pragma unroll
      for (int rt = 0; rt < 4; ++rt)
        a[rt] = *(const bf16x8*)&R[(rt * 16 + lm) * 72 + k + 8 * q];
#pragma unroll
      for (int ct = 0; ct < 4; ++ct)
        b[ct] = *(const bf16x8*)(w1t + (size_t)(c0 + ct * 16 + lm) * 64 + k + 8 * q);
#pragma unroll
      for (int rt = 0; rt < 4; ++rt)
#pragma unroll
        for (int ct = 0; ct < 4; ++ct)
          acc1[rt][ct] = __builtin_amdgcn_mfma_f32_16x16x32_bf16(a[rt], b[ct], acc1[rt][ct], 0, 0, 0);
    }
    __syncthreads();  // done reading R before T (aliased) is written
#pragma unroll
    for (int ct = 0; ct < 4; ++ct) {
      const int col = c0 + ct * 16 + lm;
      const float bv = b1[col];
#pragma unroll
      for (int rt = 0; rt < 4; ++rt) {
        const int row = rt * 16 + q * 4;
        float v0 = sspf(acc1[rt][ct][0] + bv);
        float v1 = sspf(acc1[rt][ct][1] + bv);
        float v2 = sspf(acc1[rt][ct][2] + bv);
        float v3 = sspf(acc1[rt][ct][3] + bv);
        uintT u01 = f2bf2(v0, v1), u23 = f2bf2(v2, v3);
        T[(row + 0) * 264 + col] = (ushortT)u01;
        T[(row + 1) * 264 + col] = (ushortT)(u01 >> 16);
        T[(row + 2) * 264 + col] = (ushortT)u23;
        T[(row + 3) * 264 + col] = (ushortT)(u23 >> 16);
      }
    }
  }
  __syncthreads();

  // phase 2: Wf = t @ w2t + b2, write table rows directly
  f32x4 acc[4][4];
#pragma unroll
  for (int rt = 0; rt < 4; ++rt)
#pragma unroll
    for (int ct = 0; ct < 4; ++ct) acc[rt][ct] = (f32x4){0.f, 0.f, 0.f, 0.f};
  mfma_kloop(T, w2t + (size_t)c0 * HID, acc, lm, q);

#pragma unroll
  for (int ct = 0; ct < 4; ++ct) {
    const int col = c0 + ct * 16 + lm;
    const float bv = b2[col];
#pragma unroll
    for (int rt = 0; rt < 4; ++rt) {
      const int row = rt * 16 + q * 4;
#pragma unroll
      for (int r = 0; r < 4; ++r) {
        int g = tb * 64 + row + r;
        if (g < NT_PTS) table[(size_t)g * HID + col] = f2bf(acc[rt][ct][r] + bv);
      }
    }
  }
}

// ---------------------------------------------------------------------------
// CSR build: histogram -> hierarchical scan -> perm (edge -> CSR slot)
__global__ __launch_bounds__(256) void hist_k(const int* __restrict__ ei,
                                              int* __restrict__ counts) {
  int e = blockIdx.x * 256 + threadIdx.x;
  if (e < N_EDGES) atomicAdd(&counts[ei[N_EDGES + e]], 1);
}

__global__ __launch_bounds__(256) void scanA_k(const int* __restrict__ counts,
                                               int* __restrict__ bsum) {
  const int b = blockIdx.x, tid = threadIdx.x;
  const int base = b * 1024 + tid * 4;
  int s = 0;
  if (base + 3 < N_NODES) {
    int4 v = *(const int4*)(counts + base);
    s = v.x + v.y + v.z + v.w;
  } else {
#pragma unroll
    for (int i = 0; i < 4; ++i) {
      int n = base + i;
      if (n < N_NODES) s += counts[n];
    }
  }
#pragma unroll
  for (int m = 32; m; m >>= 1) s += __shfl_xor(s, m, 64);
  __shared__ int ws[4];
  if ((tid & 63) == 0) ws[tid >> 6] = s;
  __syncthreads();
  if (tid == 0) bsum[b] = ws[0] + ws[1] + ws[2] + ws[3];
}

__global__ __launch_bounds__(128) void scanB_k(int* __restrict__ bsum,
                                               int* __restrict__ row_start) {
  __shared__ int sh[SCAN_NB];
  const int tid = threadIdx.x;
  if (tid < SCAN_NB) sh[tid] = bsum[tid];
  __syncthreads();
  if (tid == 0) {
    int acc = 0;
    for (int i = 0; i < SCAN_NB; ++i) { int t = sh[i]; sh[i] = acc; acc += t; }
    row_start[N_NODES] = acc;
  }
  __syncthreads();
  if (tid < SCAN_NB) bsum[tid] = sh[tid];
}

__global__ __launch_bounds__(256) void scanC_k(const int* __restrict__ counts,
                                               const int* __restrict__ bsum,
                                               int* __restrict__ row_start,
                                               int* __restrict__ cursor) {
  const int b = blockIdx.x, tid = threadIdx.x;
  const int base = b * 1024 + tid * 4;
  int c[4];
  int s = 0;
#pragma unroll
  for (int i = 0; i < 4; ++i) {
    int n = base + i;
    c[i] = (n < N_NODES) ? counts[n] : 0;
    s += c[i];
  }
  __shared__ int sc[256];
  sc[tid] = s;
  __syncthreads();
  int acc = s;
  for (int off = 1; off < 256; off <<= 1) {
    int v = (tid >= off) ? sc[tid - off] : 0;
    __syncthreads();
    acc += v;
    sc[tid] = acc;
    __syncthreads();
  }
  int off0 = acc - s + bsum[b];
#pragma unroll
  for (int i = 0; i < 4; ++i) {
    int n = base + i;
    if (n < N_NODES) {
      row_start[n] = off0;
      cursor[n] = off0;
      off0 += c[i];
    }
  }
}

__global__ __launch_bounds__(256) void perm_k(const int* __restrict__ ei,
                                              int* __restrict__ cursor,
                                              int* __restrict__ perm) {
  int e = blockIdx.x * 256 + threadIdx.x;
  if (e < N_EDGES) perm[e] = atomicAdd(&cursor[ei[N_EDGES + e]], 1);
}

// edge_prep: per edge compute packed meta {src_bits, rounded_row, cs, 0},
// CSR slot order; nearest-neighbor table row (h=1/256)
__global__ __launch_bounds__(256) void edge_prep_k(const int* __restrict__ ei,
                                                   const float* __restrict__ pos,
                                                   const int* __restrict__ perm,
                                                   float4* __restrict__ csr_meta) {
  int e = blockIdx.x * 256 + threadIdx.x;
  if (e >= N_EDGES) return;
  int s = ei[e], d = ei[N_EDGES + e];
  float dx = pos[s * 3 + 0] - pos[d * 3 + 0];
  float dy = pos[s * 3 + 1] - pos[d * 3 + 1];
  float dz = pos[s * 3 + 2] - pos[d * 3 + 2];
  float dist = sqrtf(fmaf(dx, dx, fmaf(dy, dy, dz * dz)) + 1e-12f);
  union { int i; float f; } sb;
  sb.i = s;
  float4 m;
  m.x = sb.f;
  m.y = fminf(floorf(dist * INV_H + 0.5f), 2048.0f);  // nearest row index
  m.z = 0.5f * (cosf(dist * (3.14159265358979323846f / 5.0f)) + 1.0f);
  m.w = 0.0f;
  csr_meta[perm[e]] = m;
}

// fused gather: agg[n] = sum over CSR edges of x1[src] * table[row] * C
// nearest-neighbor table (1 row/edge); 2-way unrolled edge loop.
__global__ __launch_bounds__(256) void gather2_k(const int* __restrict__ row_start,
                                                 const float4* __restrict__ csr_meta,
                                                 const ushortT* __restrict__ x1,
                                                 const ushortT* __restrict__ table,
                                                 ushortT* __restrict__ agg) {
  int node = blockIdx.x * 4 + (threadIdx.x >> 6);
  int lane = threadIdx.x & 63;
  if (node >= N_NODES) return;
  int a = row_start[node], b = row_start[node + 1];
  const int co = lane * 4;
  float s0 = 0.f, s1 = 0.f, s2 = 0.f, s3 = 0.f;
  int j = a;
  for (; j + 1 < b; j += 2) {
    float4 mtA = csr_meta[j];
    float4 mtB = csr_meta[j + 1];
    union { float f; int i; } sa, sb2;
    sa.f = mtA.x;
    sb2.f = mtB.x;
    int iA = (int)mtA.y, iB = (int)mtB.y;
    uint2 taA = *(const uint2*)(table + (size_t)iA * HID + co);
    uint2 xvA = *(const uint2*)(x1 + (size_t)sa.i * HID + co);
    uint2 taB = *(const uint2*)(table + (size_t)iB * HID + co);
    uint2 xvB = *(const uint2*)(x1 + (size_t)sb2.i * HID + co);
    // edge j
    {
      float cs = mtA.z;
      s0 = fmaf(bflo(xvA.x) * bflo(taA.x), cs, s0);
      s1 = fmaf(bfhi(xvA.x) * bfhi(taA.x), cs, s1);
      s2 = fmaf(bflo(xvA.y) * bflo(taA.y), cs, s2);
      s3 = fmaf(bfhi(xvA.y) * bfhi(taA.y), cs, s3);
    }
    // edge j+1
    {
      float cs = mtB.z;
      s0 = fmaf(bflo(xvB.x) * bflo(taB.x), cs, s0);
      s1 = fmaf(bfhi(xvB.x) * bfhi(taB.x), cs, s1);
      s2 = fmaf(bflo(xvB.y) * bflo(taB.y), cs, s2);
      s3 = fmaf(bfhi(xvB.y) * bfhi(taB.y), cs, s3);
    }
  }
  if (j < b) {
    float4 mt = csr_meta[j];
    union { float f; int i; } sb;
    sb.f = mt.x;
    int i = (int)mt.y;
    float cs = mt.z;
    uint2 ta = *(const uint2*)(table + (size_t)i * HID + co);
    uint2 xv = *(const uint2*)(x1 + (size_t)sb.i * HID + co);
    s0 = fmaf(bflo(xv.x) * bflo(ta.x), cs, s0);
    s1 = fmaf(bfhi(xv.x) * bfhi(ta.x), cs, s1);
    s2 = fmaf(bflo(xv.y) * bflo(ta.y), cs, s2);
    s3 = fmaf(bfhi(xv.y) * bfhi(ta.y), cs, s3);
  }
  uint2 o;
  o.x = f2bf2(s0, s1);
  o.y = f2bf2(s2, s3);
  *(uint2*)(agg + (size_t)node * HID + co) = o;
}

// ---------------------------------------------------------------------------
// Weight prep: fp32 W[K,256] -> bf16 Wt[256,K], square 256x256 matrices
__global__ __launch_bounds__(256) void wconv_k(const float* __restrict__ src,
                                               ushortT* __restrict__ dst) {
  __shared__ float tile[64][65];
  const int b = blockIdx.x;
  const int mat = b >> 4, t = b & 15;
  const int tr = (t >> 2) * 64, tc = (t & 3) * 64;
  const float* S = src + (size_t)mat * HID * HID;
  ushortT* D = dst + (size_t)mat * HID * HID;
  const int tid = threadIdx.x;
#pragma unroll
  for (int i = 0; i < 16; ++i) {
    int idx = i * 256 + tid;
    int r = idx >> 6, c = idx & 63;
    tile[r][c] = S[(size_t)(tr + r) * HID + tc + c];
  }
  __syncthreads();
#pragma unroll
  for (int i = 0; i < 16; ++i) {
    int idx = i * 256 + tid;
    int n = idx >> 6, k = idx & 63;
    D[(size_t)(tc + n) * HID + tr + k] = f2bf(tile[k][n]);
  }
}

// mlp_w1 [L][50][256] fp32 -> w1t [L][256][64] bf16 (k padded with zeros)
__global__ __launch_bounds__(256) void w1conv_k(const float* __restrict__ src,
                                                ushortT* __restrict__ dst) {
  const int l = blockIdx.x;
  const int n = threadIdx.x;
  const float* S = src + (size_t)l * NGAUSS * HID;
  ushortT* D = dst + (size_t)l * HID * 64;
  for (int k = 0; k < 64; ++k) {
    float v = (k < NGAUSS) ? S[(size_t)k * HID + n] : 0.0f;
    D[(size_t)n * 64 + k] = f2bf(v);
  }
}

// ---------------------------------------------------------------------------
__global__ __launch_bounds__(256) void embed_k(const int* __restrict__ z,
                                               const float* __restrict__ emb,
                                               ushortT* __restrict__ h) {
  int idx = blockIdx.x * 256 + threadIdx.x;
  if (idx >= N_NODES * HID) return;
  int n = idx >> 8;
  int c = idx & 255;
  h[idx] = f2bf(emb[z[n] * HID + c]);
}

__global__ __launch_bounds__(256) void tail_k(const int* __restrict__ batch,
                                              float* __restrict__ out) {
  int i = blockIdx.x * 256 + threadIdx.x;
  if (i < N_NODES) out[i] = (float)batch[i];
}

// ---------------------------------------------------------------------------
extern "C" void kernel_launch(void* const* d_in, const int* in_sizes, int n_in,
                              void* d_out, int out_size, void* d_ws, size_t ws_size,
                              hipStream_t stream) {
  const int* z = (const int*)d_in[0];
  const float* pos = (const float*)d_in[1];
  const int* batch = (const int*)d_in[2];
  const int* ei = (const int*)d_in[3];
  const float* emb = (const float*)d_in[4];
  const float* mlp_w1 = (const float*)d_in[5];
  const float* mlp_b1 = (const float*)d_in[6];
  const float* mlp_w2 = (const float*)d_in[7];
  const float* mlp_b2 = (const float*)d_in[8];
  const float* lin1_w = (const float*)d_in[9];
  const float* lin2_w = (const float*)d_in[10];
  const float* lin2_b = (const float*)d_in[11];
  const float* lin_w = (const float*)d_in[12];
  const float* lin_b = (const float*)d_in[13];
  const float* proj_w = (const float*)d_in[14];
  const float* proj_b = (const float*)d_in[15];
  const float* ln_g = (const float*)d_in[16];
  const float* ln_b = (const float*)d_in[17];
  float* out = (float*)d_out;  // fp32: p [N*256] then batch [N]

  const size_t NH = (size_t)N_NODES * HID;
  const size_t WSZ = (size_t)HID * HID;

  // ---- workspace layout (~270 MB) ----
  char* w = (char*)d_ws;
  ushortT* h = (ushortT*)w;      w += NH * 2;
  ushortT* x1 = (ushortT*)w;     w += NH * 2;
  ushortT* agg = (ushortT*)w;    w += NH * 2;
  ushortT* lin1t = (ushortT*)w;  w += 6 * WSZ * 2;
  ushortT* lin2t = (ushortT*)w;  w += 6 * WSZ * 2;
  ushortT* lint = (ushortT*)w;   w += 6 * WSZ * 2;
  ushortT* w2t = (ushortT*)w;    w += 6 * WSZ * 2;
  ushortT* projt = (ushortT*)w;  w += WSZ * 2;
  ushortT* w1t = (ushortT*)w;    w += 6 * (size_t)HID * 64 * 2;
  ushortT* tables = (ushortT*)w; w += 6 * (size_t)NT_PTS * HID * 2;
  int* counts = (int*)w;         w += (size_t)N_NODES * 4;
  int* cursor = (int*)w;         w += (size_t)N_NODES * 4;
  int* row_start = (int*)w;      w += (size_t)(N_NODES + 64) * 4;
  int* perm = (int*)w;           w += (size_t)N_EDGES * 4;
  float4* csr_meta = (float4*)w; w += (size_t)N_EDGES * 16;
  int* bsum = (int*)w;           w += (size_t)128 * 4;

  // ---- CSR build ----
  hipMemsetAsync(counts, 0, (size_t)N_NODES * 4, stream);
  hist_k<<<(N_EDGES + 255) / 256, 256, 0, stream>>>(ei, counts);
  scanA_k<<<SCAN_NB, 256, 0, stream>>>(counts, bsum);
  scanB_k<<<1, 128, 0, stream>>>(bsum, row_start);
  scanC_k<<<SCAN_NB, 256, 0, stream>>>(counts, bsum, row_start, cursor);
  perm_k<<<(N_EDGES + 255) / 256, 256, 0, stream>>>(ei, cursor, perm);
  edge_prep_k<<<(N_EDGES + 255) / 256, 256, 0, stream>>>(ei, pos, perm, csr_meta);

  // ---- weight prep ----
  wconv_k<<<6 * 16, 256, 0, stream>>>(lin1_w, lin1t);
  wconv_k<<<6 * 16, 256, 0, stream>>>(lin2_w, lin2t);
  wconv_k<<<6 * 16, 256, 0, stream>>>(lin_w, lint);
  wconv_k<<<6 * 16, 256, 0, stream>>>(mlp_w2, w2t);
  wconv_k<<<16, 256, 0, stream>>>(proj_w, projt);
  w1conv_k<<<6, 256, 0, stream>>>(mlp_w1, w1t);

  // ---- filter tables (all 6 layers, one dispatch) ----
  table_k<<<6 * TB_BLOCKS, 256, 0, stream>>>(w1t, mlp_b1, w2t, mlp_b2, tables);

  embed_k<<<(N_NODES * HID + 255) / 256, 256, 0, stream>>>(z, emb, h);

  const int MB64 = (N_NODES + 63) / 64;
  mgemm<<<MB64, 256, 0, stream>>>(h, lin1t, x1, N_NODES);  // x1_0
  for (int l = 0; l < NLAYERS; ++l) {
    const size_t oW = (size_t)l * WSZ;
    const size_t o1 = (size_t)l * HID;
    gather2_k<<<(N_NODES + 3) / 4, 256, 0, stream>>>(
        row_start, csr_meta, x1,
        tables + (size_t)l * NT_PTS * HID, agg);
    if (l < NLAYERS - 1) {
      mgemm3<0><<<MB64, 512, 0, stream>>>(agg, lin2t + oW, lin2_b + o1,
                                          lint + oW, lin_b + o1, h,
                                          lin1t + (size_t)(l + 1) * WSZ, nullptr,
                                          x1, nullptr, nullptr, nullptr, N_NODES);
    } else {
      mgemm3<1><<<MB64, 512, 0, stream>>>(agg, lin2t + oW, lin2_b + o1,
                                          lint + oW, lin_b + o1, h,
                                          projt, proj_b,
                                          nullptr, ln_g, ln_b, out, N_NODES);
    }
  }
  tail_k<<<(N_NODES + 255) / 256, 256, 0, stream>>>(batch, out + NH);
}

// Round 18
// 1284.178 us; speedup vs baseline: 1.3718x; 1.0370x over previous
//
#include <hip/hip_runtime.h>

#define N_NODES 100000
#define N_EDGES 320000
#define HID 256
#define NGAUSS 50
#define NLAYERS 6
#define SCAN_NB 98   // ceil(N_NODES/1024)
#define NT_PTS 2049  // filter table points over [0,8], h=1/256, nearest-neighbor
#define TB_BLOCKS 33 // ceil(2049/64)
#define H_STEP 0.00390625f
#define INV_H 256.0f

typedef unsigned short ushortT;
typedef unsigned int uintT;
typedef __attribute__((ext_vector_type(8))) short bf16x8;  // 8 bf16 = 4 VGPR
typedef __attribute__((ext_vector_type(4))) float f32x4;
typedef __attribute__((ext_vector_type(2))) __bf16 bf16v2;

// ---------------------------------------------------------------------------
// ShiftedSoftplus via native exp2/log2:
//   softplus(x) - ln2 = max(x,0) + ln2*log2(1 + exp2(-|x|*log2e)) - ln2
__device__ __forceinline__ float sspf(float x) {
  float e = exp2f(-fabsf(x) * 1.44269504088896340736f);
  float l = __log2f(1.0f + e);
  return fmaf(0.69314718055994530942f, l,
              fmaxf(x, 0.0f) - 0.69314718055994530942f);
}

__device__ __forceinline__ float bf2f(ushortT u) {
  union { uintT i; float f; } c;
  c.i = ((uintT)u) << 16;
  return c.f;
}

// unpack low/high bf16 of a packed dword (1 VALU op each; reinterpret is free)
__device__ __forceinline__ float bflo(uintT u) {
  union { uintT i; float f; } c;
  c.i = u << 16;
  return c.f;
}
__device__ __forceinline__ float bfhi(uintT u) {
  union { uintT i; float f; } c;
  c.i = u & 0xFFFF0000u;
  return c.f;
}

// native bf16 converts (RNE) -> v_cvt_pk_bf16_f32 on gfx950
__device__ __forceinline__ ushortT f2bf(float f) {
  union { __bf16 b; ushortT u; } c;
  c.b = (__bf16)f;
  return c.u;
}
__device__ __forceinline__ uintT f2bf2(float lo, float hi) {
  union { bf16v2 v; uintT u; } c;
  c.v = (bf16v2){(__bf16)lo, (__bf16)hi};
  return c.u;
}

// ---------------------------------------------------------------------------
// MFMA K-loops over K=256. A in LDS bf16 (row stride 264), Bt row-major [N,K].
//   A-frag: lane(16q+m) holds A[m][8q..8q+8); C/D: lane(16q+c) reg r -> row 4q+r, col c
__device__ __forceinline__ void mfma_kloop(const ushortT* As, const ushortT* Bt,
                                           f32x4 (&acc)[4][4], int lm, int q) {
#pragma unroll
  for (int k = 0; k < 256; k += 32) {
    bf16x8 a[4], b[4];
#pragma unroll
    for (int rt = 0; rt < 4; ++rt)
      a[rt] = *(const bf16x8*)&As[(rt * 16 + lm) * 264 + k + 8 * q];
#pragma unroll
    for (int ct = 0; ct < 4; ++ct)
      b[ct] = *(const bf16x8*)(Bt + (size_t)(ct * 16 + lm) * HID + k + 8 * q);
#pragma unroll
    for (int rt = 0; rt < 4; ++rt)
#pragma unroll
      for (int ct = 0; ct < 4; ++ct)
        acc[rt][ct] = __builtin_amdgcn_mfma_f32_16x16x32_bf16(a[rt], b[ct], acc[rt][ct], 0, 0, 0);
  }
}

// 8-wave variant, 32-col stripe per wave, acc[4][2] (measured-best plain form:
// per-k-step loads; the compiler's sunk-load schedule beat forced preloads).
__device__ __forceinline__ void mfma_kloop32(const ushortT* As, const ushortT* Bt,
                                             f32x4 (&acc)[4][2], int c0, int lm, int q) {
#pragma unroll
  for (int k = 0; k < 256; k += 32) {
    bf16x8 b[2];
#pragma unroll
    for (int ct = 0; ct < 2; ++ct)
      b[ct] = *(const bf16x8*)(Bt + (size_t)(c0 + ct * 16 + lm) * HID + k + 8 * q);
#pragma unroll
    for (int rt = 0; rt < 4; ++rt) {
      bf16x8 a = *(const bf16x8*)&As[(rt * 16 + lm) * 264 + k + 8 * q];
#pragma unroll
      for (int ct = 0; ct < 2; ++ct)
        acc[rt][ct] = __builtin_amdgcn_mfma_f32_16x16x32_bf16(a, b[ct], acc[rt][ct], 0, 0, 0);
    }
  }
}

// acc tile -> LDS (bf16, A layout), 4-wave version
__device__ __forceinline__ void acc_to_lds(ushortT* As, const f32x4 (&acc)[4][4],
                                           int c0, int lm, int q) {
#pragma unroll
  for (int ct = 0; ct < 4; ++ct) {
    const int col = c0 + ct * 16 + lm;
#pragma unroll
    for (int rt = 0; rt < 4; ++rt) {
      const int row = rt * 16 + q * 4;
      uintT u01 = f2bf2(acc[rt][ct][0], acc[rt][ct][1]);
      uintT u23 = f2bf2(acc[rt][ct][2], acc[rt][ct][3]);
      As[(row + 0) * 264 + col] = (ushortT)u01;
      As[(row + 1) * 264 + col] = (ushortT)(u01 >> 16);
      As[(row + 2) * 264 + col] = (ushortT)u23;
      As[(row + 3) * 264 + col] = (ushortT)(u23 >> 16);
    }
  }
}

// coalesced LDS tile -> global (row-contiguous uint4), 256-thread version
__device__ __forceinline__ void store_tile64(const ushortT* As,
                                             ushortT* __restrict__ dst,
                                             int m0, int M, int tid) {
#pragma unroll
  for (int i = 0; i < 8; ++i) {
    int idx = i * 256 + tid;
    int r = idx >> 5, ch = idx & 31;
    int m = m0 + r;
    if (m < M)
      *(uint4*)(dst + (size_t)m * HID + ch * 8) = *(const uint4*)&As[r * 264 + ch * 8];
  }
}

// ---------------------------------------------------------------------------
// Fused embed + x1_0 GEMM: stage emb[z[m]] (fp32->bf16) into LDS AND h,
// then C = h @ lin1t. Eliminates the separate embed dispatch + h re-read.
__global__ __launch_bounds__(256) void mgemm_embed(const int* __restrict__ z,
                                                   const float* __restrict__ emb,
                                                   const ushortT* __restrict__ Bt,
                                                   ushortT* __restrict__ h,
                                                   ushortT* __restrict__ Cbf, int M) {
  __shared__ ushortT As[64 * 264];
  const int tid = threadIdx.x;
  const int m0 = blockIdx.x * 64;

#pragma unroll
  for (int i = 0; i < 8; ++i) {
    int idx = i * 256 + tid;
    int r = idx >> 5, ch = idx & 31;
    int m = m0 + r;
    uint4 u = make_uint4(0, 0, 0, 0);
    if (m < M) {
      const float* er = emb + (size_t)z[m] * HID + ch * 8;
      float4 f0 = *(const float4*)er;
      float4 f1 = *(const float4*)(er + 4);
      u.x = f2bf2(f0.x, f0.y);
      u.y = f2bf2(f0.z, f0.w);
      u.z = f2bf2(f1.x, f1.y);
      u.w = f2bf2(f1.z, f1.w);
      *(uint4*)(h + (size_t)m * HID + ch * 8) = u;
    }
    *(uint4*)&As[r * 264 + ch * 8] = u;
  }
  __syncthreads();

  const int lane = tid & 63;
  const int lm = lane & 15, q = lane >> 4;
  const int c0 = (tid >> 6) * 64;

  f32x4 acc[4][4];
#pragma unroll
  for (int rt = 0; rt < 4; ++rt)
#pragma unroll
    for (int ct = 0; ct < 4; ++ct) acc[rt][ct] = (f32x4){0.f, 0.f, 0.f, 0.f};

  mfma_kloop(As, Bt + (size_t)c0 * HID, acc, lm, q);
  __syncthreads();  // all waves done reading As
  acc_to_lds(As, acc, c0, lm, q);
  __syncthreads();
  store_tile64(As, Cbf, m0, M, tid);
}

// ---------------------------------------------------------------------------
// Fused interaction tail + next-layer head (3 chained K=256 GEMMs, LDS-resident).
// 512 threads / 8 waves; 64-row tile; each wave owns a 32-col stripe, acc[4][2].
//   x2 = ssp(agg @ B1t + b1)
//   hn = h + x2 @ B2t + b2            (write h)
//   LAST=0: x1out = hn @ B3t (bf16)
//   LAST=1: out = SiLU(LayerNorm(hn @ B3t + b3)) fp32 -- LN fused in-block
//           (LDS reused as fp32 [32][260] tile, two halves; fp32 end-to-end)
template <int LAST>
__global__ __launch_bounds__(512, 2) void mgemm3(const ushortT* __restrict__ A,
                                                 const ushortT* __restrict__ B1t,
                                                 const float* __restrict__ b1v,
                                                 const ushortT* __restrict__ B2t,
                                                 const float* __restrict__ b2v,
                                                 ushortT* __restrict__ h,
                                                 const ushortT* __restrict__ B3t,
                                                 const float* __restrict__ b3v,
                                                 ushortT* __restrict__ x1out,
                                                 const float* __restrict__ lng,
                                                 const float* __restrict__ lnb,
                                                 float* __restrict__ outp, int M) {
  __shared__ ushortT As[64 * 264];  // 33792 B
  const int tid = threadIdx.x;
  const int m0 = blockIdx.x * 64;

  // stage 64x256 tile: 2048 uint4 over 512 threads
#pragma unroll
  for (int i = 0; i < 4; ++i) {
    int idx = i * 512 + tid;
    int r = idx >> 5, ch = idx & 31;
    int m = m0 + r;
    uint4 u = make_uint4(0, 0, 0, 0);
    if (m < M) u = *(const uint4*)(A + (size_t)m * HID + ch * 8);
    *(uint4*)&As[r * 264 + ch * 8] = u;
  }
  __syncthreads();

  const int lane = tid & 63;
  const int lm = lane & 15, q = lane >> 4;
  const int c0 = (tid >> 6) * 32;  // wave's 32-col stripe

  f32x4 acc[4][2];
#pragma unroll
  for (int rt = 0; rt < 4; ++rt)
#pragma unroll
    for (int ct = 0; ct < 2; ++ct) acc[rt][ct] = (f32x4){0.f, 0.f, 0.f, 0.f};
  mfma_kloop32(As, B1t, acc, c0, lm, q);
  __syncthreads();  // all waves done reading As

  // epi1: x2 = ssp(acc + b1) -> As
#pragma unroll
  for (int ct = 0; ct < 2; ++ct) {
    const int col = c0 + ct * 16 + lm;
    const float bv = b1v[col];
#pragma unroll
    for (int rt = 0; rt < 4; ++rt) {
      const int row = rt * 16 + q * 4;
      float v0 = sspf(acc[rt][ct][0] + bv);
      float v1 = sspf(acc[rt][ct][1] + bv);
      float v2 = sspf(acc[rt][ct][2] + bv);
      float v3 = sspf(acc[rt][ct][3] + bv);
      uintT u01 = f2bf2(v0, v1), u23 = f2bf2(v2, v3);
      As[(row + 0) * 264 + col] = (ushortT)u01;
      As[(row + 1) * 264 + col] = (ushortT)(u01 >> 16);
      As[(row + 2) * 264 + col] = (ushortT)u23;
      As[(row + 3) * 264 + col] = (ushortT)(u23 >> 16);
    }
  }
  __syncthreads();

#pragma unroll
  for (int rt = 0; rt < 4; ++rt)
#pragma unroll
    for (int ct = 0; ct < 2; ++ct) acc[rt][ct] = (f32x4){0.f, 0.f, 0.f, 0.f};
  mfma_kloop32(As, B2t, acc, c0, lm, q);
  __syncthreads();  // all waves done reading As

  // epi2: hn = acc + b2 + h_old -> h (scattered) and As
#pragma unroll
  for (int ct = 0; ct < 2; ++ct) {
    const int col = c0 + ct * 16 + lm;
    const float bv = b2v[col];
#pragma unroll
    for (int rt = 0; rt < 4; ++rt) {
      const int mb = m0 + rt * 16 + q * 4;
      const int row = rt * 16 + q * 4;
      float v[4];
#pragma unroll
      for (int r = 0; r < 4; ++r) {
        float res = (mb + r < M) ? bf2f(h[(size_t)(mb + r) * HID + col]) : 0.0f;
        v[r] = acc[rt][ct][r] + bv + res;
      }
      uintT u01 = f2bf2(v[0], v[1]), u23 = f2bf2(v[2], v[3]);
      As[(row + 0) * 264 + col] = (ushortT)u01;
      As[(row + 1) * 264 + col] = (ushortT)(u01 >> 16);
      As[(row + 2) * 264 + col] = (ushortT)u23;
      As[(row + 3) * 264 + col] = (ushortT)(u23 >> 16);
      if (mb + 0 < M) h[(size_t)(mb + 0) * HID + col] = (ushortT)u01;
      if (mb + 1 < M) h[(size_t)(mb + 1) * HID + col] = (ushortT)(u01 >> 16);
      if (mb + 2 < M) h[(size_t)(mb + 2) * HID + col] = (ushortT)u23;
      if (mb + 3 < M) h[(size_t)(mb + 3) * HID + col] = (ushortT)(u23 >> 16);
    }
  }
  __syncthreads();

#pragma unroll
  for (int rt = 0; rt < 4; ++rt)
#pragma unroll
    for (int ct = 0; ct < 2; ++ct) acc[rt][ct] = (f32x4){0.f, 0.f, 0.f, 0.f};
  mfma_kloop32(As, B3t, acc, c0, lm, q);

  if constexpr (LAST) {
    // fused LayerNorm + SiLU, fp32 end-to-end via LDS (two 32-row halves)
    __syncthreads();  // all waves done reading As (kloop3)
    float* Pf = (float*)As;
    const int PSTR = 260;  // 32*260*4 = 33280 B <= 33792 B
    const int wv = tid >> 6;
#pragma unroll
    for (int half = 0; half < 2; ++half) {
      // write this half's rows (rt = 2*half .. 2*half+1) + bias into LDS fp32
#pragma unroll
      for (int ct = 0; ct < 2; ++ct) {
        const int col = c0 + ct * 16 + lm;
        const float bv = b3v[col];
#pragma unroll
        for (int rtl = 0; rtl < 2; ++rtl) {
          const int rt = half * 2 + rtl;
          const int lrow = rtl * 16 + q * 4;
#pragma unroll
          for (int r = 0; r < 4; ++r)
            Pf[(lrow + r) * PSTR + col] = acc[rt][ct][r] + bv;
        }
      }
      __syncthreads();
      // LN+SiLU: wave wv owns rows wv*4..wv*4+3 of this half; lane holds 4 cols
#pragma unroll
      for (int rr = 0; rr < 4; ++rr) {
        const int lrow = wv * 4 + rr;
        const int grow = m0 + half * 32 + lrow;
        float4 v4 = *(float4*)&Pf[lrow * PSTR + lane * 4];
        float s = v4.x + v4.y + v4.z + v4.w;
#pragma unroll
        for (int m = 32; m; m >>= 1) s += __shfl_xor(s, m, 64);
        float mu = s * (1.0f / 256.0f);
        float d0 = v4.x - mu, d1 = v4.y - mu, d2 = v4.z - mu, d3 = v4.w - mu;
        float qv = d0 * d0 + d1 * d1 + d2 * d2 + d3 * d3;
#pragma unroll
        for (int m = 32; m; m >>= 1) qv += __shfl_xor(qv, m, 64);
        float rstd = rsqrtf(qv * (1.0f / 256.0f) + 1e-5f);
        if (grow < M) {
          float4 g4 = *(const float4*)&lng[lane * 4];
          float4 b4 = *(const float4*)&lnb[lane * 4];
          float y0 = d0 * rstd * g4.x + b4.x;
          float y1 = d1 * rstd * g4.y + b4.y;
          float y2 = d2 * rstd * g4.z + b4.z;
          float y3 = d3 * rstd * g4.w + b4.w;
          float4 o;
          o.x = y0 * (1.0f / (1.0f + exp2f(-y0 * 1.44269504088896340736f)));
          o.y = y1 * (1.0f / (1.0f + exp2f(-y1 * 1.44269504088896340736f)));
          o.z = y2 * (1.0f / (1.0f + exp2f(-y2 * 1.44269504088896340736f)));
          o.w = y3 * (1.0f / (1.0f + exp2f(-y3 * 1.44269504088896340736f)));
          *(float4*)&outp[(size_t)grow * HID + lane * 4] = o;
        }
      }
      __syncthreads();  // before next half reuses Pf
    }
  } else {
#pragma unroll
    for (int ct = 0; ct < 2; ++ct) {
      const int col = c0 + ct * 16 + lm;
#pragma unroll
      for (int rt = 0; rt < 4; ++rt) {
        const int mb = m0 + rt * 16 + q * 4;
        uintT u01 = f2bf2(acc[rt][ct][0], acc[rt][ct][1]);
        uintT u23 = f2bf2(acc[rt][ct][2], acc[rt][ct][3]);
        if (mb + 0 < M) x1out[(size_t)(mb + 0) * HID + col] = (ushortT)u01;
        if (mb + 1 < M) x1out[(size_t)(mb + 1) * HID + col] = (ushortT)(u01 >> 16);
        if (mb + 2 < M) x1out[(size_t)(mb + 2) * HID + col] = (ushortT)u23;
        if (mb + 3 < M) x1out[(size_t)(mb + 3) * HID + col] = (ushortT)(u23 >> 16);
      }
    }
  }
}

// ---------------------------------------------------------------------------
// Filter table build: table[l][g][:] = ssp(rbf(g*H_STEP) @ w1t[l] + b1[l]) @ w2t[l] + b2[l]
__global__ __launch_bounds__(256) void table_k(
    const ushortT* __restrict__ w1t_all, const float* __restrict__ b1_all,
    const ushortT* __restrict__ w2t_all, const float* __restrict__ b2_all,
    ushortT* __restrict__ table_all) {
  __shared__ ushortT T[64 * 264];
  ushortT* R = T;  // rbf tile aliases T head; barrier before T write

  const int blk = blockIdx.x;
  const int l = blk / TB_BLOCKS, tb = blk % TB_BLOCKS;
  const ushortT* w1t = w1t_all + (size_t)l * HID * 64;
  const float* b1 = b1_all + (size_t)l * HID;
  const ushortT* w2t = w2t_all + (size_t)l * HID * HID;
  const float* b2 = b2_all + (size_t)l * HID;
  ushortT* table = table_all + (size_t)l * NT_PTS * HID;

  const int tid = threadIdx.x;
  const float delta = 5.0f / 49.0f;
  const float coeff2 = (-0.5f / (delta * delta)) * 1.44269504088896340736f;
#pragma unroll
  for (int i = 0; i < 16; ++i) {
    int idx = i * 256 + tid;
    int e = idx >> 6, k = idx & 63;
    float v = 0.0f;
    if (k < NGAUSS) {
      float dist = (float)(tb * 64 + e) * H_STEP;
      float dd = dist - (float)k * delta;
      v = exp2f(coeff2 * dd * dd);
    }
    R[e * 72 + k] = f2bf(v);
  }
  __syncthreads();

  const int lane = tid & 63;
  const int lm = lane & 15, q = lane >> 4;
  const int c0 = (tid >> 6) * 64;

  // phase 1: t = ssp(R @ w1t + b1), K=64
  {
    f32x4 acc1[4][4];
#pragma unroll
    for (int rt = 0; rt < 4; ++rt)
#pragma unroll
      for (int ct = 0; ct < 4; ++ct) acc1[rt][ct] = (f32x4){0.f, 0.f, 0.f, 0.f};
#pragma unroll
    for (int k = 0; k < 64; k += 32) {
      bf16x8 a[4], b[4];
#pragma unroll
      for (int rt = 0; rt < 4; ++rt)
        a[rt] = *(const bf16x8*)&R[(rt * 16 + lm) * 72 + k + 8 * q];
#pragma unroll
      for (int ct = 0; ct < 4; ++ct)
        b[ct] = *(const bf16x8*)(w1t + (size_t)(c0 + ct * 16 + lm) * 64 + k + 8 * q);
#pragma unroll
      for (int rt = 0; rt < 4; ++rt)
#pragma unroll
        for (int ct = 0; ct < 4; ++ct)
          acc1[rt][ct] = __builtin_amdgcn_mfma_f32_16x16x32_bf16(a[rt], b[ct], acc1[rt][ct], 0, 0, 0);
    }
    __syncthreads();  // done reading R before T (aliased) is written
#pragma unroll
    for (int ct = 0; ct < 4; ++ct) {
      const int col = c0 + ct * 16 + lm;
      const float bv = b1[col];
#pragma unroll
      for (int rt = 0; rt < 4; ++rt) {
        const int row = rt * 16 + q * 4;
        float v0 = sspf(acc1[rt][ct][0] + bv);
        float v1 = sspf(acc1[rt][ct][1] + bv);
        float v2 = sspf(acc1[rt][ct][2] + bv);
        float v3 = sspf(acc1[rt][ct][3] + bv);
        uintT u01 = f2bf2(v0, v1), u23 = f2bf2(v2, v3);
        T[(row + 0) * 264 + col] = (ushortT)u01;
        T[(row + 1) * 264 + col] = (ushortT)(u01 >> 16);
        T[(row + 2) * 264 + col] = (ushortT)u23;
        T[(row + 3) * 264 + col] = (ushortT)(u23 >> 16);
      }
    }
  }
  __syncthreads();

  // phase 2: Wf = t @ w2t + b2, write table rows directly
  f32x4 acc[4][4];
#pragma unroll
  for (int rt = 0; rt < 4; ++rt)
#pragma unroll
    for (int ct = 0; ct < 4; ++ct) acc[rt][ct] = (f32x4){0.f, 0.f, 0.f, 0.f};
  mfma_kloop(T, w2t + (size_t)c0 * HID, acc, lm, q);

#pragma unroll
  for (int ct = 0; ct < 4; ++ct) {
    const int col = c0 + ct * 16 + lm;
    const float bv = b2[col];
#pragma unroll
    for (int rt = 0; rt < 4; ++rt) {
      const int row = rt * 16 + q * 4;
#pragma unroll
      for (int r = 0; r < 4; ++r) {
        int g = tb * 64 + row + r;
        if (g < NT_PTS) table[(size_t)g * HID + col] = f2bf(acc[rt][ct][r] + bv);
      }
    }
  }
}

// ---------------------------------------------------------------------------
// CSR build: histogram -> hierarchical scan -> fused slot-assign + edge_prep
__global__ __launch_bounds__(256) void hist_k(const int* __restrict__ ei,
                                              int* __restrict__ counts) {
  int e = blockIdx.x * 256 + threadIdx.x;
  if (e < N_EDGES) atomicAdd(&counts[ei[N_EDGES + e]], 1);
}

__global__ __launch_bounds__(256) void scanA_k(const int* __restrict__ counts,
                                               int* __restrict__ bsum) {
  const int b = blockIdx.x, tid = threadIdx.x;
  const int base = b * 1024 + tid * 4;
  int s = 0;
  if (base + 3 < N_NODES) {
    int4 v = *(const int4*)(counts + base);
    s = v.x + v.y + v.z + v.w;
  } else {
#pragma unroll
    for (int i = 0; i < 4; ++i) {
      int n = base + i;
      if (n < N_NODES) s += counts[n];
    }
  }
#pragma unroll
  for (int m = 32; m; m >>= 1) s += __shfl_xor(s, m, 64);
  __shared__ int ws[4];
  if ((tid & 63) == 0) ws[tid >> 6] = s;
  __syncthreads();
  if (tid == 0) bsum[b] = ws[0] + ws[1] + ws[2] + ws[3];
}

__global__ __launch_bounds__(128) void scanB_k(int* __restrict__ bsum,
                                               int* __restrict__ row_start) {
  __shared__ int sh[SCAN_NB];
  const int tid = threadIdx.x;
  if (tid < SCAN_NB) sh[tid] = bsum[tid];
  __syncthreads();
  if (tid == 0) {
    int acc = 0;
    for (int i = 0; i < SCAN_NB; ++i) { int t = sh[i]; sh[i] = acc; acc += t; }
    row_start[N_NODES] = acc;
  }
  __syncthreads();
  if (tid < SCAN_NB) bsum[tid] = sh[tid];
}

__global__ __launch_bounds__(256) void scanC_k(const int* __restrict__ counts,
                                               const int* __restrict__ bsum,
                                               int* __restrict__ row_start,
                                               int* __restrict__ cursor) {
  const int b = blockIdx.x, tid = threadIdx.x;
  const int base = b * 1024 + tid * 4;
  int c[4];
  int s = 0;
#pragma unroll
  for (int i = 0; i < 4; ++i) {
    int n = base + i;
    c[i] = (n < N_NODES) ? counts[n] : 0;
    s += c[i];
  }
  __shared__ int sc[256];
  sc[tid] = s;
  __syncthreads();
  int acc = s;
  for (int off = 1; off < 256; off <<= 1) {
    int v = (tid >= off) ? sc[tid - off] : 0;
    __syncthreads();
    acc += v;
    sc[tid] = acc;
    __syncthreads();
  }
  int off0 = acc - s + bsum[b];
#pragma unroll
  for (int i = 0; i < 4; ++i) {
    int n = base + i;
    if (n < N_NODES) {
      row_start[n] = off0;
      cursor[n] = off0;
      off0 += c[i];
    }
  }
}

// fused slot-assign + edge_prep: per edge, claim CSR slot via atomic cursor,
// write packed meta {src_bits, rounded_row, cs, 0} directly to that slot.
__global__ __launch_bounds__(256) void edge_prep_k(const int* __restrict__ ei,
                                                   const float* __restrict__ pos,
                                                   int* __restrict__ cursor,
                                                   float4* __restrict__ csr_meta) {
  int e = blockIdx.x * 256 + threadIdx.x;
  if (e >= N_EDGES) return;
  int s = ei[e], d = ei[N_EDGES + e];
  float dx = pos[s * 3 + 0] - pos[d * 3 + 0];
  float dy = pos[s * 3 + 1] - pos[d * 3 + 1];
  float dz = pos[s * 3 + 2] - pos[d * 3 + 2];
  float dist = sqrtf(fmaf(dx, dx, fmaf(dy, dy, dz * dz)) + 1e-12f);
  union { int i; float f; } sb;
  sb.i = s;
  float4 m;
  m.x = sb.f;
  m.y = fminf(floorf(dist * INV_H + 0.5f), 2048.0f);  // nearest row index
  m.z = 0.5f * (cosf(dist * (3.14159265358979323846f / 5.0f)) + 1.0f);
  m.w = 0.0f;
  int slot = atomicAdd(&cursor[d], 1);
  csr_meta[slot] = m;
}

// fused gather: agg[n] = sum over CSR edges of x1[src] * table[row] * C
// nearest-neighbor table (1 row/edge); 2-way unrolled edge loop.
__global__ __launch_bounds__(256) void gather2_k(const int* __restrict__ row_start,
                                                 const float4* __restrict__ csr_meta,
                                                 const ushortT* __restrict__ x1,
                                                 const ushortT* __restrict__ table,
                                                 ushortT* __restrict__ agg) {
  int node = blockIdx.x * 4 + (threadIdx.x >> 6);
  int lane = threadIdx.x & 63;
  if (node >= N_NODES) return;
  int a = row_start[node], b = row_start[node + 1];
  const int co = lane * 4;
  float s0 = 0.f, s1 = 0.f, s2 = 0.f, s3 = 0.f;
  int j = a;
  for (; j + 1 < b; j += 2) {
    float4 mtA = csr_meta[j];
    float4 mtB = csr_meta[j + 1];
    union { float f; int i; } sa, sb2;
    sa.f = mtA.x;
    sb2.f = mtB.x;
    int iA = (int)mtA.y, iB = (int)mtB.y;
    uint2 taA = *(const uint2*)(table + (size_t)iA * HID + co);
    uint2 xvA = *(const uint2*)(x1 + (size_t)sa.i * HID + co);
    uint2 taB = *(const uint2*)(table + (size_t)iB * HID + co);
    uint2 xvB = *(const uint2*)(x1 + (size_t)sb2.i * HID + co);
    // edge j
    {
      float cs = mtA.z;
      s0 = fmaf(bflo(xvA.x) * bflo(taA.x), cs, s0);
      s1 = fmaf(bfhi(xvA.x) * bfhi(taA.x), cs, s1);
      s2 = fmaf(bflo(xvA.y) * bflo(taA.y), cs, s2);
      s3 = fmaf(bfhi(xvA.y) * bfhi(taA.y), cs, s3);
    }
    // edge j+1
    {
      float cs = mtB.z;
      s0 = fmaf(bflo(xvB.x) * bflo(taB.x), cs, s0);
      s1 = fmaf(bfhi(xvB.x) * bfhi(taB.x), cs, s1);
      s2 = fmaf(bflo(xvB.y) * bflo(taB.y), cs, s2);
      s3 = fmaf(bfhi(xvB.y) * bfhi(taB.y), cs, s3);
    }
  }
  if (j < b) {
    float4 mt = csr_meta[j];
    union { float f; int i; } sb;
    sb.f = mt.x;
    int i = (int)mt.y;
    float cs = mt.z;
    uint2 ta = *(const uint2*)(table + (size_t)i * HID + co);
    uint2 xv = *(const uint2*)(x1 + (size_t)sb.i * HID + co);
    s0 = fmaf(bflo(xv.x) * bflo(ta.x), cs, s0);
    s1 = fmaf(bfhi(xv.x) * bfhi(ta.x), cs, s1);
    s2 = fmaf(bflo(xv.y) * bflo(ta.y), cs, s2);
    s3 = fmaf(bfhi(xv.y) * bfhi(ta.y), cs, s3);
  }
  uint2 o;
  o.x = f2bf2(s0, s1);
  o.y = f2bf2(s2, s3);
  *(uint2*)(agg + (size_t)node * HID + co) = o;
}

// ---------------------------------------------------------------------------
// Weight prep: fp32 W[K,256] -> bf16 Wt[256,K], square 256x256 matrices
__global__ __launch_bounds__(256) void wconv_k(const float* __restrict__ src,
                                               ushortT* __restrict__ dst) {
  __shared__ float tile[64][65];
  const int b = blockIdx.x;
  const int mat = b >> 4, t = b & 15;
  const int tr = (t >> 2) * 64, tc = (t & 3) * 64;
  const float* S = src + (size_t)mat * HID * HID;
  ushortT* D = dst + (size_t)mat * HID * HID;
  const int tid = threadIdx.x;
#pragma unroll
  for (int i = 0; i < 16; ++i) {
    int idx = i * 256 + tid;
    int r = idx >> 6, c = idx & 63;
    tile[r][c] = S[(size_t)(tr + r) * HID + tc + c];
  }
  __syncthreads();
#pragma unroll
  for (int i = 0; i < 16; ++i) {
    int idx = i * 256 + tid;
    int n = idx >> 6, k = idx & 63;
    D[(size_t)(tc + n) * HID + tr + k] = f2bf(tile[k][n]);
  }
}

// mlp_w1 [L][50][256] fp32 -> w1t [L][256][64] bf16 (k padded with zeros)
__global__ __launch_bounds__(256) void w1conv_k(const float* __restrict__ src,
                                                ushortT* __restrict__ dst) {
  const int l = blockIdx.x;
  const int n = threadIdx.x;
  const float* S = src + (size_t)l * NGAUSS * HID;
  ushortT* D = dst + (size_t)l * HID * 64;
  for (int k = 0; k < 64; ++k) {
    float v = (k < NGAUSS) ? S[(size_t)k * HID + n] : 0.0f;
    D[(size_t)n * 64 + k] = f2bf(v);
  }
}

__global__ __launch_bounds__(256) void tail_k(const int* __restrict__ batch,
                                              float* __restrict__ out) {
  int i = blockIdx.x * 256 + threadIdx.x;
  if (i < N_NODES) out[i] = (float)batch[i];
}

// ---------------------------------------------------------------------------
extern "C" void kernel_launch(void* const* d_in, const int* in_sizes, int n_in,
                              void* d_out, int out_size, void* d_ws, size_t ws_size,
                              hipStream_t stream) {
  const int* z = (const int*)d_in[0];
  const float* pos = (const float*)d_in[1];
  const int* batch = (const int*)d_in[2];
  const int* ei = (const int*)d_in[3];
  const float* emb = (const float*)d_in[4];
  const float* mlp_w1 = (const float*)d_in[5];
  const float* mlp_b1 = (const float*)d_in[6];
  const float* mlp_w2 = (const float*)d_in[7];
  const float* mlp_b2 = (const float*)d_in[8];
  const float* lin1_w = (const float*)d_in[9];
  const float* lin2_w = (const float*)d_in[10];
  const float* lin2_b = (const float*)d_in[11];
  const float* lin_w = (const float*)d_in[12];
  const float* lin_b = (const float*)d_in[13];
  const float* proj_w = (const float*)d_in[14];
  const float* proj_b = (const float*)d_in[15];
  const float* ln_g = (const float*)d_in[16];
  const float* ln_b = (const float*)d_in[17];
  float* out = (float*)d_out;  // fp32: p [N*256] then batch [N]

  const size_t NH = (size_t)N_NODES * HID;
  const size_t WSZ = (size_t)HID * HID;

  // ---- workspace layout (~270 MB) ----
  char* w = (char*)d_ws;
  ushortT* h = (ushortT*)w;      w += NH * 2;
  ushortT* x1 = (ushortT*)w;     w += NH * 2;
  ushortT* agg = (ushortT*)w;    w += NH * 2;
  ushortT* lin1t = (ushortT*)w;  w += 6 * WSZ * 2;
  ushortT* lin2t = (ushortT*)w;  w += 6 * WSZ * 2;
  ushortT* lint = (ushortT*)w;   w += 6 * WSZ * 2;
  ushortT* w2t = (ushortT*)w;    w += 6 * WSZ * 2;
  ushortT* projt = (ushortT*)w;  w += WSZ * 2;
  ushortT* w1t = (ushortT*)w;    w += 6 * (size_t)HID * 64 * 2;
  ushortT* tables = (ushortT*)w; w += 6 * (size_t)NT_PTS * HID * 2;
  int* counts = (int*)w;         w += (size_t)N_NODES * 4;
  int* cursor = (int*)w;         w += (size_t)N_NODES * 4;
  int* row_start = (int*)w;      w += (size_t)(N_NODES + 64) * 4;
  float4* csr_meta = (float4*)w; w += (size_t)N_EDGES * 16;
  int* bsum = (int*)w;           w += (size_t)128 * 4;

  // ---- CSR build (perm fused into edge_prep) ----
  hipMemsetAsync(counts, 0, (size_t)N_NODES * 4, stream);
  hist_k<<<(N_EDGES + 255) / 256, 256, 0, stream>>>(ei, counts);
  scanA_k<<<SCAN_NB, 256, 0, stream>>>(counts, bsum);
  scanB_k<<<1, 128, 0, stream>>>(bsum, row_start);
  scanC_k<<<SCAN_NB, 256, 0, stream>>>(counts, bsum, row_start, cursor);
  edge_prep_k<<<(N_EDGES + 255) / 256, 256, 0, stream>>>(ei, pos, cursor, csr_meta);

  // ---- weight prep ----
  wconv_k<<<6 * 16, 256, 0, stream>>>(lin1_w, lin1t);
  wconv_k<<<6 * 16, 256, 0, stream>>>(lin2_w, lin2t);
  wconv_k<<<6 * 16, 256, 0, stream>>>(lin_w, lint);
  wconv_k<<<6 * 16, 256, 0, stream>>>(mlp_w2, w2t);
  wconv_k<<<16, 256, 0, stream>>>(proj_w, projt);
  w1conv_k<<<6, 256, 0, stream>>>(mlp_w1, w1t);

  // ---- filter tables (all 6 layers, one dispatch) ----
  table_k<<<6 * TB_BLOCKS, 256, 0, stream>>>(w1t, mlp_b1, w2t, mlp_b2, tables);

  const int MB64 = (N_NODES + 63) / 64;
  // fused embed + x1_0 GEMM (writes h and x1)
  mgemm_embed<<<MB64, 256, 0, stream>>>(z, emb, lin1t, h, x1, N_NODES);
  for (int l = 0; l < NLAYERS; ++l) {
    const size_t oW = (size_t)l * WSZ;
    const size_t o1 = (size_t)l * HID;
    gather2_k<<<(N_NODES + 3) / 4, 256, 0, stream>>>(
        row_start, csr_meta, x1,
        tables + (size_t)l * NT_PTS * HID, agg);
    if (l < NLAYERS - 1) {
      mgemm3<0><<<MB64, 512, 0, stream>>>(agg, lin2t + oW, lin2_b + o1,
                                          lint + oW, lin_b + o1, h,
                                          lin1t + (size_t)(l + 1) * WSZ, nullptr,
                                          x1, nullptr, nullptr, nullptr, N_NODES);
    } else {
      mgemm3<1><<<MB64, 512, 0, stream>>>(agg, lin2t + oW, lin2_b + o1,
                                          lint + oW, lin_b + o1, h,
                                          projt, proj_b,
                                          nullptr, ln_g, ln_b, out, N_NODES);
    }
  }
  tail_k<<<(N_NODES + 255) / 256, 256, 0, stream>>>(batch, out + NH);
}

// Round 19
// 1266.107 us; speedup vs baseline: 1.3913x; 1.0143x over previous
//
#include <hip/hip_runtime.h>

#define N_NODES 100000
#define N_EDGES 320000
#define HID 256
#define NGAUSS 50
#define NLAYERS 6
#define SCAN_NB 98   // ceil(N_NODES/1024)
#define NT_PTS 2049  // filter table points over [0,8], h=1/256, nearest-neighbor
#define TB_BLOCKS 33 // ceil(2049/64)
#define H_STEP 0.00390625f
#define INV_H 256.0f

typedef unsigned short ushortT;
typedef unsigned int uintT;
typedef __attribute__((ext_vector_type(8))) short bf16x8;  // 8 bf16 = 4 VGPR
typedef __attribute__((ext_vector_type(4))) float f32x4;
typedef __attribute__((ext_vector_type(2))) __bf16 bf16v2;

// ---------------------------------------------------------------------------
// ShiftedSoftplus via native exp2/log2:
//   softplus(x) - ln2 = max(x,0) + ln2*log2(1 + exp2(-|x|*log2e)) - ln2
__device__ __forceinline__ float sspf(float x) {
  float e = exp2f(-fabsf(x) * 1.44269504088896340736f);
  float l = __log2f(1.0f + e);
  return fmaf(0.69314718055994530942f, l,
              fmaxf(x, 0.0f) - 0.69314718055994530942f);
}

__device__ __forceinline__ float bf2f(ushortT u) {
  union { uintT i; float f; } c;
  c.i = ((uintT)u) << 16;
  return c.f;
}

// unpack low/high bf16 of a packed dword (1 VALU op each; reinterpret is free)
__device__ __forceinline__ float bflo(uintT u) {
  union { uintT i; float f; } c;
  c.i = u << 16;
  return c.f;
}
__device__ __forceinline__ float bfhi(uintT u) {
  union { uintT i; float f; } c;
  c.i = u & 0xFFFF0000u;
  return c.f;
}

// native bf16 converts (RNE) -> v_cvt_pk_bf16_f32 on gfx950
__device__ __forceinline__ ushortT f2bf(float f) {
  union { __bf16 b; ushortT u; } c;
  c.b = (__bf16)f;
  return c.u;
}
__device__ __forceinline__ uintT f2bf2(float lo, float hi) {
  union { bf16v2 v; uintT u; } c;
  c.v = (bf16v2){(__bf16)lo, (__bf16)hi};
  return c.u;
}

// ---------------------------------------------------------------------------
// MFMA K-loops over K=256. A in LDS bf16 (row stride 264), Bt row-major [N,K].
//   A-frag: lane(16q+m) holds A[m][8q..8q+8); C/D: lane(16q+c) reg r -> row 4q+r, col c
__device__ __forceinline__ void mfma_kloop(const ushortT* As, const ushortT* Bt,
                                           f32x4 (&acc)[4][4], int lm, int q) {
#pragma unroll
  for (int k = 0; k < 256; k += 32) {
    bf16x8 a[4], b[4];
#pragma unroll
    for (int rt = 0; rt < 4; ++rt)
      a[rt] = *(const bf16x8*)&As[(rt * 16 + lm) * 264 + k + 8 * q];
#pragma unroll
    for (int ct = 0; ct < 4; ++ct)
      b[ct] = *(const bf16x8*)(Bt + (size_t)(ct * 16 + lm) * HID + k + 8 * q);
#pragma unroll
    for (int rt = 0; rt < 4; ++rt)
#pragma unroll
      for (int ct = 0; ct < 4; ++ct)
        acc[rt][ct] = __builtin_amdgcn_mfma_f32_16x16x32_bf16(a[rt], b[ct], acc[rt][ct], 0, 0, 0);
  }
}

// 8-wave variant, 32-col stripe per wave, acc[4][2] (measured-best plain form:
// per-k-step loads; the compiler's sunk-load schedule beat forced preloads).
__device__ __forceinline__ void mfma_kloop32(const ushortT* As, const ushortT* Bt,
                                             f32x4 (&acc)[4][2], int c0, int lm, int q) {
#pragma unroll
  for (int k = 0; k < 256; k += 32) {
    bf16x8 b[2];
#pragma unroll
    for (int ct = 0; ct < 2; ++ct)
      b[ct] = *(const bf16x8*)(Bt + (size_t)(c0 + ct * 16 + lm) * HID + k + 8 * q);
#pragma unroll
    for (int rt = 0; rt < 4; ++rt) {
      bf16x8 a = *(const bf16x8*)&As[(rt * 16 + lm) * 264 + k + 8 * q];
#pragma unroll
      for (int ct = 0; ct < 2; ++ct)
        acc[rt][ct] = __builtin_amdgcn_mfma_f32_16x16x32_bf16(a, b[ct], acc[rt][ct], 0, 0, 0);
    }
  }
}

// acc tile -> LDS (bf16, A layout), 4-wave version
__device__ __forceinline__ void acc_to_lds(ushortT* As, const f32x4 (&acc)[4][4],
                                           int c0, int lm, int q) {
#pragma unroll
  for (int ct = 0; ct < 4; ++ct) {
    const int col = c0 + ct * 16 + lm;
#pragma unroll
    for (int rt = 0; rt < 4; ++rt) {
      const int row = rt * 16 + q * 4;
      uintT u01 = f2bf2(acc[rt][ct][0], acc[rt][ct][1]);
      uintT u23 = f2bf2(acc[rt][ct][2], acc[rt][ct][3]);
      As[(row + 0) * 264 + col] = (ushortT)u01;
      As[(row + 1) * 264 + col] = (ushortT)(u01 >> 16);
      As[(row + 2) * 264 + col] = (ushortT)u23;
      As[(row + 3) * 264 + col] = (ushortT)(u23 >> 16);
    }
  }
}

// coalesced LDS tile -> global (row-contiguous uint4), 256-thread version
__device__ __forceinline__ void store_tile64(const ushortT* As,
                                             ushortT* __restrict__ dst,
                                             int m0, int M, int tid) {
#pragma unroll
  for (int i = 0; i < 8; ++i) {
    int idx = i * 256 + tid;
    int r = idx >> 5, ch = idx & 31;
    int m = m0 + r;
    if (m < M)
      *(uint4*)(dst + (size_t)m * HID + ch * 8) = *(const uint4*)&As[r * 264 + ch * 8];
  }
}

// ---------------------------------------------------------------------------
// Fused embed + x1_0 GEMM: stage emb[z[m]] (fp32->bf16) into LDS AND h,
// then C = h @ lin1t. Eliminates the separate embed dispatch + h re-read.
__global__ __launch_bounds__(256) void mgemm_embed(const int* __restrict__ z,
                                                   const float* __restrict__ emb,
                                                   const ushortT* __restrict__ Bt,
                                                   ushortT* __restrict__ h,
                                                   ushortT* __restrict__ Cbf, int M) {
  __shared__ ushortT As[64 * 264];
  const int tid = threadIdx.x;
  const int m0 = blockIdx.x * 64;

#pragma unroll
  for (int i = 0; i < 8; ++i) {
    int idx = i * 256 + tid;
    int r = idx >> 5, ch = idx & 31;
    int m = m0 + r;
    uint4 u = make_uint4(0, 0, 0, 0);
    if (m < M) {
      const float* er = emb + (size_t)z[m] * HID + ch * 8;
      float4 f0 = *(const float4*)er;
      float4 f1 = *(const float4*)(er + 4);
      u.x = f2bf2(f0.x, f0.y);
      u.y = f2bf2(f0.z, f0.w);
      u.z = f2bf2(f1.x, f1.y);
      u.w = f2bf2(f1.z, f1.w);
      *(uint4*)(h + (size_t)m * HID + ch * 8) = u;
    }
    *(uint4*)&As[r * 264 + ch * 8] = u;
  }
  __syncthreads();

  const int lane = tid & 63;
  const int lm = lane & 15, q = lane >> 4;
  const int c0 = (tid >> 6) * 64;

  f32x4 acc[4][4];
#pragma unroll
  for (int rt = 0; rt < 4; ++rt)
#pragma unroll
    for (int ct = 0; ct < 4; ++ct) acc[rt][ct] = (f32x4){0.f, 0.f, 0.f, 0.f};

  mfma_kloop(As, Bt + (size_t)c0 * HID, acc, lm, q);
  __syncthreads();  // all waves done reading As
  acc_to_lds(As, acc, c0, lm, q);
  __syncthreads();
  store_tile64(As, Cbf, m0, M, tid);
}

// ---------------------------------------------------------------------------
// Fused interaction tail + next-layer head (3 chained K=256 GEMMs, LDS-resident).
// 512 threads / 8 waves; 64-row tile; each wave owns a 32-col stripe, acc[4][2].
//   x2 = ssp(agg @ B1t + b1)
//   hn = h + x2 @ B2t + b2            (write h)
//   LAST=0: x1out = hn @ B3t (bf16)
//   LAST=1: out = SiLU(LayerNorm(hn @ B3t + b3)) fp32 -- LN fused in-block
//           (LDS reused as fp32 [32][260] tile, two halves; fp32 end-to-end)
template <int LAST>
__global__ __launch_bounds__(512, 2) void mgemm3(const ushortT* __restrict__ A,
                                                 const ushortT* __restrict__ B1t,
                                                 const float* __restrict__ b1v,
                                                 const ushortT* __restrict__ B2t,
                                                 const float* __restrict__ b2v,
                                                 ushortT* __restrict__ h,
                                                 const ushortT* __restrict__ B3t,
                                                 const float* __restrict__ b3v,
                                                 ushortT* __restrict__ x1out,
                                                 const float* __restrict__ lng,
                                                 const float* __restrict__ lnb,
                                                 float* __restrict__ outp, int M) {
  __shared__ ushortT As[64 * 264];  // 33792 B
  const int tid = threadIdx.x;
  const int m0 = blockIdx.x * 64;

  // stage 64x256 tile: 2048 uint4 over 512 threads
#pragma unroll
  for (int i = 0; i < 4; ++i) {
    int idx = i * 512 + tid;
    int r = idx >> 5, ch = idx & 31;
    int m = m0 + r;
    uint4 u = make_uint4(0, 0, 0, 0);
    if (m < M) u = *(const uint4*)(A + (size_t)m * HID + ch * 8);
    *(uint4*)&As[r * 264 + ch * 8] = u;
  }
  __syncthreads();

  const int lane = tid & 63;
  const int lm = lane & 15, q = lane >> 4;
  const int c0 = (tid >> 6) * 32;  // wave's 32-col stripe

  f32x4 acc[4][2];
#pragma unroll
  for (int rt = 0; rt < 4; ++rt)
#pragma unroll
    for (int ct = 0; ct < 2; ++ct) acc[rt][ct] = (f32x4){0.f, 0.f, 0.f, 0.f};
  mfma_kloop32(As, B1t, acc, c0, lm, q);
  __syncthreads();  // all waves done reading As

  // epi1: x2 = ssp(acc + b1) -> As
#pragma unroll
  for (int ct = 0; ct < 2; ++ct) {
    const int col = c0 + ct * 16 + lm;
    const float bv = b1v[col];
#pragma unroll
    for (int rt = 0; rt < 4; ++rt) {
      const int row = rt * 16 + q * 4;
      float v0 = sspf(acc[rt][ct][0] + bv);
      float v1 = sspf(acc[rt][ct][1] + bv);
      float v2 = sspf(acc[rt][ct][2] + bv);
      float v3 = sspf(acc[rt][ct][3] + bv);
      uintT u01 = f2bf2(v0, v1), u23 = f2bf2(v2, v3);
      As[(row + 0) * 264 + col] = (ushortT)u01;
      As[(row + 1) * 264 + col] = (ushortT)(u01 >> 16);
      As[(row + 2) * 264 + col] = (ushortT)u23;
      As[(row + 3) * 264 + col] = (ushortT)(u23 >> 16);
    }
  }
  __syncthreads();

#pragma unroll
  for (int rt = 0; rt < 4; ++rt)
#pragma unroll
    for (int ct = 0; ct < 2; ++ct) acc[rt][ct] = (f32x4){0.f, 0.f, 0.f, 0.f};
  mfma_kloop32(As, B2t, acc, c0, lm, q);
  __syncthreads();  // all waves done reading As

  // epi2: hn = acc + b2 + h_old -> h (scattered) and As
#pragma unroll
  for (int ct = 0; ct < 2; ++ct) {
    const int col = c0 + ct * 16 + lm;
    const float bv = b2v[col];
#pragma unroll
    for (int rt = 0; rt < 4; ++rt) {
      const int mb = m0 + rt * 16 + q * 4;
      const int row = rt * 16 + q * 4;
      float v[4];
#pragma unroll
      for (int r = 0; r < 4; ++r) {
        float res = (mb + r < M) ? bf2f(h[(size_t)(mb + r) * HID + col]) : 0.0f;
        v[r] = acc[rt][ct][r] + bv + res;
      }
      uintT u01 = f2bf2(v[0], v[1]), u23 = f2bf2(v[2], v[3]);
      As[(row + 0) * 264 + col] = (ushortT)u01;
      As[(row + 1) * 264 + col] = (ushortT)(u01 >> 16);
      As[(row + 2) * 264 + col] = (ushortT)u23;
      As[(row + 3) * 264 + col] = (ushortT)(u23 >> 16);
      if (mb + 0 < M) h[(size_t)(mb + 0) * HID + col] = (ushortT)u01;
      if (mb + 1 < M) h[(size_t)(mb + 1) * HID + col] = (ushortT)(u01 >> 16);
      if (mb + 2 < M) h[(size_t)(mb + 2) * HID + col] = (ushortT)u23;
      if (mb + 3 < M) h[(size_t)(mb + 3) * HID + col] = (ushortT)(u23 >> 16);
    }
  }
  __syncthreads();

#pragma unroll
  for (int rt = 0; rt < 4; ++rt)
#pragma unroll
    for (int ct = 0; ct < 2; ++ct) acc[rt][ct] = (f32x4){0.f, 0.f, 0.f, 0.f};
  mfma_kloop32(As, B3t, acc, c0, lm, q);

  if constexpr (LAST) {
    // fused LayerNorm + SiLU, fp32 end-to-end via LDS (two 32-row halves)
    __syncthreads();  // all waves done reading As (kloop3)
    float* Pf = (float*)As;
    const int PSTR = 260;  // 32*260*4 = 33280 B <= 33792 B
    const int wv = tid >> 6;
#pragma unroll
    for (int half = 0; half < 2; ++half) {
      // write this half's rows (rt = 2*half .. 2*half+1) + bias into LDS fp32
#pragma unroll
      for (int ct = 0; ct < 2; ++ct) {
        const int col = c0 + ct * 16 + lm;
        const float bv = b3v[col];
#pragma unroll
        for (int rtl = 0; rtl < 2; ++rtl) {
          const int rt = half * 2 + rtl;
          const int lrow = rtl * 16 + q * 4;
#pragma unroll
          for (int r = 0; r < 4; ++r)
            Pf[(lrow + r) * PSTR + col] = acc[rt][ct][r] + bv;
        }
      }
      __syncthreads();
      // LN+SiLU: wave wv owns rows wv*4..wv*4+3 of this half; lane holds 4 cols
#pragma unroll
      for (int rr = 0; rr < 4; ++rr) {
        const int lrow = wv * 4 + rr;
        const int grow = m0 + half * 32 + lrow;
        float4 v4 = *(float4*)&Pf[lrow * PSTR + lane * 4];
        float s = v4.x + v4.y + v4.z + v4.w;
#pragma unroll
        for (int m = 32; m; m >>= 1) s += __shfl_xor(s, m, 64);
        float mu = s * (1.0f / 256.0f);
        float d0 = v4.x - mu, d1 = v4.y - mu, d2 = v4.z - mu, d3 = v4.w - mu;
        float qv = d0 * d0 + d1 * d1 + d2 * d2 + d3 * d3;
#pragma unroll
        for (int m = 32; m; m >>= 1) qv += __shfl_xor(qv, m, 64);
        float rstd = rsqrtf(qv * (1.0f / 256.0f) + 1e-5f);
        if (grow < M) {
          float4 g4 = *(const float4*)&lng[lane * 4];
          float4 b4 = *(const float4*)&lnb[lane * 4];
          float y0 = d0 * rstd * g4.x + b4.x;
          float y1 = d1 * rstd * g4.y + b4.y;
          float y2 = d2 * rstd * g4.z + b4.z;
          float y3 = d3 * rstd * g4.w + b4.w;
          float4 o;
          o.x = y0 * (1.0f / (1.0f + exp2f(-y0 * 1.44269504088896340736f)));
          o.y = y1 * (1.0f / (1.0f + exp2f(-y1 * 1.44269504088896340736f)));
          o.z = y2 * (1.0f / (1.0f + exp2f(-y2 * 1.44269504088896340736f)));
          o.w = y3 * (1.0f / (1.0f + exp2f(-y3 * 1.44269504088896340736f)));
          *(float4*)&outp[(size_t)grow * HID + lane * 4] = o;
        }
      }
      __syncthreads();  // before next half reuses Pf
    }
  } else {
#pragma unroll
    for (int ct = 0; ct < 2; ++ct) {
      const int col = c0 + ct * 16 + lm;
#pragma unroll
      for (int rt = 0; rt < 4; ++rt) {
        const int mb = m0 + rt * 16 + q * 4;
        uintT u01 = f2bf2(acc[rt][ct][0], acc[rt][ct][1]);
        uintT u23 = f2bf2(acc[rt][ct][2], acc[rt][ct][3]);
        if (mb + 0 < M) x1out[(size_t)(mb + 0) * HID + col] = (ushortT)u01;
        if (mb + 1 < M) x1out[(size_t)(mb + 1) * HID + col] = (ushortT)(u01 >> 16);
        if (mb + 2 < M) x1out[(size_t)(mb + 2) * HID + col] = (ushortT)u23;
        if (mb + 3 < M) x1out[(size_t)(mb + 3) * HID + col] = (ushortT)(u23 >> 16);
      }
    }
  }
}

// ---------------------------------------------------------------------------
// Filter table build: table[l][g][:] = ssp(rbf(g*H_STEP) @ w1t[l] + b1[l]) @ w2t[l] + b2[l]
__global__ __launch_bounds__(256) void table_k(
    const ushortT* __restrict__ w1t_all, const float* __restrict__ b1_all,
    const ushortT* __restrict__ w2t_all, const float* __restrict__ b2_all,
    ushortT* __restrict__ table_all) {
  __shared__ ushortT T[64 * 264];
  ushortT* R = T;  // rbf tile aliases T head; barrier before T write

  const int blk = blockIdx.x;
  const int l = blk / TB_BLOCKS, tb = blk % TB_BLOCKS;
  const ushortT* w1t = w1t_all + (size_t)l * HID * 64;
  const float* b1 = b1_all + (size_t)l * HID;
  const ushortT* w2t = w2t_all + (size_t)l * HID * HID;
  const float* b2 = b2_all + (size_t)l * HID;
  ushortT* table = table_all + (size_t)l * NT_PTS * HID;

  const int tid = threadIdx.x;
  const float delta = 5.0f / 49.0f;
  const float coeff2 = (-0.5f / (delta * delta)) * 1.44269504088896340736f;
#pragma unroll
  for (int i = 0; i < 16; ++i) {
    int idx = i * 256 + tid;
    int e = idx >> 6, k = idx & 63;
    float v = 0.0f;
    if (k < NGAUSS) {
      float dist = (float)(tb * 64 + e) * H_STEP;
      float dd = dist - (float)k * delta;
      v = exp2f(coeff2 * dd * dd);
    }
    R[e * 72 + k] = f2bf(v);
  }
  __syncthreads();

  const int lane = tid & 63;
  const int lm = lane & 15, q = lane >> 4;
  const int c0 = (tid >> 6) * 64;

  // phase 1: t = ssp(R @ w1t + b1), K=64
  {
    f32x4 acc1[4][4];
#pragma unroll
    for (int rt = 0; rt < 4; ++rt)
#pragma unroll
      for (int ct = 0; ct < 4; ++ct) acc1[rt][ct] = (f32x4){0.f, 0.f, 0.f, 0.f};
#pragma unroll
    for (int k = 0; k < 64; k += 32) {
      bf16x8 a[4], b[4];
#pragma unroll
      for (int rt = 0; rt < 4; ++rt)
        a[rt] = *(const bf16x8*)&R[(rt * 16 + lm) * 72 + k + 8 * q];
#pragma unroll
      for (int ct = 0; ct < 4; ++ct)
        b[ct] = *(const bf16x8*)(w1t + (size_t)(c0 + ct * 16 + lm) * 64 + k + 8 * q);
#pragma unroll
      for (int rt = 0; rt < 4; ++rt)
#pragma unroll
        for (int ct = 0; ct < 4; ++ct)
          acc1[rt][ct] = __builtin_amdgcn_mfma_f32_16x16x32_bf16(a[rt], b[ct], acc1[rt][ct], 0, 0, 0);
    }
    __syncthreads();  // done reading R before T (aliased) is written
#pragma unroll
    for (int ct = 0; ct < 4; ++ct) {
      const int col = c0 + ct * 16 + lm;
      const float bv = b1[col];
#pragma unroll
      for (int rt = 0; rt < 4; ++rt) {
        const int row = rt * 16 + q * 4;
        float v0 = sspf(acc1[rt][ct][0] + bv);
        float v1 = sspf(acc1[rt][ct][1] + bv);
        float v2 = sspf(acc1[rt][ct][2] + bv);
        float v3 = sspf(acc1[rt][ct][3] + bv);
        uintT u01 = f2bf2(v0, v1), u23 = f2bf2(v2, v3);
        T[(row + 0) * 264 + col] = (ushortT)u01;
        T[(row + 1) * 264 + col] = (ushortT)(u01 >> 16);
        T[(row + 2) * 264 + col] = (ushortT)u23;
        T[(row + 3) * 264 + col] = (ushortT)(u23 >> 16);
      }
    }
  }
  __syncthreads();

  // phase 2: Wf = t @ w2t + b2, write table rows directly
  f32x4 acc[4][4];
#pragma unroll
  for (int rt = 0; rt < 4; ++rt)
#pragma unroll
    for (int ct = 0; ct < 4; ++ct) acc[rt][ct] = (f32x4){0.f, 0.f, 0.f, 0.f};
  mfma_kloop(T, w2t + (size_t)c0 * HID, acc, lm, q);

#pragma unroll
  for (int ct = 0; ct < 4; ++ct) {
    const int col = c0 + ct * 16 + lm;
    const float bv = b2[col];
#pragma unroll
    for (int rt = 0; rt < 4; ++rt) {
      const int row = rt * 16 + q * 4;
#pragma unroll
      for (int r = 0; r < 4; ++r) {
        int g = tb * 64 + row + r;
        if (g < NT_PTS) table[(size_t)g * HID + col] = f2bf(acc[rt][ct][r] + bv);
      }
    }
  }
}

// ---------------------------------------------------------------------------
// CSR build: histogram -> hierarchical scan -> fused slot-assign + edge_prep
__global__ __launch_bounds__(256) void hist_k(const int* __restrict__ ei,
                                              int* __restrict__ counts) {
  int e = blockIdx.x * 256 + threadIdx.x;
  if (e < N_EDGES) atomicAdd(&counts[ei[N_EDGES + e]], 1);
}

__global__ __launch_bounds__(256) void scanA_k(const int* __restrict__ counts,
                                               int* __restrict__ bsum) {
  const int b = blockIdx.x, tid = threadIdx.x;
  const int base = b * 1024 + tid * 4;
  int s = 0;
  if (base + 3 < N_NODES) {
    int4 v = *(const int4*)(counts + base);
    s = v.x + v.y + v.z + v.w;
  } else {
#pragma unroll
    for (int i = 0; i < 4; ++i) {
      int n = base + i;
      if (n < N_NODES) s += counts[n];
    }
  }
#pragma unroll
  for (int m = 32; m; m >>= 1) s += __shfl_xor(s, m, 64);
  __shared__ int ws[4];
  if ((tid & 63) == 0) ws[tid >> 6] = s;
  __syncthreads();
  if (tid == 0) bsum[b] = ws[0] + ws[1] + ws[2] + ws[3];
}

__global__ __launch_bounds__(128) void scanB_k(int* __restrict__ bsum,
                                               int* __restrict__ row_start) {
  __shared__ int sh[SCAN_NB];
  const int tid = threadIdx.x;
  if (tid < SCAN_NB) sh[tid] = bsum[tid];
  __syncthreads();
  if (tid == 0) {
    int acc = 0;
    for (int i = 0; i < SCAN_NB; ++i) { int t = sh[i]; sh[i] = acc; acc += t; }
    row_start[N_NODES] = acc;
  }
  __syncthreads();
  if (tid < SCAN_NB) bsum[tid] = sh[tid];
}

__global__ __launch_bounds__(256) void scanC_k(const int* __restrict__ counts,
                                               const int* __restrict__ bsum,
                                               int* __restrict__ row_start,
                                               int* __restrict__ cursor) {
  const int b = blockIdx.x, tid = threadIdx.x;
  const int base = b * 1024 + tid * 4;
  int c[4];
  int s = 0;
#pragma unroll
  for (int i = 0; i < 4; ++i) {
    int n = base + i;
    c[i] = (n < N_NODES) ? counts[n] : 0;
    s += c[i];
  }
  __shared__ int sc[256];
  sc[tid] = s;
  __syncthreads();
  int acc = s;
  for (int off = 1; off < 256; off <<= 1) {
    int v = (tid >= off) ? sc[tid - off] : 0;
    __syncthreads();
    acc += v;
    sc[tid] = acc;
    __syncthreads();
  }
  int off0 = acc - s + bsum[b];
#pragma unroll
  for (int i = 0; i < 4; ++i) {
    int n = base + i;
    if (n < N_NODES) {
      row_start[n] = off0;
      cursor[n] = off0;
      off0 += c[i];
    }
  }
}

// fused slot-assign + edge_prep + batch tail: per edge, claim CSR slot via
// atomic cursor, write packed meta {src_bits, rounded_row, cs, 0}; threads
// with e < N_NODES also emit the batch tail (out[NH+e] = (float)batch[e]).
__global__ __launch_bounds__(256) void edge_prep_k(const int* __restrict__ ei,
                                                   const float* __restrict__ pos,
                                                   int* __restrict__ cursor,
                                                   float4* __restrict__ csr_meta,
                                                   const int* __restrict__ batch,
                                                   float* __restrict__ tail_out) {
  int e = blockIdx.x * 256 + threadIdx.x;
  if (e >= N_EDGES) return;
  if (e < N_NODES) tail_out[e] = (float)batch[e];
  int s = ei[e], d = ei[N_EDGES + e];
  float dx = pos[s * 3 + 0] - pos[d * 3 + 0];
  float dy = pos[s * 3 + 1] - pos[d * 3 + 1];
  float dz = pos[s * 3 + 2] - pos[d * 3 + 2];
  float dist = sqrtf(fmaf(dx, dx, fmaf(dy, dy, dz * dz)) + 1e-12f);
  union { int i; float f; } sb;
  sb.i = s;
  float4 m;
  m.x = sb.f;
  m.y = fminf(floorf(dist * INV_H + 0.5f), 2048.0f);  // nearest row index
  m.z = 0.5f * (cosf(dist * (3.14159265358979323846f / 5.0f)) + 1.0f);
  m.w = 0.0f;
  int slot = atomicAdd(&cursor[d], 1);
  csr_meta[slot] = m;
}

// fused gather: agg[n] = sum over CSR edges of x1[src] * table[row] * C
// nearest-neighbor table (1 row/edge); 2-way unrolled edge loop.
__global__ __launch_bounds__(256) void gather2_k(const int* __restrict__ row_start,
                                                 const float4* __restrict__ csr_meta,
                                                 const ushortT* __restrict__ x1,
                                                 const ushortT* __restrict__ table,
                                                 ushortT* __restrict__ agg) {
  int node = blockIdx.x * 4 + (threadIdx.x >> 6);
  int lane = threadIdx.x & 63;
  if (node >= N_NODES) return;
  int a = row_start[node], b = row_start[node + 1];
  const int co = lane * 4;
  float s0 = 0.f, s1 = 0.f, s2 = 0.f, s3 = 0.f;
  int j = a;
  for (; j + 1 < b; j += 2) {
    float4 mtA = csr_meta[j];
    float4 mtB = csr_meta[j + 1];
    union { float f; int i; } sa, sb2;
    sa.f = mtA.x;
    sb2.f = mtB.x;
    int iA = (int)mtA.y, iB = (int)mtB.y;
    uint2 taA = *(const uint2*)(table + (size_t)iA * HID + co);
    uint2 xvA = *(const uint2*)(x1 + (size_t)sa.i * HID + co);
    uint2 taB = *(const uint2*)(table + (size_t)iB * HID + co);
    uint2 xvB = *(const uint2*)(x1 + (size_t)sb2.i * HID + co);
    // edge j
    {
      float cs = mtA.z;
      s0 = fmaf(bflo(xvA.x) * bflo(taA.x), cs, s0);
      s1 = fmaf(bfhi(xvA.x) * bfhi(taA.x), cs, s1);
      s2 = fmaf(bflo(xvA.y) * bflo(taA.y), cs, s2);
      s3 = fmaf(bfhi(xvA.y) * bfhi(taA.y), cs, s3);
    }
    // edge j+1
    {
      float cs = mtB.z;
      s0 = fmaf(bflo(xvB.x) * bflo(taB.x), cs, s0);
      s1 = fmaf(bfhi(xvB.x) * bfhi(taB.x), cs, s1);
      s2 = fmaf(bflo(xvB.y) * bflo(taB.y), cs, s2);
      s3 = fmaf(bfhi(xvB.y) * bfhi(taB.y), cs, s3);
    }
  }
  if (j < b) {
    float4 mt = csr_meta[j];
    union { float f; int i; } sb;
    sb.f = mt.x;
    int i = (int)mt.y;
    float cs = mt.z;
    uint2 ta = *(const uint2*)(table + (size_t)i * HID + co);
    uint2 xv = *(const uint2*)(x1 + (size_t)sb.i * HID + co);
    s0 = fmaf(bflo(xv.x) * bflo(ta.x), cs, s0);
    s1 = fmaf(bfhi(xv.x) * bfhi(ta.x), cs, s1);
    s2 = fmaf(bflo(xv.y) * bflo(ta.y), cs, s2);
    s3 = fmaf(bfhi(xv.y) * bfhi(ta.y), cs, s3);
  }
  uint2 o;
  o.x = f2bf2(s0, s1);
  o.y = f2bf2(s2, s3);
  *(uint2*)(agg + (size_t)node * HID + co) = o;
}

// ---------------------------------------------------------------------------
// Merged weight prep: one dispatch handles all 5 square-matrix groups
// (lin1/lin2/lin/mlp_w2: 6 mats each; proj: 1 mat) + mlp_w1 conversion.
// Blocks [0,96): lin1; [96,192): lin2; [192,288): lin; [288,384): w2;
// [384,400): proj; [400,406): w1conv (one block per layer).
__global__ __launch_bounds__(256) void wprep_all_k(
    const float* __restrict__ lin1_w, ushortT* __restrict__ lin1t,
    const float* __restrict__ lin2_w, ushortT* __restrict__ lin2t,
    const float* __restrict__ lin_w, ushortT* __restrict__ lint,
    const float* __restrict__ mlp_w2, ushortT* __restrict__ w2t,
    const float* __restrict__ proj_w, ushortT* __restrict__ projt,
    const float* __restrict__ mlp_w1, ushortT* __restrict__ w1t) {
  const int blk = blockIdx.x;
  const int tid = threadIdx.x;

  if (blk >= 400) {
    // w1conv: mlp_w1 [L][50][256] fp32 -> w1t [L][256][64] bf16 (zero-pad k)
    const int l = blk - 400;
    const float* S = mlp_w1 + (size_t)l * NGAUSS * HID;
    ushortT* D = w1t + (size_t)l * HID * 64;
    const int n = tid;
    for (int k = 0; k < 64; ++k) {
      float v = (k < NGAUSS) ? S[(size_t)k * HID + n] : 0.0f;
      D[(size_t)n * 64 + k] = f2bf(v);
    }
    return;
  }

  // square 256x256 transpose+convert path
  const float* S;
  ushortT* D;
  int b;
  if (blk < 96) { S = lin1_w; D = lin1t; b = blk; }
  else if (blk < 192) { S = lin2_w; D = lin2t; b = blk - 96; }
  else if (blk < 288) { S = lin_w; D = lint; b = blk - 192; }
  else if (blk < 384) { S = mlp_w2; D = w2t; b = blk - 288; }
  else { S = proj_w; D = projt; b = blk - 384; }

  __shared__ float tile[64][65];
  const int mat = b >> 4, t = b & 15;
  const int tr = (t >> 2) * 64, tc = (t & 3) * 64;
  S += (size_t)mat * HID * HID;
  D += (size_t)mat * HID * HID;
#pragma unroll
  for (int i = 0; i < 16; ++i) {
    int idx = i * 256 + tid;
    int r = idx >> 6, c = idx & 63;
    tile[r][c] = S[(size_t)(tr + r) * HID + tc + c];
  }
  __syncthreads();
#pragma unroll
  for (int i = 0; i < 16; ++i) {
    int idx = i * 256 + tid;
    int n = idx >> 6, k = idx & 63;
    D[(size_t)(tc + n) * HID + tr + k] = f2bf(tile[k][n]);
  }
}

// ---------------------------------------------------------------------------
extern "C" void kernel_launch(void* const* d_in, const int* in_sizes, int n_in,
                              void* d_out, int out_size, void* d_ws, size_t ws_size,
                              hipStream_t stream) {
  const int* z = (const int*)d_in[0];
  const float* pos = (const float*)d_in[1];
  const int* batch = (const int*)d_in[2];
  const int* ei = (const int*)d_in[3];
  const float* emb = (const float*)d_in[4];
  const float* mlp_w1 = (const float*)d_in[5];
  const float* mlp_b1 = (const float*)d_in[6];
  const float* mlp_w2 = (const float*)d_in[7];
  const float* mlp_b2 = (const float*)d_in[8];
  const float* lin1_w = (const float*)d_in[9];
  const float* lin2_w = (const float*)d_in[10];
  const float* lin2_b = (const float*)d_in[11];
  const float* lin_w = (const float*)d_in[12];
  const float* lin_b = (const float*)d_in[13];
  const float* proj_w = (const float*)d_in[14];
  const float* proj_b = (const float*)d_in[15];
  const float* ln_g = (const float*)d_in[16];
  const float* ln_b = (const float*)d_in[17];
  float* out = (float*)d_out;  // fp32: p [N*256] then batch [N]

  const size_t NH = (size_t)N_NODES * HID;
  const size_t WSZ = (size_t)HID * HID;

  // ---- workspace layout (~270 MB) ----
  char* w = (char*)d_ws;
  ushortT* h = (ushortT*)w;      w += NH * 2;
  ushortT* x1 = (ushortT*)w;     w += NH * 2;
  ushortT* agg = (ushortT*)w;    w += NH * 2;
  ushortT* lin1t = (ushortT*)w;  w += 6 * WSZ * 2;
  ushortT* lin2t = (ushortT*)w;  w += 6 * WSZ * 2;
  ushortT* lint = (ushortT*)w;   w += 6 * WSZ * 2;
  ushortT* w2t = (ushortT*)w;    w += 6 * WSZ * 2;
  ushortT* projt = (ushortT*)w;  w += WSZ * 2;
  ushortT* w1t = (ushortT*)w;    w += 6 * (size_t)HID * 64 * 2;
  ushortT* tables = (ushortT*)w; w += 6 * (size_t)NT_PTS * HID * 2;
  int* counts = (int*)w;         w += (size_t)N_NODES * 4;
  int* cursor = (int*)w;         w += (size_t)N_NODES * 4;
  int* row_start = (int*)w;      w += (size_t)(N_NODES + 64) * 4;
  float4* csr_meta = (float4*)w; w += (size_t)N_EDGES * 16;
  int* bsum = (int*)w;           w += (size_t)128 * 4;

  // ---- CSR build (perm fused into edge_prep; batch tail fused too) ----
  hipMemsetAsync(counts, 0, (size_t)N_NODES * 4, stream);
  hist_k<<<(N_EDGES + 255) / 256, 256, 0, stream>>>(ei, counts);
  scanA_k<<<SCAN_NB, 256, 0, stream>>>(counts, bsum);
  scanB_k<<<1, 128, 0, stream>>>(bsum, row_start);
  scanC_k<<<SCAN_NB, 256, 0, stream>>>(counts, bsum, row_start, cursor);
  edge_prep_k<<<(N_EDGES + 255) / 256, 256, 0, stream>>>(ei, pos, cursor, csr_meta,
                                                         batch, out + NH);

  // ---- weight prep: single merged dispatch ----
  wprep_all_k<<<406, 256, 0, stream>>>(lin1_w, lin1t, lin2_w, lin2t,
                                       lin_w, lint, mlp_w2, w2t,
                                       proj_w, projt, mlp_w1, w1t);

  // ---- filter tables (all 6 layers, one dispatch) ----
  table_k<<<6 * TB_BLOCKS, 256, 0, stream>>>(w1t, mlp_b1, w2t, mlp_b2, tables);

  const int MB64 = (N_NODES + 63) / 64;
  // fused embed + x1_0 GEMM (writes h and x1)
  mgemm_embed<<<MB64, 256, 0, stream>>>(z, emb, lin1t, h, x1, N_NODES);
  for (int l = 0; l < NLAYERS; ++l) {
    const size_t oW = (size_t)l * WSZ;
    const size_t o1 = (size_t)l * HID;
    gather2_k<<<(N_NODES + 3) / 4, 256, 0, stream>>>(
        row_start, csr_meta, x1,
        tables + (size_t)l * NT_PTS * HID, agg);
    if (l < NLAYERS - 1) {
      mgemm3<0><<<MB64, 512, 0, stream>>>(agg, lin2t + oW, lin2_b + o1,
                                          lint + oW, lin_b + o1, h,
                                          lin1t + (size_t)(l + 1) * WSZ, nullptr,
                                          x1, nullptr, nullptr, nullptr, N_NODES);
    } else {
      mgemm3<1><<<MB64, 512, 0, stream>>>(agg, lin2t + oW, lin2_b + o1,
                                          lint + oW, lin_b + o1, h,
                                          projt, proj_b,
                                          nullptr, ln_g, ln_b, out, N_NODES);
    }
  }
}

// Round 20
// 1264.746 us; speedup vs baseline: 1.3928x; 1.0011x over previous
//
#include <hip/hip_runtime.h>

#define N_NODES 100000
#define N_EDGES 320000
#define HID 256
#define NGAUSS 50
#define NLAYERS 6
#define SCAN_NB 98   // ceil(N_NODES/1024)
#define NT_PTS 2049  // filter table points over [0,8], h=1/256, nearest-neighbor
#define TB_BLOCKS 33 // ceil(2049/64)
#define H_STEP 0.00390625f
#define INV_H 256.0f

typedef unsigned short ushortT;
typedef unsigned int uintT;
typedef __attribute__((ext_vector_type(8))) short bf16x8;  // 8 bf16 = 4 VGPR
typedef __attribute__((ext_vector_type(4))) float f32x4;
typedef __attribute__((ext_vector_type(2))) __bf16 bf16v2;

// ---------------------------------------------------------------------------
// ShiftedSoftplus via native exp2/log2:
//   softplus(x) - ln2 = max(x,0) + ln2*log2(1 + exp2(-|x|*log2e)) - ln2
__device__ __forceinline__ float sspf(float x) {
  float e = exp2f(-fabsf(x) * 1.44269504088896340736f);
  float l = __log2f(1.0f + e);
  return fmaf(0.69314718055994530942f, l,
              fmaxf(x, 0.0f) - 0.69314718055994530942f);
}

__device__ __forceinline__ float bf2f(ushortT u) {
  union { uintT i; float f; } c;
  c.i = ((uintT)u) << 16;
  return c.f;
}

// unpack low/high bf16 of a packed dword (1 VALU op each; reinterpret is free)
__device__ __forceinline__ float bflo(uintT u) {
  union { uintT i; float f; } c;
  c.i = u << 16;
  return c.f;
}
__device__ __forceinline__ float bfhi(uintT u) {
  union { uintT i; float f; } c;
  c.i = u & 0xFFFF0000u;
  return c.f;
}

// native bf16 converts (RNE) -> v_cvt_pk_bf16_f32 on gfx950
__device__ __forceinline__ ushortT f2bf(float f) {
  union { __bf16 b; ushortT u; } c;
  c.b = (__bf16)f;
  return c.u;
}
__device__ __forceinline__ uintT f2bf2(float lo, float hi) {
  union { bf16v2 v; uintT u; } c;
  c.v = (bf16v2){(__bf16)lo, (__bf16)hi};
  return c.u;
}

// ---------------------------------------------------------------------------
// MFMA K-loops over K=256. A in LDS bf16 (row stride 264), Bt row-major [N,K].
//   A-frag: lane(16q+m) holds A[m][8q..8q+8); C/D: lane(16q+c) reg r -> row 4q+r, col c
__device__ __forceinline__ void mfma_kloop(const ushortT* As, const ushortT* Bt,
                                           f32x4 (&acc)[4][4], int lm, int q) {
#pragma unroll
  for (int k = 0; k < 256; k += 32) {
    bf16x8 a[4], b[4];
#pragma unroll
    for (int rt = 0; rt < 4; ++rt)
      a[rt] = *(const bf16x8*)&As[(rt * 16 + lm) * 264 + k + 8 * q];
#pragma unroll
    for (int ct = 0; ct < 4; ++ct)
      b[ct] = *(const bf16x8*)(Bt + (size_t)(ct * 16 + lm) * HID + k + 8 * q);
#pragma unroll
    for (int rt = 0; rt < 4; ++rt)
#pragma unroll
      for (int ct = 0; ct < 4; ++ct)
        acc[rt][ct] = __builtin_amdgcn_mfma_f32_16x16x32_bf16(a[rt], b[ct], acc[rt][ct], 0, 0, 0);
  }
}

// 8-wave variant, 32-col stripe per wave, acc[4][2] (measured-best plain form:
// per-k-step loads; the compiler's sunk-load schedule beat forced preloads).
__device__ __forceinline__ void mfma_kloop32(const ushortT* As, const ushortT* Bt,
                                             f32x4 (&acc)[4][2], int c0, int lm, int q) {
#pragma unroll
  for (int k = 0; k < 256; k += 32) {
    bf16x8 b[2];
#pragma unroll
    for (int ct = 0; ct < 2; ++ct)
      b[ct] = *(const bf16x8*)(Bt + (size_t)(c0 + ct * 16 + lm) * HID + k + 8 * q);
#pragma unroll
    for (int rt = 0; rt < 4; ++rt) {
      bf16x8 a = *(const bf16x8*)&As[(rt * 16 + lm) * 264 + k + 8 * q];
#pragma unroll
      for (int ct = 0; ct < 2; ++ct)
        acc[rt][ct] = __builtin_amdgcn_mfma_f32_16x16x32_bf16(a, b[ct], acc[rt][ct], 0, 0, 0);
    }
  }
}

// acc tile -> LDS (bf16, A layout), 4-wave version
__device__ __forceinline__ void acc_to_lds(ushortT* As, const f32x4 (&acc)[4][4],
                                           int c0, int lm, int q) {
#pragma unroll
  for (int ct = 0; ct < 4; ++ct) {
    const int col = c0 + ct * 16 + lm;
#pragma unroll
    for (int rt = 0; rt < 4; ++rt) {
      const int row = rt * 16 + q * 4;
      uintT u01 = f2bf2(acc[rt][ct][0], acc[rt][ct][1]);
      uintT u23 = f2bf2(acc[rt][ct][2], acc[rt][ct][3]);
      As[(row + 0) * 264 + col] = (ushortT)u01;
      As[(row + 1) * 264 + col] = (ushortT)(u01 >> 16);
      As[(row + 2) * 264 + col] = (ushortT)u23;
      As[(row + 3) * 264 + col] = (ushortT)(u23 >> 16);
    }
  }
}

// coalesced LDS tile -> global (row-contiguous uint4), 256-thread version
__device__ __forceinline__ void store_tile64(const ushortT* As,
                                             ushortT* __restrict__ dst,
                                             int m0, int M, int tid) {
#pragma unroll
  for (int i = 0; i < 8; ++i) {
    int idx = i * 256 + tid;
    int r = idx >> 5, ch = idx & 31;
    int m = m0 + r;
    if (m < M)
      *(uint4*)(dst + (size_t)m * HID + ch * 8) = *(const uint4*)&As[r * 264 + ch * 8];
  }
}

// ---------------------------------------------------------------------------
// Fused embed + x1_0 GEMM: stage emb[z[m]] (fp32->bf16) into LDS AND h,
// then C = h @ lin1t. Eliminates the separate embed dispatch + h re-read.
__global__ __launch_bounds__(256) void mgemm_embed(const int* __restrict__ z,
                                                   const float* __restrict__ emb,
                                                   const ushortT* __restrict__ Bt,
                                                   ushortT* __restrict__ h,
                                                   ushortT* __restrict__ Cbf, int M) {
  __shared__ ushortT As[64 * 264];
  const int tid = threadIdx.x;
  const int m0 = blockIdx.x * 64;

#pragma unroll
  for (int i = 0; i < 8; ++i) {
    int idx = i * 256 + tid;
    int r = idx >> 5, ch = idx & 31;
    int m = m0 + r;
    uint4 u = make_uint4(0, 0, 0, 0);
    if (m < M) {
      const float* er = emb + (size_t)z[m] * HID + ch * 8;
      float4 f0 = *(const float4*)er;
      float4 f1 = *(const float4*)(er + 4);
      u.x = f2bf2(f0.x, f0.y);
      u.y = f2bf2(f0.z, f0.w);
      u.z = f2bf2(f1.x, f1.y);
      u.w = f2bf2(f1.z, f1.w);
      *(uint4*)(h + (size_t)m * HID + ch * 8) = u;
    }
    *(uint4*)&As[r * 264 + ch * 8] = u;
  }
  __syncthreads();

  const int lane = tid & 63;
  const int lm = lane & 15, q = lane >> 4;
  const int c0 = (tid >> 6) * 64;

  f32x4 acc[4][4];
#pragma unroll
  for (int rt = 0; rt < 4; ++rt)
#pragma unroll
    for (int ct = 0; ct < 4; ++ct) acc[rt][ct] = (f32x4){0.f, 0.f, 0.f, 0.f};

  mfma_kloop(As, Bt + (size_t)c0 * HID, acc, lm, q);
  __syncthreads();  // all waves done reading As
  acc_to_lds(As, acc, c0, lm, q);
  __syncthreads();
  store_tile64(As, Cbf, m0, M, tid);
}

// ---------------------------------------------------------------------------
// Fused interaction tail + next-layer head (3 chained K=256 GEMMs, LDS-resident).
// 512 threads / 8 waves; 64-row tile; each wave owns a 32-col stripe, acc[4][2].
// LDS ping-pong (buf0/buf1) removes the two WAR barriers: phases alternate
// buffers so epi writes never clobber a buffer still being read.
//   buf0: A-tile          (kloop1 reads)
//   buf1: x2 = ssp(...)   (epi1 writes, kloop2 reads)
//   buf0: hn = ...        (epi2 writes, kloop3 reads)
//   LAST=1: buf1 reused as fp32 LN tile.
// 3 __syncthreads per block instead of 5.
template <int LAST>
__global__ __launch_bounds__(512, 2) void mgemm3(const ushortT* __restrict__ A,
                                                 const ushortT* __restrict__ B1t,
                                                 const float* __restrict__ b1v,
                                                 const ushortT* __restrict__ B2t,
                                                 const float* __restrict__ b2v,
                                                 ushortT* __restrict__ h,
                                                 const ushortT* __restrict__ B3t,
                                                 const float* __restrict__ b3v,
                                                 ushortT* __restrict__ x1out,
                                                 const float* __restrict__ lng,
                                                 const float* __restrict__ lnb,
                                                 float* __restrict__ outp, int M) {
  __shared__ ushortT As[2][64 * 264];  // 67584 B -> 2 blocks/CU
  ushortT* buf0 = As[0];
  ushortT* buf1 = As[1];
  const int tid = threadIdx.x;
  const int m0 = blockIdx.x * 64;

  // stage 64x256 tile into buf0: 2048 uint4 over 512 threads
#pragma unroll
  for (int i = 0; i < 4; ++i) {
    int idx = i * 512 + tid;
    int r = idx >> 5, ch = idx & 31;
    int m = m0 + r;
    uint4 u = make_uint4(0, 0, 0, 0);
    if (m < M) u = *(const uint4*)(A + (size_t)m * HID + ch * 8);
    *(uint4*)&buf0[r * 264 + ch * 8] = u;
  }
  __syncthreads();  // (1) staging visible

  const int lane = tid & 63;
  const int lm = lane & 15, q = lane >> 4;
  const int c0 = (tid >> 6) * 32;  // wave's 32-col stripe

  f32x4 acc[4][2];
#pragma unroll
  for (int rt = 0; rt < 4; ++rt)
#pragma unroll
    for (int ct = 0; ct < 2; ++ct) acc[rt][ct] = (f32x4){0.f, 0.f, 0.f, 0.f};
  mfma_kloop32(buf0, B1t, acc, c0, lm, q);
  // no barrier: epi1 writes buf1 (kloop1 read buf0)

  // epi1: x2 = ssp(acc + b1) -> buf1
#pragma unroll
  for (int ct = 0; ct < 2; ++ct) {
    const int col = c0 + ct * 16 + lm;
    const float bv = b1v[col];
#pragma unroll
    for (int rt = 0; rt < 4; ++rt) {
      const int row = rt * 16 + q * 4;
      float v0 = sspf(acc[rt][ct][0] + bv);
      float v1 = sspf(acc[rt][ct][1] + bv);
      float v2 = sspf(acc[rt][ct][2] + bv);
      float v3 = sspf(acc[rt][ct][3] + bv);
      uintT u01 = f2bf2(v0, v1), u23 = f2bf2(v2, v3);
      buf1[(row + 0) * 264 + col] = (ushortT)u01;
      buf1[(row + 1) * 264 + col] = (ushortT)(u01 >> 16);
      buf1[(row + 2) * 264 + col] = (ushortT)u23;
      buf1[(row + 3) * 264 + col] = (ushortT)(u23 >> 16);
    }
  }
  __syncthreads();  // (2) buf1 visible; also: all waves past kloop1 (buf0 free)

#pragma unroll
  for (int rt = 0; rt < 4; ++rt)
#pragma unroll
    for (int ct = 0; ct < 2; ++ct) acc[rt][ct] = (f32x4){0.f, 0.f, 0.f, 0.f};
  mfma_kloop32(buf1, B2t, acc, c0, lm, q);
  // no barrier: epi2 writes buf0 (free since sync 2)

  // epi2: hn = acc + b2 + h_old -> h (scattered) and buf0
#pragma unroll
  for (int ct = 0; ct < 2; ++ct) {
    const int col = c0 + ct * 16 + lm;
    const float bv = b2v[col];
#pragma unroll
    for (int rt = 0; rt < 4; ++rt) {
      const int mb = m0 + rt * 16 + q * 4;
      const int row = rt * 16 + q * 4;
      float v[4];
#pragma unroll
      for (int r = 0; r < 4; ++r) {
        float res = (mb + r < M) ? bf2f(h[(size_t)(mb + r) * HID + col]) : 0.0f;
        v[r] = acc[rt][ct][r] + bv + res;
      }
      uintT u01 = f2bf2(v[0], v[1]), u23 = f2bf2(v[2], v[3]);
      buf0[(row + 0) * 264 + col] = (ushortT)u01;
      buf0[(row + 1) * 264 + col] = (ushortT)(u01 >> 16);
      buf0[(row + 2) * 264 + col] = (ushortT)u23;
      buf0[(row + 3) * 264 + col] = (ushortT)(u23 >> 16);
      if (mb + 0 < M) h[(size_t)(mb + 0) * HID + col] = (ushortT)u01;
      if (mb + 1 < M) h[(size_t)(mb + 1) * HID + col] = (ushortT)(u01 >> 16);
      if (mb + 2 < M) h[(size_t)(mb + 2) * HID + col] = (ushortT)u23;
      if (mb + 3 < M) h[(size_t)(mb + 3) * HID + col] = (ushortT)(u23 >> 16);
    }
  }
  __syncthreads();  // (3) buf0 visible; also: all waves past kloop2 (buf1 free)

#pragma unroll
  for (int rt = 0; rt < 4; ++rt)
#pragma unroll
    for (int ct = 0; ct < 2; ++ct) acc[rt][ct] = (f32x4){0.f, 0.f, 0.f, 0.f};
  mfma_kloop32(buf0, B3t, acc, c0, lm, q);

  if constexpr (LAST) {
    // fused LayerNorm + SiLU, fp32 end-to-end; buf1 reused as fp32 [32][260]
    // tile (buf1 free since sync 3; kloop3 reads buf0 only).
    float* Pf = (float*)buf1;
    const int PSTR = 260;  // 32*260*4 = 33280 B <= 33792 B
    const int wv = tid >> 6;
#pragma unroll
    for (int half = 0; half < 2; ++half) {
      // write this half's rows (rt = 2*half .. 2*half+1) + bias into LDS fp32
#pragma unroll
      for (int ct = 0; ct < 2; ++ct) {
        const int col = c0 + ct * 16 + lm;
        const float bv = b3v[col];
#pragma unroll
        for (int rtl = 0; rtl < 2; ++rtl) {
          const int rt = half * 2 + rtl;
          const int lrow = rtl * 16 + q * 4;
#pragma unroll
          for (int r = 0; r < 4; ++r)
            Pf[(lrow + r) * PSTR + col] = acc[rt][ct][r] + bv;
        }
      }
      __syncthreads();
      // LN+SiLU: wave wv owns rows wv*4..wv*4+3 of this half; lane holds 4 cols
#pragma unroll
      for (int rr = 0; rr < 4; ++rr) {
        const int lrow = wv * 4 + rr;
        const int grow = m0 + half * 32 + lrow;
        float4 v4 = *(float4*)&Pf[lrow * PSTR + lane * 4];
        float s = v4.x + v4.y + v4.z + v4.w;
#pragma unroll
        for (int m = 32; m; m >>= 1) s += __shfl_xor(s, m, 64);
        float mu = s * (1.0f / 256.0f);
        float d0 = v4.x - mu, d1 = v4.y - mu, d2 = v4.z - mu, d3 = v4.w - mu;
        float qv = d0 * d0 + d1 * d1 + d2 * d2 + d3 * d3;
#pragma unroll
        for (int m = 32; m; m >>= 1) qv += __shfl_xor(qv, m, 64);
        float rstd = rsqrtf(qv * (1.0f / 256.0f) + 1e-5f);
        if (grow < M) {
          float4 g4 = *(const float4*)&lng[lane * 4];
          float4 b4 = *(const float4*)&lnb[lane * 4];
          float y0 = d0 * rstd * g4.x + b4.x;
          float y1 = d1 * rstd * g4.y + b4.y;
          float y2 = d2 * rstd * g4.z + b4.z;
          float y3 = d3 * rstd * g4.w + b4.w;
          float4 o;
          o.x = y0 * (1.0f / (1.0f + exp2f(-y0 * 1.44269504088896340736f)));
          o.y = y1 * (1.0f / (1.0f + exp2f(-y1 * 1.44269504088896340736f)));
          o.z = y2 * (1.0f / (1.0f + exp2f(-y2 * 1.44269504088896340736f)));
          o.w = y3 * (1.0f / (1.0f + exp2f(-y3 * 1.44269504088896340736f)));
          *(float4*)&outp[(size_t)grow * HID + lane * 4] = o;
        }
      }
      __syncthreads();  // before next half reuses Pf
    }
  } else {
#pragma unroll
    for (int ct = 0; ct < 2; ++ct) {
      const int col = c0 + ct * 16 + lm;
#pragma unroll
      for (int rt = 0; rt < 4; ++rt) {
        const int mb = m0 + rt * 16 + q * 4;
        uintT u01 = f2bf2(acc[rt][ct][0], acc[rt][ct][1]);
        uintT u23 = f2bf2(acc[rt][ct][2], acc[rt][ct][3]);
        if (mb + 0 < M) x1out[(size_t)(mb + 0) * HID + col] = (ushortT)u01;
        if (mb + 1 < M) x1out[(size_t)(mb + 1) * HID + col] = (ushortT)(u01 >> 16);
        if (mb + 2 < M) x1out[(size_t)(mb + 2) * HID + col] = (ushortT)u23;
        if (mb + 3 < M) x1out[(size_t)(mb + 3) * HID + col] = (ushortT)(u23 >> 16);
      }
    }
  }
}

// ---------------------------------------------------------------------------
// Filter table build: table[l][g][:] = ssp(rbf(g*H_STEP) @ w1t[l] + b1[l]) @ w2t[l] + b2[l]
__global__ __launch_bounds__(256) void table_k(
    const ushortT* __restrict__ w1t_all, const float* __restrict__ b1_all,
    const ushortT* __restrict__ w2t_all, const float* __restrict__ b2_all,
    ushortT* __restrict__ table_all) {
  __shared__ ushortT T[64 * 264];
  ushortT* R = T;  // rbf tile aliases T head; barrier before T write

  const int blk = blockIdx.x;
  const int l = blk / TB_BLOCKS, tb = blk % TB_BLOCKS;
  const ushortT* w1t = w1t_all + (size_t)l * HID * 64;
  const float* b1 = b1_all + (size_t)l * HID;
  const ushortT* w2t = w2t_all + (size_t)l * HID * HID;
  const float* b2 = b2_all + (size_t)l * HID;
  ushortT* table = table_all + (size_t)l * NT_PTS * HID;

  const int tid = threadIdx.x;
  const float delta = 5.0f / 49.0f;
  const float coeff2 = (-0.5f / (delta * delta)) * 1.44269504088896340736f;
#pragma unroll
  for (int i = 0; i < 16; ++i) {
    int idx = i * 256 + tid;
    int e = idx >> 6, k = idx & 63;
    float v = 0.0f;
    if (k < NGAUSS) {
      float dist = (float)(tb * 64 + e) * H_STEP;
      float dd = dist - (float)k * delta;
      v = exp2f(coeff2 * dd * dd);
    }
    R[e * 72 + k] = f2bf(v);
  }
  __syncthreads();

  const int lane = tid & 63;
  const int lm = lane & 15, q = lane >> 4;
  const int c0 = (tid >> 6) * 64;

  // phase 1: t = ssp(R @ w1t + b1), K=64
  {
    f32x4 acc1[4][4];
#pragma unroll
    for (int rt = 0; rt < 4; ++rt)
#pragma unroll
      for (int ct = 0; ct < 4; ++ct) acc1[rt][ct] = (f32x4){0.f, 0.f, 0.f, 0.f};
#pragma unroll
    for (int k = 0; k < 64; k += 32) {
      bf16x8 a[4], b[4];
#pragma unroll
      for (int rt = 0; rt < 4; ++rt)
        a[rt] = *(const bf16x8*)&R[(rt * 16 + lm) * 72 + k + 8 * q];
#pragma unroll
      for (int ct = 0; ct < 4; ++ct)
        b[ct] = *(const bf16x8*)(w1t + (size_t)(c0 + ct * 16 + lm) * 64 + k + 8 * q);
#pragma unroll
      for (int rt = 0; rt < 4; ++rt)
#pragma unroll
        for (int ct = 0; ct < 4; ++ct)
          acc1[rt][ct] = __builtin_amdgcn_mfma_f32_16x16x32_bf16(a[rt], b[ct], acc1[rt][ct], 0, 0, 0);
    }
    __syncthreads();  // done reading R before T (aliased) is written
#pragma unroll
    for (int ct = 0; ct < 4; ++ct) {
      const int col = c0 + ct * 16 + lm;
      const float bv = b1[col];
#pragma unroll
      for (int rt = 0; rt < 4; ++rt) {
        const int row = rt * 16 + q * 4;
        float v0 = sspf(acc1[rt][ct][0] + bv);
        float v1 = sspf(acc1[rt][ct][1] + bv);
        float v2 = sspf(acc1[rt][ct][2] + bv);
        float v3 = sspf(acc1[rt][ct][3] + bv);
        uintT u01 = f2bf2(v0, v1), u23 = f2bf2(v2, v3);
        T[(row + 0) * 264 + col] = (ushortT)u01;
        T[(row + 1) * 264 + col] = (ushortT)(u01 >> 16);
        T[(row + 2) * 264 + col] = (ushortT)u23;
        T[(row + 3) * 264 + col] = (ushortT)(u23 >> 16);
      }
    }
  }
  __syncthreads();

  // phase 2: Wf = t @ w2t + b2, write table rows directly
  f32x4 acc[4][4];
#pragma unroll
  for (int rt = 0; rt < 4; ++rt)
#pragma unroll
    for (int ct = 0; ct < 4; ++ct) acc[rt][ct] = (f32x4){0.f, 0.f, 0.f, 0.f};
  mfma_kloop(T, w2t + (size_t)c0 * HID, acc, lm, q);

#pragma unroll
  for (int ct = 0; ct < 4; ++ct) {
    const int col = c0 + ct * 16 + lm;
    const float bv = b2[col];
#pragma unroll
    for (int rt = 0; rt < 4; ++rt) {
      const int row = rt * 16 + q * 4;
#pragma unroll
      for (int r = 0; r < 4; ++r) {
        int g = tb * 64 + row + r;
        if (g < NT_PTS) table[(size_t)g * HID + col] = f2bf(acc[rt][ct][r] + bv);
      }
    }
  }
}

// ---------------------------------------------------------------------------
// CSR build: histogram -> hierarchical scan -> fused slot-assign + edge_prep
__global__ __launch_bounds__(256) void hist_k(const int* __restrict__ ei,
                                              int* __restrict__ counts) {
  int e = blockIdx.x * 256 + threadIdx.x;
  if (e < N_EDGES) atomicAdd(&counts[ei[N_EDGES + e]], 1);
}

__global__ __launch_bounds__(256) void scanA_k(const int* __restrict__ counts,
                                               int* __restrict__ bsum) {
  const int b = blockIdx.x, tid = threadIdx.x;
  const int base = b * 1024 + tid * 4;
  int s = 0;
  if (base + 3 < N_NODES) {
    int4 v = *(const int4*)(counts + base);
    s = v.x + v.y + v.z + v.w;
  } else {
#pragma unroll
    for (int i = 0; i < 4; ++i) {
      int n = base + i;
      if (n < N_NODES) s += counts[n];
    }
  }
#pragma unroll
  for (int m = 32; m; m >>= 1) s += __shfl_xor(s, m, 64);
  __shared__ int ws[4];
  if ((tid & 63) == 0) ws[tid >> 6] = s;
  __syncthreads();
  if (tid == 0) bsum[b] = ws[0] + ws[1] + ws[2] + ws[3];
}

__global__ __launch_bounds__(128) void scanB_k(int* __restrict__ bsum,
                                               int* __restrict__ row_start) {
  __shared__ int sh[SCAN_NB];
  const int tid = threadIdx.x;
  if (tid < SCAN_NB) sh[tid] = bsum[tid];
  __syncthreads();
  if (tid == 0) {
    int acc = 0;
    for (int i = 0; i < SCAN_NB; ++i) { int t = sh[i]; sh[i] = acc; acc += t; }
    row_start[N_NODES] = acc;
  }
  __syncthreads();
  if (tid < SCAN_NB) bsum[tid] = sh[tid];
}

__global__ __launch_bounds__(256) void scanC_k(const int* __restrict__ counts,
                                               const int* __restrict__ bsum,
                                               int* __restrict__ row_start,
                                               int* __restrict__ cursor) {
  const int b = blockIdx.x, tid = threadIdx.x;
  const int base = b * 1024 + tid * 4;
  int c[4];
  int s = 0;
#pragma unroll
  for (int i = 0; i < 4; ++i) {
    int n = base + i;
    c[i] = (n < N_NODES) ? counts[n] : 0;
    s += c[i];
  }
  __shared__ int sc[256];
  sc[tid] = s;
  __syncthreads();
  int acc = s;
  for (int off = 1; off < 256; off <<= 1) {
    int v = (tid >= off) ? sc[tid - off] : 0;
    __syncthreads();
    acc += v;
    sc[tid] = acc;
    __syncthreads();
  }
  int off0 = acc - s + bsum[b];
#pragma unroll
  for (int i = 0; i < 4; ++i) {
    int n = base + i;
    if (n < N_NODES) {
      row_start[n] = off0;
      cursor[n] = off0;
      off0 += c[i];
    }
  }
}

// fused slot-assign + edge_prep + batch tail: per edge, claim CSR slot via
// atomic cursor, write packed meta {src_bits, rounded_row, cs, 0}; threads
// with e < N_NODES also emit the batch tail (out[NH+e] = (float)batch[e]).
__global__ __launch_bounds__(256) void edge_prep_k(const int* __restrict__ ei,
                                                   const float* __restrict__ pos,
                                                   int* __restrict__ cursor,
                                                   float4* __restrict__ csr_meta,
                                                   const int* __restrict__ batch,
                                                   float* __restrict__ tail_out) {
  int e = blockIdx.x * 256 + threadIdx.x;
  if (e >= N_EDGES) return;
  if (e < N_NODES) tail_out[e] = (float)batch[e];
  int s = ei[e], d = ei[N_EDGES + e];
  float dx = pos[s * 3 + 0] - pos[d * 3 + 0];
  float dy = pos[s * 3 + 1] - pos[d * 3 + 1];
  float dz = pos[s * 3 + 2] - pos[d * 3 + 2];
  float dist = sqrtf(fmaf(dx, dx, fmaf(dy, dy, dz * dz)) + 1e-12f);
  union { int i; float f; } sb;
  sb.i = s;
  float4 m;
  m.x = sb.f;
  m.y = fminf(floorf(dist * INV_H + 0.5f), 2048.0f);  // nearest row index
  m.z = 0.5f * (cosf(dist * (3.14159265358979323846f / 5.0f)) + 1.0f);
  m.w = 0.0f;
  int slot = atomicAdd(&cursor[d], 1);
  csr_meta[slot] = m;
}

// fused gather: agg[n] = sum over CSR edges of x1[src] * table[row] * C
// nearest-neighbor table (1 row/edge); 2-way unrolled edge loop.
__global__ __launch_bounds__(256) void gather2_k(const int* __restrict__ row_start,
                                                 const float4* __restrict__ csr_meta,
                                                 const ushortT* __restrict__ x1,
                                                 const ushortT* __restrict__ table,
                                                 ushortT* __restrict__ agg) {
  int node = blockIdx.x * 4 + (threadIdx.x >> 6);
  int lane = threadIdx.x & 63;
  if (node >= N_NODES) return;
  int a = row_start[node], b = row_start[node + 1];
  const int co = lane * 4;
  float s0 = 0.f, s1 = 0.f, s2 = 0.f, s3 = 0.f;
  int j = a;
  for (; j + 1 < b; j += 2) {
    float4 mtA = csr_meta[j];
    float4 mtB = csr_meta[j + 1];
    union { float f; int i; } sa, sb2;
    sa.f = mtA.x;
    sb2.f = mtB.x;
    int iA = (int)mtA.y, iB = (int)mtB.y;
    uint2 taA = *(const uint2*)(table + (size_t)iA * HID + co);
    uint2 xvA = *(const uint2*)(x1 + (size_t)sa.i * HID + co);
    uint2 taB = *(const uint2*)(table + (size_t)iB * HID + co);
    uint2 xvB = *(const uint2*)(x1 + (size_t)sb2.i * HID + co);
    // edge j
    {
      float cs = mtA.z;
      s0 = fmaf(bflo(xvA.x) * bflo(taA.x), cs, s0);
      s1 = fmaf(bfhi(xvA.x) * bfhi(taA.x), cs, s1);
      s2 = fmaf(bflo(xvA.y) * bflo(taA.y), cs, s2);
      s3 = fmaf(bfhi(xvA.y) * bfhi(taA.y), cs, s3);
    }
    // edge j+1
    {
      float cs = mtB.z;
      s0 = fmaf(bflo(xvB.x) * bflo(taB.x), cs, s0);
      s1 = fmaf(bfhi(xvB.x) * bfhi(taB.x), cs, s1);
      s2 = fmaf(bflo(xvB.y) * bflo(taB.y), cs, s2);
      s3 = fmaf(bfhi(xvB.y) * bfhi(taB.y), cs, s3);
    }
  }
  if (j < b) {
    float4 mt = csr_meta[j];
    union { float f; int i; } sb;
    sb.f = mt.x;
    int i = (int)mt.y;
    float cs = mt.z;
    uint2 ta = *(const uint2*)(table + (size_t)i * HID + co);
    uint2 xv = *(const uint2*)(x1 + (size_t)sb.i * HID + co);
    s0 = fmaf(bflo(xv.x) * bflo(ta.x), cs, s0);
    s1 = fmaf(bfhi(xv.x) * bfhi(ta.x), cs, s1);
    s2 = fmaf(bflo(xv.y) * bflo(ta.y), cs, s2);
    s3 = fmaf(bfhi(xv.y) * bfhi(ta.y), cs, s3);
  }
  uint2 o;
  o.x = f2bf2(s0, s1);
  o.y = f2bf2(s2, s3);
  *(uint2*)(agg + (size_t)node * HID + co) = o;
}

// ---------------------------------------------------------------------------
// Merged weight prep: one dispatch handles all 5 square-matrix groups
// (lin1/lin2/lin/mlp_w2: 6 mats each; proj: 1 mat) + mlp_w1 conversion.
// Blocks [0,96): lin1; [96,192): lin2; [192,288): lin; [288,384): w2;
// [384,400): proj; [400,406): w1conv (one block per layer).
__global__ __launch_bounds__(256) void wprep_all_k(
    const float* __restrict__ lin1_w, ushortT* __restrict__ lin1t,
    const float* __restrict__ lin2_w, ushortT* __restrict__ lin2t,
    const float* __restrict__ lin_w, ushortT* __restrict__ lint,
    const float* __restrict__ mlp_w2, ushortT* __restrict__ w2t,
    const float* __restrict__ proj_w, ushortT* __restrict__ projt,
    const float* __restrict__ mlp_w1, ushortT* __restrict__ w1t) {
  const int blk = blockIdx.x;
  const int tid = threadIdx.x;

  if (blk >= 400) {
    // w1conv: mlp_w1 [L][50][256] fp32 -> w1t [L][256][64] bf16 (zero-pad k)
    const int l = blk - 400;
    const float* S = mlp_w1 + (size_t)l * NGAUSS * HID;
    ushortT* D = w1t + (size_t)l * HID * 64;
    const int n = tid;
    for (int k = 0; k < 64; ++k) {
      float v = (k < NGAUSS) ? S[(size_t)k * HID + n] : 0.0f;
      D[(size_t)n * 64 + k] = f2bf(v);
    }
    return;
  }

  // square 256x256 transpose+convert path
  const float* S;
  ushortT* D;
  int b;
  if (blk < 96) { S = lin1_w; D = lin1t; b = blk; }
  else if (blk < 192) { S = lin2_w; D = lin2t; b = blk - 96; }
  else if (blk < 288) { S = lin_w; D = lint; b = blk - 192; }
  else if (blk < 384) { S = mlp_w2; D = w2t; b = blk - 288; }
  else { S = proj_w; D = projt; b = blk - 384; }

  __shared__ float tile[64][65];
  const int mat = b >> 4, t = b & 15;
  const int tr = (t >> 2) * 64, tc = (t & 3) * 64;
  S += (size_t)mat * HID * HID;
  D += (size_t)mat * HID * HID;
#pragma unroll
  for (int i = 0; i < 16; ++i) {
    int idx = i * 256 + tid;
    int r = idx >> 6, c = idx & 63;
    tile[r][c] = S[(size_t)(tr + r) * HID + tc + c];
  }
  __syncthreads();
#pragma unroll
  for (int i = 0; i < 16; ++i) {
    int idx = i * 256 + tid;
    int n = idx >> 6, k = idx & 63;
    D[(size_t)(tc + n) * HID + tr + k] = f2bf(tile[k][n]);
  }
}

// ---------------------------------------------------------------------------
extern "C" void kernel_launch(void* const* d_in, const int* in_sizes, int n_in,
                              void* d_out, int out_size, void* d_ws, size_t ws_size,
                              hipStream_t stream) {
  const int* z = (const int*)d_in[0];
  const float* pos = (const float*)d_in[1];
  const int* batch = (const int*)d_in[2];
  const int* ei = (const int*)d_in[3];
  const float* emb = (const float*)d_in[4];
  const float* mlp_w1 = (const float*)d_in[5];
  const float* mlp_b1 = (const float*)d_in[6];
  const float* mlp_w2 = (const float*)d_in[7];
  const float* mlp_b2 = (const float*)d_in[8];
  const float* lin1_w = (const float*)d_in[9];
  const float* lin2_w = (const float*)d_in[10];
  const float* lin2_b = (const float*)d_in[11];
  const float* lin_w = (const float*)d_in[12];
  const float* lin_b = (const float*)d_in[13];
  const float* proj_w = (const float*)d_in[14];
  const float* proj_b = (const float*)d_in[15];
  const float* ln_g = (const float*)d_in[16];
  const float* ln_b = (const float*)d_in[17];
  float* out = (float*)d_out;  // fp32: p [N*256] then batch [N]

  const size_t NH = (size_t)N_NODES * HID;
  const size_t WSZ = (size_t)HID * HID;

  // ---- workspace layout (~270 MB) ----
  char* w = (char*)d_ws;
  ushortT* h = (ushortT*)w;      w += NH * 2;
  ushortT* x1 = (ushortT*)w;     w += NH * 2;
  ushortT* agg = (ushortT*)w;    w += NH * 2;
  ushortT* lin1t = (ushortT*)w;  w += 6 * WSZ * 2;
  ushortT* lin2t = (ushortT*)w;  w += 6 * WSZ * 2;
  ushortT* lint = (ushortT*)w;   w += 6 * WSZ * 2;
  ushortT* w2t = (ushortT*)w;    w += 6 * WSZ * 2;
  ushortT* projt = (ushortT*)w;  w += WSZ * 2;
  ushortT* w1t = (ushortT*)w;    w += 6 * (size_t)HID * 64 * 2;
  ushortT* tables = (ushortT*)w; w += 6 * (size_t)NT_PTS * HID * 2;
  int* counts = (int*)w;         w += (size_t)N_NODES * 4;
  int* cursor = (int*)w;         w += (size_t)N_NODES * 4;
  int* row_start = (int*)w;      w += (size_t)(N_NODES + 64) * 4;
  float4* csr_meta = (float4*)w; w += (size_t)N_EDGES * 16;
  int* bsum = (int*)w;           w += (size_t)128 * 4;

  // ---- CSR build (perm fused into edge_prep; batch tail fused too) ----
  hipMemsetAsync(counts, 0, (size_t)N_NODES * 4, stream);
  hist_k<<<(N_EDGES + 255) / 256, 256, 0, stream>>>(ei, counts);
  scanA_k<<<SCAN_NB, 256, 0, stream>>>(counts, bsum);
  scanB_k<<<1, 128, 0, stream>>>(bsum, row_start);
  scanC_k<<<SCAN_NB, 256, 0, stream>>>(counts, bsum, row_start, cursor);
  edge_prep_k<<<(N_EDGES + 255) / 256, 256, 0, stream>>>(ei, pos, cursor, csr_meta,
                                                         batch, out + NH);

  // ---- weight prep: single merged dispatch ----
  wprep_all_k<<<406, 256, 0, stream>>>(lin1_w, lin1t, lin2_w, lin2t,
                                       lin_w, lint, mlp_w2, w2t,
                                       proj_w, projt, mlp_w1, w1t);

  // ---- filter tables (all 6 layers, one dispatch) ----
  table_k<<<6 * TB_BLOCKS, 256, 0, stream>>>(w1t, mlp_b1, w2t, mlp_b2, tables);

  const int MB64 = (N_NODES + 63) / 64;
  // fused embed + x1_0 GEMM (writes h and x1)
  mgemm_embed<<<MB64, 256, 0, stream>>>(z, emb, lin1t, h, x1, N_NODES);
  for (int l = 0; l < NLAYERS; ++l) {
    const size_t oW = (size_t)l * WSZ;
    const size_t o1 = (size_t)l * HID;
    gather2_k<<<(N_NODES + 3) / 4, 256, 0, stream>>>(
        row_start, csr_meta, x1,
        tables + (size_t)l * NT_PTS * HID, agg);
    if (l < NLAYERS - 1) {
      mgemm3<0><<<MB64, 512, 0, stream>>>(agg, lin2t + oW, lin2_b + o1,
                                          lint + oW, lin_b + o1, h,
                                          lin1t + (size_t)(l + 1) * WSZ, nullptr,
                                          x1, nullptr, nullptr, nullptr, N_NODES);
    } else {
      mgemm3<1><<<MB64, 512, 0, stream>>>(agg, lin2t + oW, lin2_b + o1,
                                          lint + oW, lin_b + o1, h,
                                          projt, proj_b,
                                          nullptr, ln_g, ln_b, out, N_NODES);
    }
  }
}